// Round 13
// baseline (526.523 us; speedup 1.0000x reference)
//
#include <hip/hip_runtime.h>
#include <cmath>

#define B_   4
#define N_   2466
#define R_   (B_*N_)     // 9864
#define ELLW 96

typedef __attribute__((ext_vector_type(8))) short bf16x8;
typedef __attribute__((ext_vector_type(4))) float f32x4;

__device__ __forceinline__ unsigned short bf16_rne(float x) {
  union { float f; unsigned u; } c; c.f = x;
  unsigned r = c.u + 0x7FFFu + ((c.u >> 16) & 1u);
  return (unsigned short)(r >> 16);
}
__device__ __forceinline__ float bf16_back(unsigned short h) {
  union { float f; unsigned u; } c; c.u = ((unsigned)h) << 16;
  return c.f;
}

struct WMats { const float* p[15]; };   // rb-major: w00,w01,pw,w10,w11

// Fragment-order layout (lin_w and res weights):
// e = ((slab*8 + nt)*64 + lane)*8 + j ; k = slab*32 + (lane>>4)*8 + j ; n = nt*16 + (lane&15)

// ============ fused pre-kernel: transposes + ELL + all W hi/lo fragment splits ============
__global__ __launch_bounds__(256) void k_pre(
    const float* __restrict__ c2, const float* __restrict__ c3,
    const float* __restrict__ c4, const float* __restrict__ c5,
    float* __restrict__ t0, float* __restrict__ t1,
    float* __restrict__ t2, float* __restrict__ t3,
    const float* __restrict__ adj, int* __restrict__ cols, int* __restrict__ cnts,
    const float* __restrict__ lin_w,
    unsigned short* __restrict__ whi, unsigned short* __restrict__ wlo,
    WMats wm,
    unsigned short* __restrict__ wrh, unsigned short* __restrict__ wrl) {
  __shared__ float t[32][33];
  int bid = blockIdx.x;
  if (bid < 6144) {
    const float* in; float* out; int C, P, nx, ny, rem;
    if (bid < 3136)      { in = c2; out = t0; C = 256;  P = 3136; nx = 98; ny = 8;  rem = bid; }
    else if (bid < 4736) { in = c3; out = t1; C = 512;  P = 784;  nx = 25; ny = 16; rem = bid - 3136; }
    else if (bid < 5632) { in = c4; out = t2; C = 1024; P = 196;  nx = 7;  ny = 32; rem = bid - 4736; }
    else                 { in = c5; out = t3; C = 2048; P = 49;   nx = 2;  ny = 64; rem = bid - 5632; }
    int x = rem % nx; int tq = rem / nx; int y = tq % ny; int b = tq / ny;
    int p0 = x * 32, c0 = y * 32;
    int lp = threadIdx.x & 31, lc = threadIdx.x >> 5;
    for (int cc = lc; cc < 32; cc += 8) {
      int c = c0 + cc, p = p0 + lp;
      t[cc][lp] = (c < C && p < P) ? in[((size_t)b*C + c)*P + p] : 0.f;
    }
    __syncthreads();
    for (int pp = lc; pp < 32; pp += 8) {
      int p = p0 + pp, c = c0 + lp;
      if (p < P && c < C) out[((size_t)b*P + p)*C + c] = t[lp][pp];
    }
  } else if (bid < 8610) {
    int wave = threadIdx.x >> 6, lane = threadIdx.x & 63;
    int row = (bid - 6144) * 4 + wave;
    const float* Ar = adj + (size_t)row * N_;
    int* cp = cols + (size_t)row * ELLW;
    unsigned long long below = (lane == 63) ? 0xFFFFFFFFFFFFFFFFull >> 1
                                            : ((1ull << lane) - 1ull);
    int base = 0;
    for (int i0 = 0; i0 < 20; i0++) {
      int j0 = i0 * 128 + lane * 2;
      float2 v = make_float2(0.f, 0.f);
      if (j0 + 1 < N_) v = *(const float2*)&Ar[j0];
      bool nz0 = (j0 < N_) && (v.x != 0.f);
      bool nz1 = (j0 + 1 < N_) && (v.y != 0.f);
      unsigned long long m0 = __ballot(nz0);
      unsigned long long m1 = __ballot(nz1);
      int pre = __popcll(m0 & below) + __popcll(m1 & below);
      int p0 = base + pre;
      int p1 = p0 + (nz0 ? 1 : 0);
      if (nz0 && p0 < ELLW) cp[p0] = j0;
      if (nz1 && p1 < ELLW) cp[p1] = j0 + 1;
      base += __popcll(m0) + __popcll(m1);
    }
    if (lane == 0) cnts[row] = (base > ELLW) ? ELLW : base;
  } else if (bid < 9090) {
    // lin_w -> bf16 hi/lo fragments (491520 elems)
    int b = bid - 8610;
    int e0 = (b * 256 + threadIdx.x) * 4;
    #pragma unroll
    for (int u = 0; u < 4; u++) {
      int e = e0 + u;
      int j = e & 7;
      int lane = (e >> 3) & 63;
      int nt = (e >> 9) & 7;
      int slab = e >> 12;
      int k = slab * 32 + ((lane >> 4) << 3) + j;
      int n = nt * 16 + (lane & 15);
      float x = lin_w[(size_t)k * 128 + n];
      unsigned short h = bf16_rne(x);
      whi[e] = h;
      wlo[e] = bf16_rne(x - bf16_back(h));
    }
  } else {
    // res weights -> bf16 hi/lo fragments (307200 elems, zero-padded past K)
    int b = bid - 9090;                 // 0..299
    int e0 = (b * 256 + threadIdx.x) * 4;
    #pragma unroll
    for (int u = 0; u < 4; u++) {
      int e = e0 + u;
      int rb, mat, rem, K;
      if (e < 143360) {
        rb = 0;
        if (e < 110592) { mat = e / 36864; rem = e - mat * 36864; K = 259; }
        else { int tt = e - 110592; mat = 3 + tt / 16384; rem = tt & 16383; K = 128; }
      } else {
        int tt = e - 143360;
        rb = 1 + tt / 81920;
        int r2 = tt % 81920;
        mat = r2 / 16384; rem = r2 & 16383; K = 128;
      }
      int j = rem & 7, lane = (rem >> 3) & 63, nt = (rem >> 9) & 7, slab = rem >> 12;
      int k = slab * 32 + ((lane >> 4) << 3) + j;
      int n = nt * 16 + (lane & 15);
      float x = (k < K) ? wm.p[rb * 5 + mat][(size_t)k * 128 + n] : 0.f;
      unsigned short h = bf16_rne(x);
      wrh[e] = h;
      wrl[e] = bf16_rne(x - bf16_back(h));
    }
  }
}

// ============ split-K vertex-align gather + bf16x3 MFMA GEMM (R10-proven body) ============
__global__ __launch_bounds__(512) void k_align_mfma(
    const float* __restrict__ tr0, const float* __restrict__ tr1,
    const float* __restrict__ tr2, const float* __restrict__ tr3,
    const float* __restrict__ pos,
    const unsigned short* __restrict__ whi, const unsigned short* __restrict__ wlo,
    float* __restrict__ part, int kchunk) {
  int tid  = threadIdx.x;
  int wave = tid >> 6, lane = tid & 63;
  int q    = lane >> 4, l15 = lane & 15;
  int m0   = blockIdx.x * 128;
  int s    = blockIdx.y;
  int mrow = m0 + wave * 16 + l15;

  float wgt[4]; int base[4];
  {
    int rowc = (mrow < R_) ? mrow : 0;
    int b = rowc / N_;
    float px = pos[rowc*3+0], py = pos[rowc*3+1], pz = pos[rowc*3+2];
    float hh = fminf(fmaxf(248.f*(py/pz)    + 111.5f, 0.f), 223.f);
    float wc = fminf(fmaxf(248.f*(px/(-pz)) + 111.5f, 0.f), 223.f);
    const int Sarr[4] = {56, 28, 14, 7};
    const int Carr[4] = {256, 512, 1024, 2048};
    #pragma unroll
    for (int sc = 0; sc < 4; sc++) {
      int S = Sarr[sc], C = Carr[sc];
      float dv = 224.f / (float)S;
      float x = hh / dv, y = wc / dv;
      int x1 = (int)floorf(x), y1 = (int)floorf(y);
      int x2 = min((int)ceilf(x), S - 1), y2 = min((int)ceilf(y), S - 1);
      float w = (float)((x2 - x1) * (y2 - y1));   // xi==x1,yi==y1 -> single tap
      if (mrow >= R_) w = 0.f;
      wgt[sc]  = w;
      base[sc] = (b * S * S + x1 * S + y1) * C;   // NHWC; add channel
    }
  }

  f32x4 acc[8];
  #pragma unroll
  for (int nt = 0; nt < 8; nt++) acc[nt] = (f32x4){0.f, 0.f, 0.f, 0.f};

  const bf16x8* BH = (const bf16x8*)whi;
  const bf16x8* BL = (const bf16x8*)wlo;

  int kbeg = s * kchunk, kend = kbeg + kchunk;
  #pragma unroll 1
  for (int k0 = kbeg; k0 < kend; k0 += 32) {
    const float* tr; int off, sI;
    if (k0 < 256)       { tr = tr0; off = 0;    sI = 0; }
    else if (k0 < 768)  { tr = tr1; off = 256;  sI = 1; }
    else if (k0 < 1792) { tr = tr2; off = 768;  sI = 2; }
    else                { tr = tr3; off = 1792; sI = 3; }

    const float* src = tr + base[sI] + (k0 - off + q * 8);
    float4 a0 = *(const float4*)src;
    float4 a1 = *(const float4*)(src + 4);
    float wg = wgt[sI];
    float af[8] = {a0.x*wg, a0.y*wg, a0.z*wg, a0.w*wg,
                   a1.x*wg, a1.y*wg, a1.z*wg, a1.w*wg};
    bf16x8 ahi, alo;
    #pragma unroll
    for (int j = 0; j < 8; j++) {
      unsigned short h = bf16_rne(af[j]);
      ahi[j] = (short)h;
      alo[j] = (short)bf16_rne(af[j] - bf16_back(h));
    }

    int slab = k0 >> 5;
    bf16x8 Bh[8], Bl[8];
    #pragma unroll
    for (int nt = 0; nt < 8; nt++) {
      size_t fi = (size_t)(slab * 8 + nt) * 64 + lane;
      Bh[nt] = BH[fi];
      Bl[nt] = BL[fi];
    }
    #pragma unroll
    for (int nt = 0; nt < 8; nt++)
      acc[nt] = __builtin_amdgcn_mfma_f32_16x16x32_bf16(ahi, Bh[nt], acc[nt], 0, 0, 0);
    #pragma unroll
    for (int nt = 0; nt < 8; nt++)
      acc[nt] = __builtin_amdgcn_mfma_f32_16x16x32_bf16(alo, Bh[nt], acc[nt], 0, 0, 0);
    #pragma unroll
    for (int nt = 0; nt < 8; nt++)
      acc[nt] = __builtin_amdgcn_mfma_f32_16x16x32_bf16(ahi, Bl[nt], acc[nt], 0, 0, 0);
  }

  // C/D layout: col = lane&15, row_in_tile = q*4 + reg
  #pragma unroll
  for (int nt = 0; nt < 8; nt++)
    #pragma unroll
    for (int r = 0; r < 4; r++) {
      int row = m0 + wave * 16 + q * 4 + r;
      if (row < R_)
        part[((size_t)s * R_ + row) * 128 + nt * 16 + l15] = acc[nt][r];
    }
}

// ============ fused X-build (once, in LDS) + bf16x3 MFMA GEMM over NW weight matrices ============
// MODE 0: X = [reduce(part)+lin_b | vf | pos | 0] (K=288, SLABS=9)
// MODE 1: X = relu(s + A@t)                       (K=128, SLABS=4)
// MODE 2: X = skip + relu(s + A@t)                (K=128, SLABS=4)
// Block = 32 rows; NW*2 waves: wave w -> which=w>>1, mtile=w&1 (16 rows each).
// X-build is done ONCE per row (no which-redundancy — the R9 fusion flaw).
// LDS stride ≡ 4 (mod 32) -> frag b128 reads are 2-way bank aliased = free (m136).
template<int MODE, int SLABS, int NW>
__global__ __launch_bounds__(NW == 3 ? 384 : 256) void k_fgemm(
    const float* __restrict__ part, const float* __restrict__ lin_b,
    const float* __restrict__ vf, const float* __restrict__ pos,
    const float* __restrict__ sin_, const float* __restrict__ tin,
    const float* __restrict__ skin,
    const int* __restrict__ cols, const int* __restrict__ cnts,
    const unsigned short* __restrict__ wh, const unsigned short* __restrict__ wl,
    int matStride, const float* __restrict__ pb,
    float* __restrict__ o0, float* __restrict__ o1, float* __restrict__ o2,
    int nsplit) {
  constexpr int LDX  = SLABS * 32 + 4;        // 292 / 132
  constexpr int NGRP = (NW == 3) ? 12 : 8;    // 32-lane groups in block
  __shared__ alignas(16) float X[32][LDX];
  int tid = threadIdx.x;
  int m0 = blockIdx.x * 32;
  int grp = tid >> 5, ln = tid & 31;

  if (MODE == 0) {
    #pragma unroll 1
    for (int r = grp; r < 32; r += NGRP) {
      int row = m0 + r;
      #pragma unroll 1
      for (int c4 = ln; c4 < 72; c4 += 32) {
        float4 v = make_float4(0.f, 0.f, 0.f, 0.f);
        if (row < R_) {
          if (c4 < 32) {
            v = ((const float4*)lin_b)[c4];
            for (int ss = 0; ss < nsplit; ss++) {
              float4 pv = ((const float4*)part)[((size_t)ss * R_ + row) * 32 + c4];
              v.x += pv.x; v.y += pv.y; v.z += pv.z; v.w += pv.w;
            }
          } else if (c4 < 64) {
            v = ((const float4*)vf)[(size_t)row * 32 + (c4 - 32)];
          } else {
            int cb = (c4 - 64) * 4;   // offset past col 256
            v.x = (cb + 0 < 3) ? pos[(size_t)row * 3 + cb + 0] : 0.f;
            v.y = (cb + 1 < 3) ? pos[(size_t)row * 3 + cb + 1] : 0.f;
            v.z = (cb + 2 < 3) ? pos[(size_t)row * 3 + cb + 2] : 0.f;
            v.w = 0.f;
          }
        }
        *(float4*)&X[r][c4 * 4] = v;
      }
    }
  } else {
    #pragma unroll 1
    for (int r = grp; r < 32; r += NGRP) {
      int row = m0 + r;
      float4 acc = make_float4(0.f, 0.f, 0.f, 0.f);
      if (row < R_) {
        int b = row / N_;
        size_t tbase = (size_t)b * N_;
        acc = ((const float4*)sin_)[(size_t)row * 32 + ln];
        int cnt = cnts[row];
        const int* cp = cols + (size_t)row * ELLW;
        for (int i = 0; i < cnt; i++) {
          float4 vv = ((const float4*)tin)[(tbase + cp[i]) * 32 + ln];
          acc.x += vv.x; acc.y += vv.y; acc.z += vv.z; acc.w += vv.w;
        }
        acc.x = fmaxf(acc.x, 0.f); acc.y = fmaxf(acc.y, 0.f);
        acc.z = fmaxf(acc.z, 0.f); acc.w = fmaxf(acc.w, 0.f);
        if (MODE == 2) {
          float4 sk = ((const float4*)skin)[(size_t)row * 32 + ln];
          acc.x += sk.x; acc.y += sk.y; acc.z += sk.z; acc.w += sk.w;
        }
      }
      *(float4*)&X[r][ln * 4] = acc;
    }
  }
  __syncthreads();

  int wave = tid >> 6, lane = tid & 63;
  int q = lane >> 4, l15 = lane & 15;
  int which = wave >> 1, mtile = wave & 1;

  const bf16x8* BH = (const bf16x8*)(wh + (size_t)which * matStride);
  const bf16x8* BL = (const bf16x8*)(wl + (size_t)which * matStride);

  f32x4 acc[8];
  #pragma unroll
  for (int nt = 0; nt < 8; nt++) acc[nt] = (f32x4){0.f, 0.f, 0.f, 0.f};

  #pragma unroll 1
  for (int slab = 0; slab < SLABS; slab++) {
    const float* src = &X[mtile * 16 + l15][slab * 32 + q * 8];
    float4 a0 = *(const float4*)src;
    float4 a1 = *(const float4*)(src + 4);
    float af[8] = {a0.x, a0.y, a0.z, a0.w, a1.x, a1.y, a1.z, a1.w};
    bf16x8 ahi, alo;
    #pragma unroll
    for (int j = 0; j < 8; j++) {
      unsigned short h = bf16_rne(af[j]);
      ahi[j] = (short)h;
      alo[j] = (short)bf16_rne(af[j] - bf16_back(h));
    }
    bf16x8 Bh[8], Bl[8];
    #pragma unroll
    for (int nt = 0; nt < 8; nt++) {
      size_t fi = (size_t)(slab * 8 + nt) * 64 + lane;
      Bh[nt] = BH[fi];
      Bl[nt] = BL[fi];
    }
    #pragma unroll
    for (int nt = 0; nt < 8; nt++)
      acc[nt] = __builtin_amdgcn_mfma_f32_16x16x32_bf16(ahi, Bh[nt], acc[nt], 0, 0, 0);
    #pragma unroll
    for (int nt = 0; nt < 8; nt++)
      acc[nt] = __builtin_amdgcn_mfma_f32_16x16x32_bf16(alo, Bh[nt], acc[nt], 0, 0, 0);
    #pragma unroll
    for (int nt = 0; nt < 8; nt++)
      acc[nt] = __builtin_amdgcn_mfma_f32_16x16x32_bf16(ahi, Bl[nt], acc[nt], 0, 0, 0);
  }

  float* out = (which == 0) ? o0 : (which == 1) ? o1 : o2;
  #pragma unroll
  for (int nt = 0; nt < 8; nt++) {
    int col = nt * 16 + l15;
    float bias = (NW == 3 && which == 2 && pb != nullptr) ? pb[col] : 0.f;
    #pragma unroll
    for (int r = 0; r < 4; r++) {
      int row = m0 + mtile * 16 + q * 4 + r;
      if (row < R_) out[(size_t)row * 128 + col] = acc[nt][r] + bias;
    }
  }
}

// ---------------- last spmm2 + fused 128->3 GEMV (both gf weights) ----------------
__global__ __launch_bounds__(256) void k_spmm_gf(
    const float* __restrict__ u, const float* __restrict__ v,
    const int* __restrict__ cols, const int* __restrict__ cnts,
    const float* __restrict__ skipb,
    const float* __restrict__ gw0, const float* __restrict__ gw1,
    float* __restrict__ gsb, float* __restrict__ gtb) {
  int tid = threadIdx.x;
  int grp = tid >> 5, ln = tid & 31;
  int row = blockIdx.x * 8 + grp;           // 1233*8 = 9864
  int b = row / N_;
  size_t tbase = (size_t)b * N_;
  float4 acc = ((const float4*)u)[(size_t)row*32 + ln];
  int cnt = cnts[row];
  const int* cp = cols + (size_t)row * ELLW;
  for (int i = 0; i < cnt; i++) {
    float4 vv = ((const float4*)v)[(tbase + cp[i])*32 + ln];
    acc.x += vv.x; acc.y += vv.y; acc.z += vv.z; acc.w += vv.w;
  }
  acc.x = fmaxf(acc.x, 0.f); acc.y = fmaxf(acc.y, 0.f);
  acc.z = fmaxf(acc.z, 0.f); acc.w = fmaxf(acc.w, 0.f);
  float4 sk = ((const float4*)skipb)[(size_t)row*32 + ln];
  acc.x += sk.x; acc.y += sk.y; acc.z += sk.z; acc.w += sk.w;
  float av[4] = {acc.x, acc.y, acc.z, acc.w};
  int j0 = ln * 4;
  float p0 = 0.f, p1 = 0.f, p2 = 0.f, q0 = 0.f, q1 = 0.f, q2 = 0.f;
  #pragma unroll
  for (int uu = 0; uu < 4; uu++) {
    int j = j0 + uu;
    p0 += av[uu] * gw0[j*3+0]; p1 += av[uu] * gw0[j*3+1]; p2 += av[uu] * gw0[j*3+2];
    q0 += av[uu] * gw1[j*3+0]; q1 += av[uu] * gw1[j*3+1]; q2 += av[uu] * gw1[j*3+2];
  }
  #pragma unroll
  for (int off = 16; off >= 1; off >>= 1) {
    p0 += __shfl_xor(p0, off); p1 += __shfl_xor(p1, off); p2 += __shfl_xor(p2, off);
    q0 += __shfl_xor(q0, off); q1 += __shfl_xor(q1, off); q2 += __shfl_xor(q2, off);
  }
  if (ln == 0) {
    gsb[(size_t)row*128 + 0] = p0; gsb[(size_t)row*128 + 1] = p1; gsb[(size_t)row*128 + 2] = p2;
    gtb[(size_t)row*128 + 0] = q0; gtb[(size_t)row*128 + 1] = q1; gtb[(size_t)row*128 + 2] = q2;
  }
}

// ---------------- final: out = pos + tanh(relu(s + A@t)) ----------------
__global__ __launch_bounds__(256) void k_gf_final(
    const float* __restrict__ sb, const float* __restrict__ tb,
    const int* __restrict__ cols, const int* __restrict__ cnts,
    const float* __restrict__ pos, float* __restrict__ out) {
  int wave = threadIdx.x >> 6, lane = threadIdx.x & 63;
  int row = blockIdx.x * 4 + wave;          // grid 2466
  if (lane >= 3) return;
  int b = row / N_;
  float acc = sb[(size_t)row*128 + lane];
  int cnt = cnts[row];
  const int* cp = cols + (size_t)row * ELLW;
  size_t tbase = (size_t)b * N_;
  for (int i = 0; i < cnt; i++)
    acc += tb[(tbase + cp[i])*128 + lane];
  float v = tanhf(fmaxf(acc, 0.f));
  out[(size_t)row*3 + lane] = pos[(size_t)row*3 + lane] + v;
}

extern "C" void kernel_launch(void* const* d_in, const int* in_sizes, int n_in,
                              void* d_out, int out_size, void* d_ws, size_t ws_size,
                              hipStream_t stream) {
  const float* conv2_3 = (const float*)d_in[0];
  const float* conv3_4 = (const float*)d_in[1];
  const float* conv4_6 = (const float*)d_in[2];
  const float* conv5_3 = (const float*)d_in[3];
  const float* pos     = (const float*)d_in[4];
  const float* vf      = (const float*)d_in[5];
  const float* adj     = (const float*)d_in[6];
  const float* lin_w   = (const float*)d_in[7];
  const float* lin_b   = (const float*)d_in[8];
  const float* r_pb[3]  = {(const float*)d_in[10], (const float*)d_in[16], (const float*)d_in[22]};
  const float* gf_w0 = (const float*)d_in[27];
  const float* gf_w1 = (const float*)d_in[28];
  float* out = (float*)d_out;

  // ---- workspace layout (float slots) ----
  const size_t TR_TOT  = (size_t)4*(256*3136 + 512*784 + 1024*196 + 2048*49); // 6,021,120
  const size_t ROWF    = (size_t)R_ * 128;                                    // 1,262,592
  const size_t LINW_E  = 491520;                                              // shorts per array
  const size_t RESW_E  = 307200;                                              // shorts per array

  float* ws  = (float*)d_ws;
  float* tr0 = ws;
  float* tr1 = tr0 + (size_t)4*256*3136;
  float* tr2 = tr1 + (size_t)4*512*784;
  float* tr3 = tr2 + (size_t)4*1024*196;
  int*   ell_cnt  = (int*)(tr3 + (size_t)4*2048*49);
  int*   ell_cols = ell_cnt + R_;
  unsigned short* whi = (unsigned short*)(ell_cols + (size_t)R_*ELLW);
  unsigned short* wlo = whi + LINW_E;
  unsigned short* wrh = wlo + LINW_E;
  unsigned short* wrl = wrh + RESW_E;
  float* part = (float*)(wrl + RESW_E);

  size_t fixed_f = TR_TOT + (size_t)R_*(ELLW+1) + LINW_E + RESW_E;
  size_t need8 = (fixed_f + (size_t)8*ROWF + 5*ROWF) * sizeof(float);
  int nsplit = (ws_size >= need8) ? 8 : 4;
  int kchunk = 3840 / nsplit;

  float* s_   = part + (size_t)nsplit * ROWF;
  float* t_   = s_   + ROWF;
  float* skip = t_   + ROWF;
  float* u_   = skip + ROWF;
  float* v_   = u_   + ROWF;
  float* gsb  = part;            // part is dead after k_fgemm<0>
  float* gtb  = part + ROWF;

  WMats wm;
  for (int rb = 0; rb < 3; rb++) {
    wm.p[rb*5 + 0] = (const float*)d_in[11 + 6*rb];  // w00
    wm.p[rb*5 + 1] = (const float*)d_in[12 + 6*rb];  // w01
    wm.p[rb*5 + 2] = (const float*)d_in[9  + 6*rb];  // pw
    wm.p[rb*5 + 3] = (const float*)d_in[13 + 6*rb];  // w10
    wm.p[rb*5 + 4] = (const float*)d_in[14 + 6*rb];  // w11
  }
  const int RB_BASE[3] = {0, 143360, 225280};

  // D0: transposes + ELL + all W splits
  k_pre<<<9390, 256, 0, stream>>>(conv2_3, conv3_4, conv4_6, conv5_3,
                                  tr0, tr1, tr2, tr3,
                                  adj, ell_cols, ell_cnt,
                                  lin_w, whi, wlo, wm, wrh, wrl);

  // D1: split-K MFMA align GEMM
  k_align_mfma<<<dim3(78, nsplit), 512, 0, stream>>>(tr0, tr1, tr2, tr3, pos,
                                                     whi, wlo, part, kchunk);

  // D2: fused [reduce+concat -> gemm3 {w00,w01,pw}+pb] => s,t,skip
  k_fgemm<0, 9, 3><<<309, 384, 0, stream>>>(
      part, lin_b, vf, pos, nullptr, nullptr, nullptr, nullptr, nullptr,
      wrh + RB_BASE[0], wrl + RB_BASE[0], 36864, r_pb[0], s_, t_, skip, nsplit);

  for (int rb = 0; rb < 3; rb++) {
    // fused [spmm -> gemm2 {w10,w11}] => u,v
    int g2off = RB_BASE[rb] + ((rb == 0) ? 110592 : 3 * 16384);
    k_fgemm<1, 4, 2><<<309, 256, 0, stream>>>(
        nullptr, nullptr, nullptr, nullptr, s_, t_, nullptr, ell_cols, ell_cnt,
        wrh + g2off, wrl + g2off, 16384, nullptr, u_, v_, nullptr, 0);
    if (rb < 2) {
      // fused [spmm2(+skip) -> gemm3 {w00',w01',pw'}+pb'] => s,t,skip
      k_fgemm<2, 4, 3><<<309, 384, 0, stream>>>(
          nullptr, nullptr, nullptr, nullptr, u_, v_, skip, ell_cols, ell_cnt,
          wrh + RB_BASE[rb+1], wrl + RB_BASE[rb+1], 16384, r_pb[rb+1], s_, t_, skip, 0);
    } else {
      // spmm2(+skip) + fused 128->3 gemv => gsb,gtb
      k_spmm_gf<<<1233, 256, 0, stream>>>(u_, v_, ell_cols, ell_cnt, skip,
                                          gf_w0, gf_w1, gsb, gtb);
    }
  }

  // final: out = pos + tanh(relu(gsb + A@gtb))
  k_gf_final<<<2466, 256, 0, stream>>>(gsb, gtb, ell_cols, ell_cnt, pos, out);
}

// Round 14
// 515.611 us; speedup vs baseline: 1.0212x; 1.0212x over previous
//
#include <hip/hip_runtime.h>
#include <cmath>

#define B_   4
#define N_   2466
#define R_   (B_*N_)     // 9864
#define ELLW 96

typedef __attribute__((ext_vector_type(8))) short bf16x8;
typedef __attribute__((ext_vector_type(4))) float f32x4;

__device__ __forceinline__ unsigned short bf16_rne(float x) {
  union { float f; unsigned u; } c; c.f = x;
  unsigned r = c.u + 0x7FFFu + ((c.u >> 16) & 1u);
  return (unsigned short)(r >> 16);
}
__device__ __forceinline__ float bf16_back(unsigned short h) {
  union { float f; unsigned u; } c; c.u = ((unsigned)h) << 16;
  return c.f;
}

struct WMats { const float* p[15]; };   // rb-major: w00,w01,pw,w10,w11

// Fragment-order layout (lin_w and res weights):
// e = ((slab*8 + nt)*64 + lane)*8 + j ; k = slab*32 + (lane>>4)*8 + j ; n = nt*16 + (lane&15)

// ============ fused pre-kernel: transposes + ELL + all W hi/lo fragment splits ============
__global__ __launch_bounds__(256) void k_pre(
    const float* __restrict__ c2, const float* __restrict__ c3,
    const float* __restrict__ c4, const float* __restrict__ c5,
    float* __restrict__ t0, float* __restrict__ t1,
    float* __restrict__ t2, float* __restrict__ t3,
    const float* __restrict__ adj, int* __restrict__ cols, int* __restrict__ cnts,
    const float* __restrict__ lin_w,
    unsigned short* __restrict__ whi, unsigned short* __restrict__ wlo,
    WMats wm,
    unsigned short* __restrict__ wrh, unsigned short* __restrict__ wrl) {
  __shared__ float t[32][33];
  int bid = blockIdx.x;
  if (bid < 6144) {
    const float* in; float* out; int C, P, nx, ny, rem;
    if (bid < 3136)      { in = c2; out = t0; C = 256;  P = 3136; nx = 98; ny = 8;  rem = bid; }
    else if (bid < 4736) { in = c3; out = t1; C = 512;  P = 784;  nx = 25; ny = 16; rem = bid - 3136; }
    else if (bid < 5632) { in = c4; out = t2; C = 1024; P = 196;  nx = 7;  ny = 32; rem = bid - 4736; }
    else                 { in = c5; out = t3; C = 2048; P = 49;   nx = 2;  ny = 64; rem = bid - 5632; }
    int x = rem % nx; int tq = rem / nx; int y = tq % ny; int b = tq / ny;
    int p0 = x * 32, c0 = y * 32;
    int lp = threadIdx.x & 31, lc = threadIdx.x >> 5;
    for (int cc = lc; cc < 32; cc += 8) {
      int c = c0 + cc, p = p0 + lp;
      t[cc][lp] = (c < C && p < P) ? in[((size_t)b*C + c)*P + p] : 0.f;
    }
    __syncthreads();
    for (int pp = lc; pp < 32; pp += 8) {
      int p = p0 + pp, c = c0 + lp;
      if (p < P && c < C) out[((size_t)b*P + p)*C + c] = t[lp][pp];
    }
  } else if (bid < 8610) {
    int wave = threadIdx.x >> 6, lane = threadIdx.x & 63;
    int row = (bid - 6144) * 4 + wave;
    const float* Ar = adj + (size_t)row * N_;
    int* cp = cols + (size_t)row * ELLW;
    unsigned long long below = (lane == 63) ? 0xFFFFFFFFFFFFFFFFull >> 1
                                            : ((1ull << lane) - 1ull);
    int base = 0;
    for (int i0 = 0; i0 < 20; i0++) {
      int j0 = i0 * 128 + lane * 2;
      float2 v = make_float2(0.f, 0.f);
      if (j0 + 1 < N_) v = *(const float2*)&Ar[j0];
      bool nz0 = (j0 < N_) && (v.x != 0.f);
      bool nz1 = (j0 + 1 < N_) && (v.y != 0.f);
      unsigned long long m0 = __ballot(nz0);
      unsigned long long m1 = __ballot(nz1);
      int pre = __popcll(m0 & below) + __popcll(m1 & below);
      int p0 = base + pre;
      int p1 = p0 + (nz0 ? 1 : 0);
      if (nz0 && p0 < ELLW) cp[p0] = j0;
      if (nz1 && p1 < ELLW) cp[p1] = j0 + 1;
      base += __popcll(m0) + __popcll(m1);
    }
    if (lane == 0) cnts[row] = (base > ELLW) ? ELLW : base;
  } else if (bid < 9090) {
    // lin_w -> bf16 hi/lo fragments (491520 elems)
    int b = bid - 8610;
    int e0 = (b * 256 + threadIdx.x) * 4;
    #pragma unroll
    for (int u = 0; u < 4; u++) {
      int e = e0 + u;
      int j = e & 7;
      int lane = (e >> 3) & 63;
      int nt = (e >> 9) & 7;
      int slab = e >> 12;
      int k = slab * 32 + ((lane >> 4) << 3) + j;
      int n = nt * 16 + (lane & 15);
      float x = lin_w[(size_t)k * 128 + n];
      unsigned short h = bf16_rne(x);
      whi[e] = h;
      wlo[e] = bf16_rne(x - bf16_back(h));
    }
  } else {
    // res weights -> bf16 hi/lo fragments (307200 elems, zero-padded past K)
    int b = bid - 9090;                 // 0..299
    int e0 = (b * 256 + threadIdx.x) * 4;
    #pragma unroll
    for (int u = 0; u < 4; u++) {
      int e = e0 + u;
      int rb, mat, rem, K;
      if (e < 143360) {
        rb = 0;
        if (e < 110592) { mat = e / 36864; rem = e - mat * 36864; K = 259; }
        else { int tt = e - 110592; mat = 3 + tt / 16384; rem = tt & 16383; K = 128; }
      } else {
        int tt = e - 143360;
        rb = 1 + tt / 81920;
        int r2 = tt % 81920;
        mat = r2 / 16384; rem = r2 & 16383; K = 128;
      }
      int j = rem & 7, lane = (rem >> 3) & 63, nt = (rem >> 9) & 7, slab = rem >> 12;
      int k = slab * 32 + ((lane >> 4) << 3) + j;
      int n = nt * 16 + (lane & 15);
      float x = (k < K) ? wm.p[rb * 5 + mat][(size_t)k * 128 + n] : 0.f;
      unsigned short h = bf16_rne(x);
      wrh[e] = h;
      wrl[e] = bf16_rne(x - bf16_back(h));
    }
  }
}

// ============ split-K vertex-align gather + bf16x3 MFMA GEMM (R10-proven body) ============
// 512-thread blocks: 8 waves, each wave owns one 16-row m-tile -> M=128/block.
// NOTE: A-prefetch (R11) and fused variants (R9/R13) all regressed; keep plain.
__global__ __launch_bounds__(512) void k_align_mfma(
    const float* __restrict__ tr0, const float* __restrict__ tr1,
    const float* __restrict__ tr2, const float* __restrict__ tr3,
    const float* __restrict__ pos,
    const unsigned short* __restrict__ whi, const unsigned short* __restrict__ wlo,
    float* __restrict__ part, int kchunk) {
  int tid  = threadIdx.x;
  int wave = tid >> 6, lane = tid & 63;
  int q    = lane >> 4, l15 = lane & 15;
  int m0   = blockIdx.x * 128;
  int s    = blockIdx.y;
  int mrow = m0 + wave * 16 + l15;

  float wgt[4]; int base[4];
  {
    int rowc = (mrow < R_) ? mrow : 0;
    int b = rowc / N_;
    float px = pos[rowc*3+0], py = pos[rowc*3+1], pz = pos[rowc*3+2];
    float hh = fminf(fmaxf(248.f*(py/pz)    + 111.5f, 0.f), 223.f);
    float wc = fminf(fmaxf(248.f*(px/(-pz)) + 111.5f, 0.f), 223.f);
    const int Sarr[4] = {56, 28, 14, 7};
    const int Carr[4] = {256, 512, 1024, 2048};
    #pragma unroll
    for (int sc = 0; sc < 4; sc++) {
      int S = Sarr[sc], C = Carr[sc];
      float dv = 224.f / (float)S;
      float x = hh / dv, y = wc / dv;
      int x1 = (int)floorf(x), y1 = (int)floorf(y);
      int x2 = min((int)ceilf(x), S - 1), y2 = min((int)ceilf(y), S - 1);
      float w = (float)((x2 - x1) * (y2 - y1));   // xi==x1,yi==y1 -> single tap
      if (mrow >= R_) w = 0.f;
      wgt[sc]  = w;
      base[sc] = (b * S * S + x1 * S + y1) * C;   // NHWC; add channel
    }
  }

  f32x4 acc[8];
  #pragma unroll
  for (int nt = 0; nt < 8; nt++) acc[nt] = (f32x4){0.f, 0.f, 0.f, 0.f};

  const bf16x8* BH = (const bf16x8*)whi;
  const bf16x8* BL = (const bf16x8*)wlo;

  int kbeg = s * kchunk, kend = kbeg + kchunk;
  #pragma unroll 1
  for (int k0 = kbeg; k0 < kend; k0 += 32) {
    const float* tr; int off, sI;
    if (k0 < 256)       { tr = tr0; off = 0;    sI = 0; }
    else if (k0 < 768)  { tr = tr1; off = 256;  sI = 1; }
    else if (k0 < 1792) { tr = tr2; off = 768;  sI = 2; }
    else                { tr = tr3; off = 1792; sI = 3; }

    const float* src = tr + base[sI] + (k0 - off + q * 8);
    float4 a0 = *(const float4*)src;
    float4 a1 = *(const float4*)(src + 4);
    float wg = wgt[sI];
    float af[8] = {a0.x*wg, a0.y*wg, a0.z*wg, a0.w*wg,
                   a1.x*wg, a1.y*wg, a1.z*wg, a1.w*wg};
    bf16x8 ahi, alo;
    #pragma unroll
    for (int j = 0; j < 8; j++) {
      unsigned short h = bf16_rne(af[j]);
      ahi[j] = (short)h;
      alo[j] = (short)bf16_rne(af[j] - bf16_back(h));
    }

    int slab = k0 >> 5;
    bf16x8 Bh[8], Bl[8];
    #pragma unroll
    for (int nt = 0; nt < 8; nt++) {
      size_t fi = (size_t)(slab * 8 + nt) * 64 + lane;
      Bh[nt] = BH[fi];
      Bl[nt] = BL[fi];
    }
    // hi*hi + lo*hi + hi*lo (lo*lo dropped)
    #pragma unroll
    for (int nt = 0; nt < 8; nt++)
      acc[nt] = __builtin_amdgcn_mfma_f32_16x16x32_bf16(ahi, Bh[nt], acc[nt], 0, 0, 0);
    #pragma unroll
    for (int nt = 0; nt < 8; nt++)
      acc[nt] = __builtin_amdgcn_mfma_f32_16x16x32_bf16(alo, Bh[nt], acc[nt], 0, 0, 0);
    #pragma unroll
    for (int nt = 0; nt < 8; nt++)
      acc[nt] = __builtin_amdgcn_mfma_f32_16x16x32_bf16(ahi, Bl[nt], acc[nt], 0, 0, 0);
  }

  // C/D layout: col = lane&15, row_in_tile = q*4 + reg
  #pragma unroll
  for (int nt = 0; nt < 8; nt++)
    #pragma unroll
    for (int r = 0; r < 4; r++) {
      int row = m0 + wave * 16 + q * 4 + r;
      if (row < R_)
        part[((size_t)s * R_ + row) * 128 + nt * 16 + l15] = acc[nt][r];
    }
}

// ---------------- reduce partials + bias, build xcat (proj|vf|pos|0pad), stride 288 ----------------
__global__ __launch_bounds__(256) void k_reduce(
    const float* __restrict__ part, const float* __restrict__ lin_b,
    const float* __restrict__ vf, const float* __restrict__ pos,
    float* __restrict__ xcat, int nsplit) {
  int row = blockIdx.x * 2 + (threadIdx.x >> 7);
  int k = threadIdx.x & 127;
  float acc = lin_b[k];
  for (int s = 0; s < nsplit; s++)
    acc += part[((size_t)s*R_ + row)*128 + k];
  xcat[(size_t)row*288 + k]       = acc;
  xcat[(size_t)row*288 + 128 + k] = vf[(size_t)row*128 + k];
  if (k < 32) xcat[(size_t)row*288 + 256 + k] = (k < 3) ? pos[(size_t)row*3 + k] : 0.f;
}

// ============ bf16x3 MFMA GEMM: out[which] = X @ W[which] (+pb for which==2) ============
// M=64/block (4 waves x 16-row m-tiles), N=128, W pre-split in fragment order.
template<int SLABS>
__global__ __launch_bounds__(256) void k_gemm_mfma(
    const float* __restrict__ X, int ldx,
    const unsigned short* __restrict__ wh, const unsigned short* __restrict__ wl,
    int matStride, const float* __restrict__ pb,
    float* __restrict__ o0, float* __restrict__ o1, float* __restrict__ o2) {
  int tid = threadIdx.x;
  int wave = tid >> 6, lane = tid & 63;
  int q = lane >> 4, l15 = lane & 15;
  int which = blockIdx.y;
  int m0 = blockIdx.x * 64;
  int mrow = m0 + wave * 16 + l15;
  int rowc = (mrow < R_) ? mrow : (R_ - 1);
  const float* xrow = X + (size_t)rowc * ldx + q * 8;

  const bf16x8* BH = (const bf16x8*)(wh + (size_t)which * matStride);
  const bf16x8* BL = (const bf16x8*)(wl + (size_t)which * matStride);

  f32x4 acc[8];
  #pragma unroll
  for (int nt = 0; nt < 8; nt++) acc[nt] = (f32x4){0.f, 0.f, 0.f, 0.f};

  #pragma unroll 1
  for (int slab = 0; slab < SLABS; slab++) {
    const float* src = xrow + slab * 32;
    float4 a0 = *(const float4*)src;
    float4 a1 = *(const float4*)(src + 4);
    float af[8] = {a0.x, a0.y, a0.z, a0.w, a1.x, a1.y, a1.z, a1.w};
    bf16x8 ahi, alo;
    #pragma unroll
    for (int j = 0; j < 8; j++) {
      unsigned short h = bf16_rne(af[j]);
      ahi[j] = (short)h;
      alo[j] = (short)bf16_rne(af[j] - bf16_back(h));
    }
    bf16x8 Bh[8], Bl[8];
    #pragma unroll
    for (int nt = 0; nt < 8; nt++) {
      size_t fi = (size_t)(slab * 8 + nt) * 64 + lane;
      Bh[nt] = BH[fi];
      Bl[nt] = BL[fi];
    }
    #pragma unroll
    for (int nt = 0; nt < 8; nt++)
      acc[nt] = __builtin_amdgcn_mfma_f32_16x16x32_bf16(ahi, Bh[nt], acc[nt], 0, 0, 0);
    #pragma unroll
    for (int nt = 0; nt < 8; nt++)
      acc[nt] = __builtin_amdgcn_mfma_f32_16x16x32_bf16(alo, Bh[nt], acc[nt], 0, 0, 0);
    #pragma unroll
    for (int nt = 0; nt < 8; nt++)
      acc[nt] = __builtin_amdgcn_mfma_f32_16x16x32_bf16(ahi, Bl[nt], acc[nt], 0, 0, 0);
  }

  float* out = (which == 0) ? o0 : (which == 1) ? o1 : o2;
  #pragma unroll
  for (int nt = 0; nt < 8; nt++) {
    int col = nt * 16 + l15;
    float bias = (pb != nullptr && which == 2) ? pb[col] : 0.f;
    #pragma unroll
    for (int r = 0; r < 4; r++) {
      int row = m0 + wave * 16 + q * 4 + r;
      if (row < R_) out[(size_t)row * 128 + col] = acc[nt][r] + bias;
    }
  }
}

// ---------------- SpMM: out = [skip +] relu(s + A@t); optional fused 128->3 GEMV ----------------
__global__ __launch_bounds__(256) void k_spmm(
    const float* __restrict__ sb, const float* __restrict__ tb,
    const int* __restrict__ cols, const int* __restrict__ cnts,
    const float* __restrict__ skipb, float* __restrict__ outb,
    const float* __restrict__ gw0, const float* __restrict__ gw1,
    float* __restrict__ gsb, float* __restrict__ gtb, int fuse_gf) {
  int tid = threadIdx.x;
  int grp = tid >> 5, ln = tid & 31;
  int row = blockIdx.x * 8 + grp;           // 1233 * 8 = 9864 exact
  int b = row / N_;
  size_t tbase = (size_t)b * N_;
  const float4* sb4 = (const float4*)sb;
  const float4* tb4 = (const float4*)tb;
  float4 acc = sb4[(size_t)row*32 + ln];
  int cnt = cnts[row];
  const int* cp = cols + (size_t)row * ELLW;
  for (int i = 0; i < cnt; i++) {
    int c = cp[i];
    float4 v = tb4[(tbase + c)*32 + ln];
    acc.x += v.x; acc.y += v.y; acc.z += v.z; acc.w += v.w;
  }
  acc.x = fmaxf(acc.x, 0.f); acc.y = fmaxf(acc.y, 0.f);
  acc.z = fmaxf(acc.z, 0.f); acc.w = fmaxf(acc.w, 0.f);
  if (skipb) {
    float4 sv = ((const float4*)skipb)[(size_t)row*32 + ln];
    acc.x += sv.x; acc.y += sv.y; acc.z += sv.z; acc.w += sv.w;
  }
  if (!fuse_gf) {
    ((float4*)outb)[(size_t)row*32 + ln] = acc;
    return;
  }
  // fused final gemv: p[c] = sum_j x[j]*gw0[j][c], q likewise
  float av[4] = {acc.x, acc.y, acc.z, acc.w};
  int j0 = ln * 4;
  float p0 = 0.f, p1 = 0.f, p2 = 0.f, q0 = 0.f, q1 = 0.f, q2 = 0.f;
  #pragma unroll
  for (int u = 0; u < 4; u++) {
    int j = j0 + u;
    p0 += av[u] * gw0[j*3+0]; p1 += av[u] * gw0[j*3+1]; p2 += av[u] * gw0[j*3+2];
    q0 += av[u] * gw1[j*3+0]; q1 += av[u] * gw1[j*3+1]; q2 += av[u] * gw1[j*3+2];
  }
  #pragma unroll
  for (int off = 16; off >= 1; off >>= 1) {
    p0 += __shfl_xor(p0, off); p1 += __shfl_xor(p1, off); p2 += __shfl_xor(p2, off);
    q0 += __shfl_xor(q0, off); q1 += __shfl_xor(q1, off); q2 += __shfl_xor(q2, off);
  }
  if (ln == 0) {
    gsb[(size_t)row*128 + 0] = p0; gsb[(size_t)row*128 + 1] = p1; gsb[(size_t)row*128 + 2] = p2;
    gtb[(size_t)row*128 + 0] = q0; gtb[(size_t)row*128 + 1] = q1; gtb[(size_t)row*128 + 2] = q2;
  }
}

// ---------------- final: out = pos + tanh(relu(s + A@t)) ----------------
__global__ __launch_bounds__(256) void k_gf_final(
    const float* __restrict__ sb, const float* __restrict__ tb,
    const int* __restrict__ cols, const int* __restrict__ cnts,
    const float* __restrict__ pos, float* __restrict__ out) {
  int wave = threadIdx.x >> 6, lane = threadIdx.x & 63;
  int row = blockIdx.x * 4 + wave;          // grid 2466
  if (lane >= 3) return;
  int b = row / N_;
  float acc = sb[(size_t)row*128 + lane];
  int cnt = cnts[row];
  const int* cp = cols + (size_t)row * ELLW;
  size_t tbase = (size_t)b * N_;
  for (int i = 0; i < cnt; i++)
    acc += tb[(tbase + cp[i])*128 + lane];
  float v = tanhf(fmaxf(acc, 0.f));
  out[(size_t)row*3 + lane] = pos[(size_t)row*3 + lane] + v;
}

extern "C" void kernel_launch(void* const* d_in, const int* in_sizes, int n_in,
                              void* d_out, int out_size, void* d_ws, size_t ws_size,
                              hipStream_t stream) {
  const float* conv2_3 = (const float*)d_in[0];
  const float* conv3_4 = (const float*)d_in[1];
  const float* conv4_6 = (const float*)d_in[2];
  const float* conv5_3 = (const float*)d_in[3];
  const float* pos     = (const float*)d_in[4];
  const float* vf      = (const float*)d_in[5];
  const float* adj     = (const float*)d_in[6];
  const float* lin_w   = (const float*)d_in[7];
  const float* lin_b   = (const float*)d_in[8];
  const float* r_pb[3]  = {(const float*)d_in[10], (const float*)d_in[16], (const float*)d_in[22]};
  const float* gf_w0 = (const float*)d_in[27];
  const float* gf_w1 = (const float*)d_in[28];
  float* out = (float*)d_out;

  // ---- workspace layout (float slots) ----
  const size_t TR_TOT  = (size_t)4*(256*3136 + 512*784 + 1024*196 + 2048*49); // 6,021,120
  const size_t ROWF    = (size_t)R_ * 128;                                    // 1,262,592
  const size_t XCAT_F  = (size_t)R_ * 288;                                    // 2,840,832
  const size_t LINW_E  = 491520;                                              // shorts per array
  const size_t RESW_E  = 307200;                                              // shorts per array

  float* ws  = (float*)d_ws;
  float* tr0 = ws;
  float* tr1 = tr0 + (size_t)4*256*3136;
  float* tr2 = tr1 + (size_t)4*512*784;
  float* tr3 = tr2 + (size_t)4*1024*196;
  int*   ell_cnt  = (int*)(tr3 + (size_t)4*2048*49);
  int*   ell_cols = ell_cnt + R_;
  unsigned short* whi = (unsigned short*)(ell_cols + (size_t)R_*ELLW);
  unsigned short* wlo = whi + LINW_E;
  unsigned short* wrh = wlo + LINW_E;
  unsigned short* wrl = wrh + RESW_E;
  float* part = (float*)(wrl + RESW_E);

  size_t fixed_f = TR_TOT + (size_t)R_*(ELLW+1) + LINW_E + RESW_E;
  size_t need8 = (fixed_f + (size_t)8*ROWF + XCAT_F + 5*ROWF) * sizeof(float);
  int nsplit = (ws_size >= need8) ? 8 : 4;
  int kchunk = 3840 / nsplit;

  float* xcat = part + (size_t)nsplit * ROWF;
  float* sb   = xcat + XCAT_F;
  float* tb   = sb   + ROWF;
  float* skip = tb   + ROWF;
  float* hb   = skip + ROWF;
  float* xc   = hb   + ROWF;

  WMats wm;
  for (int rb = 0; rb < 3; rb++) {
    wm.p[rb*5 + 0] = (const float*)d_in[11 + 6*rb];  // w00
    wm.p[rb*5 + 1] = (const float*)d_in[12 + 6*rb];  // w01
    wm.p[rb*5 + 2] = (const float*)d_in[9  + 6*rb];  // pw
    wm.p[rb*5 + 3] = (const float*)d_in[13 + 6*rb];  // w10
    wm.p[rb*5 + 4] = (const float*)d_in[14 + 6*rb];  // w11
  }
  const int RB_BASE[3] = {0, 143360, 225280};

  // D0: transposes + ELL + all W splits
  k_pre<<<9390, 256, 0, stream>>>(conv2_3, conv3_4, conv4_6, conv5_3,
                                  tr0, tr1, tr2, tr3,
                                  adj, ell_cols, ell_cnt,
                                  lin_w, whi, wlo, wm, wrh, wrl);

  // D1: split-K MFMA align GEMM (512-thread blocks, M=128, no prefetch — R10 body)
  k_align_mfma<<<dim3(78, nsplit), 512, 0, stream>>>(tr0, tr1, tr2, tr3, pos,
                                                     whi, wlo, part, kchunk);

  // D2: reduce partials + concat (stride 288, zero-padded)
  k_reduce<<<4932, 256, 0, stream>>>(part, lin_b, vf, pos, xcat, nsplit);

  // D3..: three residual graph-conv blocks, all GEMMs via bf16x3 MFMA
  for (int rb = 0; rb < 3; rb++) {
    if (rb == 0) {
      k_gemm_mfma<9><<<dim3(155, 3), 256, 0, stream>>>(
          xcat, 288, wrh + RB_BASE[0], wrl + RB_BASE[0], 36864, r_pb[0], sb, tb, skip);
    } else {
      k_gemm_mfma<4><<<dim3(155, 3), 256, 0, stream>>>(
          xc, 128, wrh + RB_BASE[rb], wrl + RB_BASE[rb], 16384, r_pb[rb], sb, tb, skip);
    }
    k_spmm<<<1233, 256, 0, stream>>>(sb, tb, ell_cols, ell_cnt, nullptr, hb,
                                     nullptr, nullptr, nullptr, nullptr, 0);
    int g2off = RB_BASE[rb] + ((rb == 0) ? 110592 : 3 * 16384);
    k_gemm_mfma<4><<<dim3(155, 2), 256, 0, stream>>>(
        hb, 128, wrh + g2off, wrl + g2off, 16384, nullptr, sb, tb, nullptr);
    if (rb < 2) {
      k_spmm<<<1233, 256, 0, stream>>>(sb, tb, ell_cols, ell_cnt, skip, xc,
                                       nullptr, nullptr, nullptr, nullptr, 0);
    } else {
      k_spmm<<<1233, 256, 0, stream>>>(sb, tb, ell_cols, ell_cnt, skip, nullptr,
                                       gf_w0, gf_w1, hb, xc, 1);   // gsb=hb, gtb=xc
    }
  }

  // final: out = pos + tanh(relu(gsb + A@gtb))
  k_gf_final<<<2466, 256, 0, stream>>>(hb, xc, ell_cols, ell_cnt, pos, out);
}

// Round 15
// 463.408 us; speedup vs baseline: 1.1362x; 1.1127x over previous
//
#include <hip/hip_runtime.h>
#include <cmath>

#define B_   4
#define N_   2466
#define R_   (B_*N_)     // 9864
#define ELLW 96

typedef _Float16 f16x8 __attribute__((ext_vector_type(8)));
typedef __attribute__((ext_vector_type(4))) float f32x4;

__device__ __forceinline__ unsigned short f16_bits(float x) {
  union { _Float16 h; unsigned short u; } c;
  c.h = (_Float16)x;          // RNE
  return c.u;
}

struct WMats { const float* p[15]; };   // rb-major: w00,w01,pw,w10,w11

// Fragment-order layout (lin_w and res weights), f16 single-precision-pass:
// e = ((slab*8 + nt)*64 + lane)*8 + j ; k = slab*32 + (lane>>4)*8 + j ; n = nt*16 + (lane&15)
// Precision: f16 (e5m10) single-pass, fp32 MFMA accum. eps 2^-11 -> final absmax ~1e-2,
// threshold 8.06e-2. (bf16x3 hi/lo was 3x the MFMA/loads for precision we don't need.)

// ============ fused pre-kernel: transposes + ELL + all W f16 fragment splits ============
__global__ __launch_bounds__(256) void k_pre(
    const float* __restrict__ c2, const float* __restrict__ c3,
    const float* __restrict__ c4, const float* __restrict__ c5,
    float* __restrict__ t0, float* __restrict__ t1,
    float* __restrict__ t2, float* __restrict__ t3,
    const float* __restrict__ adj, int* __restrict__ cols, int* __restrict__ cnts,
    const float* __restrict__ lin_w,
    unsigned short* __restrict__ whf,
    WMats wm,
    unsigned short* __restrict__ wrf) {
  __shared__ float t[32][33];
  int bid = blockIdx.x;
  if (bid < 6144) {
    const float* in; float* out; int C, P, nx, ny, rem;
    if (bid < 3136)      { in = c2; out = t0; C = 256;  P = 3136; nx = 98; ny = 8;  rem = bid; }
    else if (bid < 4736) { in = c3; out = t1; C = 512;  P = 784;  nx = 25; ny = 16; rem = bid - 3136; }
    else if (bid < 5632) { in = c4; out = t2; C = 1024; P = 196;  nx = 7;  ny = 32; rem = bid - 4736; }
    else                 { in = c5; out = t3; C = 2048; P = 49;   nx = 2;  ny = 64; rem = bid - 5632; }
    int x = rem % nx; int tq = rem / nx; int y = tq % ny; int b = tq / ny;
    int p0 = x * 32, c0 = y * 32;
    int lp = threadIdx.x & 31, lc = threadIdx.x >> 5;
    for (int cc = lc; cc < 32; cc += 8) {
      int c = c0 + cc, p = p0 + lp;
      t[cc][lp] = (c < C && p < P) ? in[((size_t)b*C + c)*P + p] : 0.f;
    }
    __syncthreads();
    for (int pp = lc; pp < 32; pp += 8) {
      int p = p0 + pp, c = c0 + lp;
      if (p < P && c < C) out[((size_t)b*P + p)*C + c] = t[lp][pp];
    }
  } else if (bid < 8610) {
    int wave = threadIdx.x >> 6, lane = threadIdx.x & 63;
    int row = (bid - 6144) * 4 + wave;
    const float* Ar = adj + (size_t)row * N_;
    int* cp = cols + (size_t)row * ELLW;
    unsigned long long below = (lane == 63) ? 0xFFFFFFFFFFFFFFFFull >> 1
                                            : ((1ull << lane) - 1ull);
    int base = 0;
    for (int i0 = 0; i0 < 20; i0++) {
      int j0 = i0 * 128 + lane * 2;
      float2 v = make_float2(0.f, 0.f);
      if (j0 + 1 < N_) v = *(const float2*)&Ar[j0];
      bool nz0 = (j0 < N_) && (v.x != 0.f);
      bool nz1 = (j0 + 1 < N_) && (v.y != 0.f);
      unsigned long long m0 = __ballot(nz0);
      unsigned long long m1 = __ballot(nz1);
      int pre = __popcll(m0 & below) + __popcll(m1 & below);
      int p0 = base + pre;
      int p1 = p0 + (nz0 ? 1 : 0);
      if (nz0 && p0 < ELLW) cp[p0] = j0;
      if (nz1 && p1 < ELLW) cp[p1] = j0 + 1;
      base += __popcll(m0) + __popcll(m1);
    }
    if (lane == 0) cnts[row] = (base > ELLW) ? ELLW : base;
  } else if (bid < 9090) {
    // lin_w -> f16 fragments (491520 elems)
    int b = bid - 8610;
    int e0 = (b * 256 + threadIdx.x) * 4;
    #pragma unroll
    for (int u = 0; u < 4; u++) {
      int e = e0 + u;
      int j = e & 7;
      int lane = (e >> 3) & 63;
      int nt = (e >> 9) & 7;
      int slab = e >> 12;
      int k = slab * 32 + ((lane >> 4) << 3) + j;
      int n = nt * 16 + (lane & 15);
      whf[e] = f16_bits(lin_w[(size_t)k * 128 + n]);
    }
  } else {
    // res weights -> f16 fragments (307200 elems, zero-padded past K)
    int b = bid - 9090;                 // 0..299
    int e0 = (b * 256 + threadIdx.x) * 4;
    #pragma unroll
    for (int u = 0; u < 4; u++) {
      int e = e0 + u;
      int rb, mat, rem, K;
      if (e < 143360) {
        rb = 0;
        if (e < 110592) { mat = e / 36864; rem = e - mat * 36864; K = 259; }
        else { int tt = e - 110592; mat = 3 + tt / 16384; rem = tt & 16383; K = 128; }
      } else {
        int tt = e - 143360;
        rb = 1 + tt / 81920;
        int r2 = tt % 81920;
        mat = r2 / 16384; rem = r2 & 16383; K = 128;
      }
      int j = rem & 7, lane = (rem >> 3) & 63, nt = (rem >> 9) & 7, slab = rem >> 12;
      int k = slab * 32 + ((lane >> 4) << 3) + j;
      int n = nt * 16 + (lane & 15);
      float x = (k < K) ? wm.p[rb * 5 + mat][(size_t)k * 128 + n] : 0.f;
      wrf[e] = f16_bits(x);
    }
  }
}

// ============ split-K vertex-align gather + f16 MFMA GEMM (R10 structure, single-pass) ============
// 512-thread blocks: 8 waves, one 16-row m-tile each -> M=128/block.
// A-prefetch (R11) and fused variants (R9/R13) regressed; keep plain.
__global__ __launch_bounds__(512) void k_align_mfma(
    const float* __restrict__ tr0, const float* __restrict__ tr1,
    const float* __restrict__ tr2, const float* __restrict__ tr3,
    const float* __restrict__ pos,
    const unsigned short* __restrict__ whf,
    float* __restrict__ part, int kchunk) {
  int tid  = threadIdx.x;
  int wave = tid >> 6, lane = tid & 63;
  int q    = lane >> 4, l15 = lane & 15;
  int m0   = blockIdx.x * 128;
  int s    = blockIdx.y;
  int mrow = m0 + wave * 16 + l15;

  float wgt[4]; int base[4];
  {
    int rowc = (mrow < R_) ? mrow : 0;
    int b = rowc / N_;
    float px = pos[rowc*3+0], py = pos[rowc*3+1], pz = pos[rowc*3+2];
    float hh = fminf(fmaxf(248.f*(py/pz)    + 111.5f, 0.f), 223.f);
    float wc = fminf(fmaxf(248.f*(px/(-pz)) + 111.5f, 0.f), 223.f);
    const int Sarr[4] = {56, 28, 14, 7};
    const int Carr[4] = {256, 512, 1024, 2048};
    #pragma unroll
    for (int sc = 0; sc < 4; sc++) {
      int S = Sarr[sc], C = Carr[sc];
      float dv = 224.f / (float)S;
      float x = hh / dv, y = wc / dv;
      int x1 = (int)floorf(x), y1 = (int)floorf(y);
      int x2 = min((int)ceilf(x), S - 1), y2 = min((int)ceilf(y), S - 1);
      float w = (float)((x2 - x1) * (y2 - y1));   // xi==x1,yi==y1 -> single tap
      if (mrow >= R_) w = 0.f;
      wgt[sc]  = w;
      base[sc] = (b * S * S + x1 * S + y1) * C;   // NHWC; add channel
    }
  }

  f32x4 acc[8];
  #pragma unroll
  for (int nt = 0; nt < 8; nt++) acc[nt] = (f32x4){0.f, 0.f, 0.f, 0.f};

  const f16x8* BH = (const f16x8*)whf;

  int kbeg = s * kchunk, kend = kbeg + kchunk;
  #pragma unroll 1
  for (int k0 = kbeg; k0 < kend; k0 += 32) {
    const float* tr; int off, sI;
    if (k0 < 256)       { tr = tr0; off = 0;    sI = 0; }
    else if (k0 < 768)  { tr = tr1; off = 256;  sI = 1; }
    else if (k0 < 1792) { tr = tr2; off = 768;  sI = 2; }
    else                { tr = tr3; off = 1792; sI = 3; }

    const float* src = tr + base[sI] + (k0 - off + q * 8);
    float4 a0 = *(const float4*)src;
    float4 a1 = *(const float4*)(src + 4);
    float wg = wgt[sI];
    f16x8 af;
    af[0] = (_Float16)(a0.x*wg); af[1] = (_Float16)(a0.y*wg);
    af[2] = (_Float16)(a0.z*wg); af[3] = (_Float16)(a0.w*wg);
    af[4] = (_Float16)(a1.x*wg); af[5] = (_Float16)(a1.y*wg);
    af[6] = (_Float16)(a1.z*wg); af[7] = (_Float16)(a1.w*wg);

    int slab = k0 >> 5;
    f16x8 Bh[8];
    #pragma unroll
    for (int nt = 0; nt < 8; nt++)
      Bh[nt] = BH[(size_t)(slab * 8 + nt) * 64 + lane];
    #pragma unroll
    for (int nt = 0; nt < 8; nt++)
      acc[nt] = __builtin_amdgcn_mfma_f32_16x16x32_f16(af, Bh[nt], acc[nt], 0, 0, 0);
  }

  // C/D layout: col = lane&15, row_in_tile = q*4 + reg (dtype-independent)
  #pragma unroll
  for (int nt = 0; nt < 8; nt++)
    #pragma unroll
    for (int r = 0; r < 4; r++) {
      int row = m0 + wave * 16 + q * 4 + r;
      if (row < R_)
        part[((size_t)s * R_ + row) * 128 + nt * 16 + l15] = acc[nt][r];
    }
}

// ---------------- reduce partials + bias, build xcat (proj|vf|pos|0pad), stride 288 ----------------
__global__ __launch_bounds__(256) void k_reduce(
    const float* __restrict__ part, const float* __restrict__ lin_b,
    const float* __restrict__ vf, const float* __restrict__ pos,
    float* __restrict__ xcat, int nsplit) {
  int row = blockIdx.x * 2 + (threadIdx.x >> 7);
  int k = threadIdx.x & 127;
  float acc = lin_b[k];
  for (int s = 0; s < nsplit; s++)
    acc += part[((size_t)s*R_ + row)*128 + k];
  xcat[(size_t)row*288 + k]       = acc;
  xcat[(size_t)row*288 + 128 + k] = vf[(size_t)row*128 + k];
  if (k < 32) xcat[(size_t)row*288 + 256 + k] = (k < 3) ? pos[(size_t)row*3 + k] : 0.f;
}

// ============ f16 MFMA GEMM: out[which] = X @ W[which] (+pb for which==2) ============
// M=64/block (4 waves x 16-row m-tiles), N=128, W pre-split f16 fragment order.
template<int SLABS>
__global__ __launch_bounds__(256) void k_gemm_mfma(
    const float* __restrict__ X, int ldx,
    const unsigned short* __restrict__ wf,
    int matStride, const float* __restrict__ pb,
    float* __restrict__ o0, float* __restrict__ o1, float* __restrict__ o2) {
  int tid = threadIdx.x;
  int wave = tid >> 6, lane = tid & 63;
  int q = lane >> 4, l15 = lane & 15;
  int which = blockIdx.y;
  int m0 = blockIdx.x * 64;
  int mrow = m0 + wave * 16 + l15;
  int rowc = (mrow < R_) ? mrow : (R_ - 1);
  const float* xrow = X + (size_t)rowc * ldx + q * 8;

  const f16x8* BH = (const f16x8*)(wf + (size_t)which * matStride);

  f32x4 acc[8];
  #pragma unroll
  for (int nt = 0; nt < 8; nt++) acc[nt] = (f32x4){0.f, 0.f, 0.f, 0.f};

  #pragma unroll 1
  for (int slab = 0; slab < SLABS; slab++) {
    const float* src = xrow + slab * 32;
    float4 a0 = *(const float4*)src;
    float4 a1 = *(const float4*)(src + 4);
    f16x8 af;
    af[0] = (_Float16)a0.x; af[1] = (_Float16)a0.y;
    af[2] = (_Float16)a0.z; af[3] = (_Float16)a0.w;
    af[4] = (_Float16)a1.x; af[5] = (_Float16)a1.y;
    af[6] = (_Float16)a1.z; af[7] = (_Float16)a1.w;
    f16x8 Bh[8];
    #pragma unroll
    for (int nt = 0; nt < 8; nt++)
      Bh[nt] = BH[(size_t)(slab * 8 + nt) * 64 + lane];
    #pragma unroll
    for (int nt = 0; nt < 8; nt++)
      acc[nt] = __builtin_amdgcn_mfma_f32_16x16x32_f16(af, Bh[nt], acc[nt], 0, 0, 0);
  }

  float* out = (which == 0) ? o0 : (which == 1) ? o1 : o2;
  #pragma unroll
  for (int nt = 0; nt < 8; nt++) {
    int col = nt * 16 + l15;
    float bias = (pb != nullptr && which == 2) ? pb[col] : 0.f;
    #pragma unroll
    for (int r = 0; r < 4; r++) {
      int row = m0 + wave * 16 + q * 4 + r;
      if (row < R_) out[(size_t)row * 128 + col] = acc[nt][r] + bias;
    }
  }
}

// ---------------- SpMM: out = [skip +] relu(s + A@t); optional fused 128->3 GEMV ----------------
__global__ __launch_bounds__(256) void k_spmm(
    const float* __restrict__ sb, const float* __restrict__ tb,
    const int* __restrict__ cols, const int* __restrict__ cnts,
    const float* __restrict__ skipb, float* __restrict__ outb,
    const float* __restrict__ gw0, const float* __restrict__ gw1,
    float* __restrict__ gsb, float* __restrict__ gtb, int fuse_gf) {
  int tid = threadIdx.x;
  int grp = tid >> 5, ln = tid & 31;
  int row = blockIdx.x * 8 + grp;           // 1233 * 8 = 9864 exact
  int b = row / N_;
  size_t tbase = (size_t)b * N_;
  const float4* sb4 = (const float4*)sb;
  const float4* tb4 = (const float4*)tb;
  float4 acc = sb4[(size_t)row*32 + ln];
  int cnt = cnts[row];
  const int* cp = cols + (size_t)row * ELLW;
  for (int i = 0; i < cnt; i++) {
    int c = cp[i];
    float4 v = tb4[(tbase + c)*32 + ln];
    acc.x += v.x; acc.y += v.y; acc.z += v.z; acc.w += v.w;
  }
  acc.x = fmaxf(acc.x, 0.f); acc.y = fmaxf(acc.y, 0.f);
  acc.z = fmaxf(acc.z, 0.f); acc.w = fmaxf(acc.w, 0.f);
  if (skipb) {
    float4 sv = ((const float4*)skipb)[(size_t)row*32 + ln];
    acc.x += sv.x; acc.y += sv.y; acc.z += sv.z; acc.w += sv.w;
  }
  if (!fuse_gf) {
    ((float4*)outb)[(size_t)row*32 + ln] = acc;
    return;
  }
  // fused final gemv: p[c] = sum_j x[j]*gw0[j][c], q likewise (fp32, exact order kept)
  float av[4] = {acc.x, acc.y, acc.z, acc.w};
  int j0 = ln * 4;
  float p0 = 0.f, p1 = 0.f, p2 = 0.f, q0 = 0.f, q1 = 0.f, q2 = 0.f;
  #pragma unroll
  for (int u = 0; u < 4; u++) {
    int j = j0 + u;
    p0 += av[u] * gw0[j*3+0]; p1 += av[u] * gw0[j*3+1]; p2 += av[u] * gw0[j*3+2];
    q0 += av[u] * gw1[j*3+0]; q1 += av[u] * gw1[j*3+1]; q2 += av[u] * gw1[j*3+2];
  }
  #pragma unroll
  for (int off = 16; off >= 1; off >>= 1) {
    p0 += __shfl_xor(p0, off); p1 += __shfl_xor(p1, off); p2 += __shfl_xor(p2, off);
    q0 += __shfl_xor(q0, off); q1 += __shfl_xor(q1, off); q2 += __shfl_xor(q2, off);
  }
  if (ln == 0) {
    gsb[(size_t)row*128 + 0] = p0; gsb[(size_t)row*128 + 1] = p1; gsb[(size_t)row*128 + 2] = p2;
    gtb[(size_t)row*128 + 0] = q0; gtb[(size_t)row*128 + 1] = q1; gtb[(size_t)row*128 + 2] = q2;
  }
}

// ---------------- final: out = pos + tanh(relu(s + A@t)) ----------------
__global__ __launch_bounds__(256) void k_gf_final(
    const float* __restrict__ sb, const float* __restrict__ tb,
    const int* __restrict__ cols, const int* __restrict__ cnts,
    const float* __restrict__ pos, float* __restrict__ out) {
  int wave = threadIdx.x >> 6, lane = threadIdx.x & 63;
  int row = blockIdx.x * 4 + wave;          // grid 2466
  if (lane >= 3) return;
  int b = row / N_;
  float acc = sb[(size_t)row*128 + lane];
  int cnt = cnts[row];
  const int* cp = cols + (size_t)row * ELLW;
  size_t tbase = (size_t)b * N_;
  for (int i = 0; i < cnt; i++)
    acc += tb[(tbase + cp[i])*128 + lane];
  float v = tanhf(fmaxf(acc, 0.f));
  out[(size_t)row*3 + lane] = pos[(size_t)row*3 + lane] + v;
}

extern "C" void kernel_launch(void* const* d_in, const int* in_sizes, int n_in,
                              void* d_out, int out_size, void* d_ws, size_t ws_size,
                              hipStream_t stream) {
  const float* conv2_3 = (const float*)d_in[0];
  const float* conv3_4 = (const float*)d_in[1];
  const float* conv4_6 = (const float*)d_in[2];
  const float* conv5_3 = (const float*)d_in[3];
  const float* pos     = (const float*)d_in[4];
  const float* vf      = (const float*)d_in[5];
  const float* adj     = (const float*)d_in[6];
  const float* lin_w   = (const float*)d_in[7];
  const float* lin_b   = (const float*)d_in[8];
  const float* r_pb[3]  = {(const float*)d_in[10], (const float*)d_in[16], (const float*)d_in[22]};
  const float* gf_w0 = (const float*)d_in[27];
  const float* gf_w1 = (const float*)d_in[28];
  float* out = (float*)d_out;

  // ---- workspace layout (float slots; lo arrays retired but slots kept for layout stability) ----
  const size_t TR_TOT  = (size_t)4*(256*3136 + 512*784 + 1024*196 + 2048*49); // 6,021,120
  const size_t ROWF    = (size_t)R_ * 128;                                    // 1,262,592
  const size_t XCAT_F  = (size_t)R_ * 288;                                    // 2,840,832
  const size_t LINW_E  = 491520;                                              // shorts per array
  const size_t RESW_E  = 307200;                                              // shorts per array

  float* ws  = (float*)d_ws;
  float* tr0 = ws;
  float* tr1 = tr0 + (size_t)4*256*3136;
  float* tr2 = tr1 + (size_t)4*512*784;
  float* tr3 = tr2 + (size_t)4*1024*196;
  int*   ell_cnt  = (int*)(tr3 + (size_t)4*2048*49);
  int*   ell_cols = ell_cnt + R_;
  unsigned short* whf = (unsigned short*)(ell_cols + (size_t)R_*ELLW);
  unsigned short* wrf = whf + 2*LINW_E;     // (old wlo slot unused)
  float* part = (float*)(wrf + 2*RESW_E);   // (old wrl slot unused)

  size_t fixed_f = TR_TOT + (size_t)R_*(ELLW+1) + LINW_E + RESW_E;
  size_t need8 = (fixed_f + (size_t)8*ROWF + XCAT_F + 5*ROWF) * sizeof(float);
  int nsplit = (ws_size >= need8) ? 8 : 4;
  int kchunk = 3840 / nsplit;

  float* xcat = part + (size_t)nsplit * ROWF;
  float* sb   = xcat + XCAT_F;
  float* tb   = sb   + ROWF;
  float* skip = tb   + ROWF;
  float* hb   = skip + ROWF;
  float* xc   = hb   + ROWF;

  WMats wm;
  for (int rb = 0; rb < 3; rb++) {
    wm.p[rb*5 + 0] = (const float*)d_in[11 + 6*rb];  // w00
    wm.p[rb*5 + 1] = (const float*)d_in[12 + 6*rb];  // w01
    wm.p[rb*5 + 2] = (const float*)d_in[9  + 6*rb];  // pw
    wm.p[rb*5 + 3] = (const float*)d_in[13 + 6*rb];  // w10
    wm.p[rb*5 + 4] = (const float*)d_in[14 + 6*rb];  // w11
  }
  const int RB_BASE[3] = {0, 143360, 225280};

  // D0: transposes + ELL + all W f16 splits
  k_pre<<<9390, 256, 0, stream>>>(conv2_3, conv3_4, conv4_6, conv5_3,
                                  tr0, tr1, tr2, tr3,
                                  adj, ell_cols, ell_cnt,
                                  lin_w, whf, wm, wrf);

  // D1: split-K f16 MFMA align GEMM
  k_align_mfma<<<dim3(78, nsplit), 512, 0, stream>>>(tr0, tr1, tr2, tr3, pos,
                                                     whf, part, kchunk);

  // D2: reduce partials + concat (stride 288, zero-padded)
  k_reduce<<<4932, 256, 0, stream>>>(part, lin_b, vf, pos, xcat, nsplit);

  // D3..: three residual graph-conv blocks, all GEMMs via single-pass f16 MFMA
  for (int rb = 0; rb < 3; rb++) {
    if (rb == 0) {
      k_gemm_mfma<9><<<dim3(155, 3), 256, 0, stream>>>(
          xcat, 288, wrf + RB_BASE[0], 36864, r_pb[0], sb, tb, skip);
    } else {
      k_gemm_mfma<4><<<dim3(155, 3), 256, 0, stream>>>(
          xc, 128, wrf + RB_BASE[rb], 16384, r_pb[rb], sb, tb, skip);
    }
    k_spmm<<<1233, 256, 0, stream>>>(sb, tb, ell_cols, ell_cnt, nullptr, hb,
                                     nullptr, nullptr, nullptr, nullptr, 0);
    int g2off = RB_BASE[rb] + ((rb == 0) ? 110592 : 3 * 16384);
    k_gemm_mfma<4><<<dim3(155, 2), 256, 0, stream>>>(
        hb, 128, wrf + g2off, 16384, nullptr, sb, tb, nullptr);
    if (rb < 2) {
      k_spmm<<<1233, 256, 0, stream>>>(sb, tb, ell_cols, ell_cnt, skip, xc,
                                       nullptr, nullptr, nullptr, nullptr, 0);
    } else {
      k_spmm<<<1233, 256, 0, stream>>>(sb, tb, ell_cols, ell_cnt, skip, nullptr,
                                       gf_w0, gf_w1, hb, xc, 1);   // gsb=hb, gtb=xc
    }
  }

  // final: out = pos + tanh(relu(gsb + A@gtb))
  k_gf_final<<<2466, 256, 0, stream>>>(hb, xc, ell_cols, ell_cnt, pos, out);
}

// Round 16
// 452.501 us; speedup vs baseline: 1.1636x; 1.0241x over previous
//
#include <hip/hip_runtime.h>
#include <cmath>

#define B_   4
#define N_   2466
#define R_   (B_*N_)     // 9864
#define ELLW 96

typedef _Float16 f16x8 __attribute__((ext_vector_type(8)));
typedef __attribute__((ext_vector_type(4))) float f32x4;

__device__ __forceinline__ unsigned short f16_bits(float x) {
  union { _Float16 h; unsigned short u; } c;
  c.h = (_Float16)x;          // RNE
  return c.u;
}

struct WMats { const float* p[15]; };   // rb-major: w00,w01,pw,w10,w11

// Fragment-order layout (lin_w and res weights), f16 single-pass:
// e = ((slab*8 + nt)*64 + lane)*8 + j ; k = slab*32 + (lane>>4)*8 + j ; n = nt*16 + (lane&15)

// ============ fused pre-kernel: transposes + ELL + all W f16 fragment splits ============
__global__ __launch_bounds__(256) void k_pre(
    const float* __restrict__ c2, const float* __restrict__ c3,
    const float* __restrict__ c4, const float* __restrict__ c5,
    float* __restrict__ t0, float* __restrict__ t1,
    float* __restrict__ t2, float* __restrict__ t3,
    const float* __restrict__ adj, int* __restrict__ cols, int* __restrict__ cnts,
    const float* __restrict__ lin_w,
    unsigned short* __restrict__ whf,
    WMats wm,
    unsigned short* __restrict__ wrf) {
  __shared__ float t[32][33];
  int bid = blockIdx.x;
  if (bid < 6144) {
    const float* in; float* out; int C, P, nx, ny, rem;
    if (bid < 3136)      { in = c2; out = t0; C = 256;  P = 3136; nx = 98; ny = 8;  rem = bid; }
    else if (bid < 4736) { in = c3; out = t1; C = 512;  P = 784;  nx = 25; ny = 16; rem = bid - 3136; }
    else if (bid < 5632) { in = c4; out = t2; C = 1024; P = 196;  nx = 7;  ny = 32; rem = bid - 4736; }
    else                 { in = c5; out = t3; C = 2048; P = 49;   nx = 2;  ny = 64; rem = bid - 5632; }
    int x = rem % nx; int tq = rem / nx; int y = tq % ny; int b = tq / ny;
    int p0 = x * 32, c0 = y * 32;
    int lp = threadIdx.x & 31, lc = threadIdx.x >> 5;
    for (int cc = lc; cc < 32; cc += 8) {
      int c = c0 + cc, p = p0 + lp;
      t[cc][lp] = (c < C && p < P) ? in[((size_t)b*C + c)*P + p] : 0.f;
    }
    __syncthreads();
    for (int pp = lc; pp < 32; pp += 8) {
      int p = p0 + pp, c = c0 + lp;
      if (p < P && c < C) out[((size_t)b*P + p)*C + c] = t[lp][pp];
    }
  } else if (bid < 8610) {
    // ---- adjacency -> ELL, two-phase: batch all loads (latency), then ballot chain ----
    int wave = threadIdx.x >> 6, lane = threadIdx.x & 63;
    int row = (bid - 6144) * 4 + wave;
    const float* Ar = adj + (size_t)row * N_;   // row stride 9864 B: 8B-aligned -> float2 ok
    int* cp = cols + (size_t)row * ELLW;
    unsigned long long below = (lane == 63) ? 0xFFFFFFFFFFFFFFFFull >> 1
                                            : ((1ull << lane) - 1ull);
    float2 v[20];
    #pragma unroll
    for (int i0 = 0; i0 < 20; i0++) {
      int j0 = i0 * 128 + lane * 2;
      v[i0] = make_float2(0.f, 0.f);
      if (j0 + 1 < N_) v[i0] = *(const float2*)&Ar[j0];   // all 20 loads in flight
    }
    int base = 0;
    #pragma unroll
    for (int i0 = 0; i0 < 20; i0++) {
      int j0 = i0 * 128 + lane * 2;
      bool nz0 = (j0 < N_) && (v[i0].x != 0.f);
      bool nz1 = (j0 + 1 < N_) && (v[i0].y != 0.f);
      unsigned long long m0 = __ballot(nz0);
      unsigned long long m1 = __ballot(nz1);
      int pre = __popcll(m0 & below) + __popcll(m1 & below);
      int p0 = base + pre;
      int p1 = p0 + (nz0 ? 1 : 0);
      if (nz0 && p0 < ELLW) cp[p0] = j0;
      if (nz1 && p1 < ELLW) cp[p1] = j0 + 1;
      base += __popcll(m0) + __popcll(m1);
    }
    if (lane == 0) cnts[row] = (base > ELLW) ? ELLW : base;
  } else if (bid < 9090) {
    // lin_w -> f16 fragments (491520 elems)
    int b = bid - 8610;
    int e0 = (b * 256 + threadIdx.x) * 4;
    #pragma unroll
    for (int u = 0; u < 4; u++) {
      int e = e0 + u;
      int j = e & 7;
      int lane = (e >> 3) & 63;
      int nt = (e >> 9) & 7;
      int slab = e >> 12;
      int k = slab * 32 + ((lane >> 4) << 3) + j;
      int n = nt * 16 + (lane & 15);
      whf[e] = f16_bits(lin_w[(size_t)k * 128 + n]);
    }
  } else {
    // res weights -> f16 fragments (307200 elems, zero-padded past K)
    int b = bid - 9090;                 // 0..299
    int e0 = (b * 256 + threadIdx.x) * 4;
    #pragma unroll
    for (int u = 0; u < 4; u++) {
      int e = e0 + u;
      int rb, mat, rem, K;
      if (e < 143360) {
        rb = 0;
        if (e < 110592) { mat = e / 36864; rem = e - mat * 36864; K = 259; }
        else { int tt = e - 110592; mat = 3 + tt / 16384; rem = tt & 16383; K = 128; }
      } else {
        int tt = e - 143360;
        rb = 1 + tt / 81920;
        int r2 = tt % 81920;
        mat = r2 / 16384; rem = r2 & 16383; K = 128;
      }
      int j = rem & 7, lane = (rem >> 3) & 63, nt = (rem >> 9) & 7, slab = rem >> 12;
      int k = slab * 32 + ((lane >> 4) << 3) + j;
      int n = nt * 16 + (lane & 15);
      float x = (k < K) ? wm.p[rb * 5 + mat][(size_t)k * 128 + n] : 0.f;
      wrf[e] = f16_bits(x);
    }
  }
}

// ============ split-K vertex-align gather + f16 MFMA GEMM (single-pass) ============
// 512-thread blocks: 8 waves, one 16-row m-tile each -> M=128/block.
// A-prefetch (R11) and fused variants (R9/R13) regressed; keep plain.
__global__ __launch_bounds__(512) void k_align_mfma(
    const float* __restrict__ tr0, const float* __restrict__ tr1,
    const float* __restrict__ tr2, const float* __restrict__ tr3,
    const float* __restrict__ pos,
    const unsigned short* __restrict__ whf,
    float* __restrict__ part, int kchunk) {
  int tid  = threadIdx.x;
  int wave = tid >> 6, lane = tid & 63;
  int q    = lane >> 4, l15 = lane & 15;
  int m0   = blockIdx.x * 128;
  int s    = blockIdx.y;
  int mrow = m0 + wave * 16 + l15;

  float wgt[4]; int base[4];
  {
    int rowc = (mrow < R_) ? mrow : 0;
    int b = rowc / N_;
    float px = pos[rowc*3+0], py = pos[rowc*3+1], pz = pos[rowc*3+2];
    float hh = fminf(fmaxf(248.f*(py/pz)    + 111.5f, 0.f), 223.f);
    float wc = fminf(fmaxf(248.f*(px/(-pz)) + 111.5f, 0.f), 223.f);
    const int Sarr[4] = {56, 28, 14, 7};
    const int Carr[4] = {256, 512, 1024, 2048};
    #pragma unroll
    for (int sc = 0; sc < 4; sc++) {
      int S = Sarr[sc], C = Carr[sc];
      float dv = 224.f / (float)S;
      float x = hh / dv, y = wc / dv;
      int x1 = (int)floorf(x), y1 = (int)floorf(y);
      int x2 = min((int)ceilf(x), S - 1), y2 = min((int)ceilf(y), S - 1);
      float w = (float)((x2 - x1) * (y2 - y1));   // xi==x1,yi==y1 -> single tap
      if (mrow >= R_) w = 0.f;
      wgt[sc]  = w;
      base[sc] = (b * S * S + x1 * S + y1) * C;   // NHWC; add channel
    }
  }

  f32x4 acc[8];
  #pragma unroll
  for (int nt = 0; nt < 8; nt++) acc[nt] = (f32x4){0.f, 0.f, 0.f, 0.f};

  const f16x8* BH = (const f16x8*)whf;

  int kbeg = s * kchunk, kend = kbeg + kchunk;
  #pragma unroll 1
  for (int k0 = kbeg; k0 < kend; k0 += 32) {
    const float* tr; int off, sI;
    if (k0 < 256)       { tr = tr0; off = 0;    sI = 0; }
    else if (k0 < 768)  { tr = tr1; off = 256;  sI = 1; }
    else if (k0 < 1792) { tr = tr2; off = 768;  sI = 2; }
    else                { tr = tr3; off = 1792; sI = 3; }

    const float* src = tr + base[sI] + (k0 - off + q * 8);
    float4 a0 = *(const float4*)src;
    float4 a1 = *(const float4*)(src + 4);
    float wg = wgt[sI];
    f16x8 af;
    af[0] = (_Float16)(a0.x*wg); af[1] = (_Float16)(a0.y*wg);
    af[2] = (_Float16)(a0.z*wg); af[3] = (_Float16)(a0.w*wg);
    af[4] = (_Float16)(a1.x*wg); af[5] = (_Float16)(a1.y*wg);
    af[6] = (_Float16)(a1.z*wg); af[7] = (_Float16)(a1.w*wg);

    int slab = k0 >> 5;
    f16x8 Bh[8];
    #pragma unroll
    for (int nt = 0; nt < 8; nt++)
      Bh[nt] = BH[(size_t)(slab * 8 + nt) * 64 + lane];
    #pragma unroll
    for (int nt = 0; nt < 8; nt++)
      acc[nt] = __builtin_amdgcn_mfma_f32_16x16x32_f16(af, Bh[nt], acc[nt], 0, 0, 0);
  }

  // C/D layout: col = lane&15, row_in_tile = q*4 + reg (dtype-independent)
  #pragma unroll
  for (int nt = 0; nt < 8; nt++)
    #pragma unroll
    for (int r = 0; r < 4; r++) {
      int row = m0 + wave * 16 + q * 4 + r;
      if (row < R_)
        part[((size_t)s * R_ + row) * 128 + nt * 16 + l15] = acc[nt][r];
    }
}

// ---------------- reduce partials + bias, build xcat (proj|vf|pos|0pad), stride 288 ----------------
__global__ __launch_bounds__(256) void k_reduce(
    const float* __restrict__ part, const float* __restrict__ lin_b,
    const float* __restrict__ vf, const float* __restrict__ pos,
    float* __restrict__ xcat, int nsplit) {
  int row = blockIdx.x * 2 + (threadIdx.x >> 7);
  int k = threadIdx.x & 127;
  float acc = lin_b[k];
  for (int s = 0; s < nsplit; s++)
    acc += part[((size_t)s*R_ + row)*128 + k];
  xcat[(size_t)row*288 + k]       = acc;
  xcat[(size_t)row*288 + 128 + k] = vf[(size_t)row*128 + k];
  if (k < 32) xcat[(size_t)row*288 + 256 + k] = (k < 3) ? pos[(size_t)row*3 + k] : 0.f;
}

// ============ f16 MFMA GEMM: out[which] = X @ W[which] (+pb for which==2) ============
// M=64/block (4 waves x 16-row m-tiles), N=128, W pre-split f16 fragment order.
template<int SLABS>
__global__ __launch_bounds__(256) void k_gemm_mfma(
    const float* __restrict__ X, int ldx,
    const unsigned short* __restrict__ wf,
    int matStride, const float* __restrict__ pb,
    float* __restrict__ o0, float* __restrict__ o1, float* __restrict__ o2) {
  int tid = threadIdx.x;
  int wave = tid >> 6, lane = tid & 63;
  int q = lane >> 4, l15 = lane & 15;
  int which = blockIdx.y;
  int m0 = blockIdx.x * 64;
  int mrow = m0 + wave * 16 + l15;
  int rowc = (mrow < R_) ? mrow : (R_ - 1);
  const float* xrow = X + (size_t)rowc * ldx + q * 8;

  const f16x8* BH = (const f16x8*)(wf + (size_t)which * matStride);

  f32x4 acc[8];
  #pragma unroll
  for (int nt = 0; nt < 8; nt++) acc[nt] = (f32x4){0.f, 0.f, 0.f, 0.f};

  #pragma unroll 1
  for (int slab = 0; slab < SLABS; slab++) {
    const float* src = xrow + slab * 32;
    float4 a0 = *(const float4*)src;
    float4 a1 = *(const float4*)(src + 4);
    f16x8 af;
    af[0] = (_Float16)a0.x; af[1] = (_Float16)a0.y;
    af[2] = (_Float16)a0.z; af[3] = (_Float16)a0.w;
    af[4] = (_Float16)a1.x; af[5] = (_Float16)a1.y;
    af[6] = (_Float16)a1.z; af[7] = (_Float16)a1.w;
    f16x8 Bh[8];
    #pragma unroll
    for (int nt = 0; nt < 8; nt++)
      Bh[nt] = BH[(size_t)(slab * 8 + nt) * 64 + lane];
    #pragma unroll
    for (int nt = 0; nt < 8; nt++)
      acc[nt] = __builtin_amdgcn_mfma_f32_16x16x32_f16(af, Bh[nt], acc[nt], 0, 0, 0);
  }

  float* out = (which == 0) ? o0 : (which == 1) ? o1 : o2;
  #pragma unroll
  for (int nt = 0; nt < 8; nt++) {
    int col = nt * 16 + l15;
    float bias = (pb != nullptr && which == 2) ? pb[col] : 0.f;
    #pragma unroll
    for (int r = 0; r < 4; r++) {
      int row = m0 + wave * 16 + q * 4 + r;
      if (row < R_) out[(size_t)row * 128 + col] = acc[nt][r] + bias;
    }
  }
}

// ---------------- SpMM: out = [skip +] relu(s + A@t); optional fused 128->3 GEMV ----------------
__global__ __launch_bounds__(256) void k_spmm(
    const float* __restrict__ sb, const float* __restrict__ tb,
    const int* __restrict__ cols, const int* __restrict__ cnts,
    const float* __restrict__ skipb, float* __restrict__ outb,
    const float* __restrict__ gw0, const float* __restrict__ gw1,
    float* __restrict__ gsb, float* __restrict__ gtb, int fuse_gf) {
  int tid = threadIdx.x;
  int grp = tid >> 5, ln = tid & 31;
  int row = blockIdx.x * 8 + grp;           // 1233 * 8 = 9864 exact
  int b = row / N_;
  size_t tbase = (size_t)b * N_;
  const float4* sb4 = (const float4*)sb;
  const float4* tb4 = (const float4*)tb;
  float4 acc = sb4[(size_t)row*32 + ln];
  int cnt = cnts[row];
  const int* cp = cols + (size_t)row * ELLW;
  for (int i = 0; i < cnt; i++) {
    int c = cp[i];
    float4 v = tb4[(tbase + c)*32 + ln];
    acc.x += v.x; acc.y += v.y; acc.z += v.z; acc.w += v.w;
  }
  acc.x = fmaxf(acc.x, 0.f); acc.y = fmaxf(acc.y, 0.f);
  acc.z = fmaxf(acc.z, 0.f); acc.w = fmaxf(acc.w, 0.f);
  if (skipb) {
    float4 sv = ((const float4*)skipb)[(size_t)row*32 + ln];
    acc.x += sv.x; acc.y += sv.y; acc.z += sv.z; acc.w += sv.w;
  }
  if (!fuse_gf) {
    ((float4*)outb)[(size_t)row*32 + ln] = acc;
    return;
  }
  // fused final gemv: p[c] = sum_j x[j]*gw0[j][c], q likewise (fp32, exact order kept)
  float av[4] = {acc.x, acc.y, acc.z, acc.w};
  int j0 = ln * 4;
  float p0 = 0.f, p1 = 0.f, p2 = 0.f, q0 = 0.f, q1 = 0.f, q2 = 0.f;
  #pragma unroll
  for (int u = 0; u < 4; u++) {
    int j = j0 + u;
    p0 += av[u] * gw0[j*3+0]; p1 += av[u] * gw0[j*3+1]; p2 += av[u] * gw0[j*3+2];
    q0 += av[u] * gw1[j*3+0]; q1 += av[u] * gw1[j*3+1]; q2 += av[u] * gw1[j*3+2];
  }
  #pragma unroll
  for (int off = 16; off >= 1; off >>= 1) {
    p0 += __shfl_xor(p0, off); p1 += __shfl_xor(p1, off); p2 += __shfl_xor(p2, off);
    q0 += __shfl_xor(q0, off); q1 += __shfl_xor(q1, off); q2 += __shfl_xor(q2, off);
  }
  if (ln == 0) {
    gsb[(size_t)row*128 + 0] = p0; gsb[(size_t)row*128 + 1] = p1; gsb[(size_t)row*128 + 2] = p2;
    gtb[(size_t)row*128 + 0] = q0; gtb[(size_t)row*128 + 1] = q1; gtb[(size_t)row*128 + 2] = q2;
  }
}

// ---------------- final: out = pos + tanh(relu(s + A@t)) ----------------
__global__ __launch_bounds__(256) void k_gf_final(
    const float* __restrict__ sb, const float* __restrict__ tb,
    const int* __restrict__ cols, const int* __restrict__ cnts,
    const float* __restrict__ pos, float* __restrict__ out) {
  int wave = threadIdx.x >> 6, lane = threadIdx.x & 63;
  int row = blockIdx.x * 4 + wave;          // grid 2466
  if (lane >= 3) return;
  int b = row / N_;
  float acc = sb[(size_t)row*128 + lane];
  int cnt = cnts[row];
  const int* cp = cols + (size_t)row * ELLW;
  size_t tbase = (size_t)b * N_;
  for (int i = 0; i < cnt; i++)
    acc += tb[(tbase + cp[i])*128 + lane];
  float v = tanhf(fmaxf(acc, 0.f));
  out[(size_t)row*3 + lane] = pos[(size_t)row*3 + lane] + v;
}

extern "C" void kernel_launch(void* const* d_in, const int* in_sizes, int n_in,
                              void* d_out, int out_size, void* d_ws, size_t ws_size,
                              hipStream_t stream) {
  const float* conv2_3 = (const float*)d_in[0];
  const float* conv3_4 = (const float*)d_in[1];
  const float* conv4_6 = (const float*)d_in[2];
  const float* conv5_3 = (const float*)d_in[3];
  const float* pos     = (const float*)d_in[4];
  const float* vf      = (const float*)d_in[5];
  const float* adj     = (const float*)d_in[6];
  const float* lin_w   = (const float*)d_in[7];
  const float* lin_b   = (const float*)d_in[8];
  const float* r_pb[3]  = {(const float*)d_in[10], (const float*)d_in[16], (const float*)d_in[22]};
  const float* gf_w0 = (const float*)d_in[27];
  const float* gf_w1 = (const float*)d_in[28];
  float* out = (float*)d_out;

  // ---- workspace layout (float slots) ----
  const size_t TR_TOT  = (size_t)4*(256*3136 + 512*784 + 1024*196 + 2048*49); // 6,021,120
  const size_t ROWF    = (size_t)R_ * 128;                                    // 1,262,592
  const size_t XCAT_F  = (size_t)R_ * 288;                                    // 2,840,832
  const size_t LINW_E  = 491520;                                              // shorts per array
  const size_t RESW_E  = 307200;                                              // shorts per array

  float* ws  = (float*)d_ws;
  float* tr0 = ws;
  float* tr1 = tr0 + (size_t)4*256*3136;
  float* tr2 = tr1 + (size_t)4*512*784;
  float* tr3 = tr2 + (size_t)4*1024*196;
  int*   ell_cnt  = (int*)(tr3 + (size_t)4*2048*49);
  int*   ell_cols = ell_cnt + R_;
  unsigned short* whf = (unsigned short*)(ell_cols + (size_t)R_*ELLW);
  unsigned short* wrf = whf + 2*LINW_E;
  float* part = (float*)(wrf + 2*RESW_E);

  size_t fixed_f = TR_TOT + (size_t)R_*(ELLW+1) + LINW_E + RESW_E;
  size_t need8 = (fixed_f + (size_t)8*ROWF + XCAT_F + 5*ROWF) * sizeof(float);
  int nsplit = (ws_size >= need8) ? 8 : 4;
  int kchunk = 3840 / nsplit;

  float* xcat = part + (size_t)nsplit * ROWF;
  float* sb   = xcat + XCAT_F;
  float* tb   = sb   + ROWF;
  float* skip = tb   + ROWF;
  float* hb   = skip + ROWF;
  float* xc   = hb   + ROWF;

  WMats wm;
  for (int rb = 0; rb < 3; rb++) {
    wm.p[rb*5 + 0] = (const float*)d_in[11 + 6*rb];  // w00
    wm.p[rb*5 + 1] = (const float*)d_in[12 + 6*rb];  // w01
    wm.p[rb*5 + 2] = (const float*)d_in[9  + 6*rb];  // pw
    wm.p[rb*5 + 3] = (const float*)d_in[13 + 6*rb];  // w10
    wm.p[rb*5 + 4] = (const float*)d_in[14 + 6*rb];  // w11
  }
  const int RB_BASE[3] = {0, 143360, 225280};

  // D0: transposes + ELL (batched loads) + all W f16 splits
  k_pre<<<9390, 256, 0, stream>>>(conv2_3, conv3_4, conv4_6, conv5_3,
                                  tr0, tr1, tr2, tr3,
                                  adj, ell_cols, ell_cnt,
                                  lin_w, whf, wm, wrf);

  // D1: split-K f16 MFMA align GEMM
  k_align_mfma<<<dim3(78, nsplit), 512, 0, stream>>>(tr0, tr1, tr2, tr3, pos,
                                                     whf, part, kchunk);

  // D2: reduce partials + concat (stride 288, zero-padded)
  k_reduce<<<4932, 256, 0, stream>>>(part, lin_b, vf, pos, xcat, nsplit);

  // D3..: three residual graph-conv blocks, all GEMMs via single-pass f16 MFMA
  for (int rb = 0; rb < 3; rb++) {
    if (rb == 0) {
      k_gemm_mfma<9><<<dim3(155, 3), 256, 0, stream>>>(
          xcat, 288, wrf + RB_BASE[0], 36864, r_pb[0], sb, tb, skip);
    } else {
      k_gemm_mfma<4><<<dim3(155, 3), 256, 0, stream>>>(
          xc, 128, wrf + RB_BASE[rb], 16384, r_pb[rb], sb, tb, skip);
    }
    k_spmm<<<1233, 256, 0, stream>>>(sb, tb, ell_cols, ell_cnt, nullptr, hb,
                                     nullptr, nullptr, nullptr, nullptr, 0);
    int g2off = RB_BASE[rb] + ((rb == 0) ? 110592 : 3 * 16384);
    k_gemm_mfma<4><<<dim3(155, 2), 256, 0, stream>>>(
        hb, 128, wrf + g2off, 16384, nullptr, sb, tb, nullptr);
    if (rb < 2) {
      k_spmm<<<1233, 256, 0, stream>>>(sb, tb, ell_cols, ell_cnt, skip, xc,
                                       nullptr, nullptr, nullptr, nullptr, 0);
    } else {
      k_spmm<<<1233, 256, 0, stream>>>(sb, tb, ell_cols, ell_cnt, skip, nullptr,
                                       gf_w0, gf_w1, hb, xc, 1);   // gsb=hb, gtb=xc
    }
  }

  // final: out = pos + tanh(relu(gsb + A@gtb))
  k_gf_final<<<2466, 256, 0, stream>>>(hb, xc, ell_cols, ell_cnt, pos, out);
}

// Round 17
// 446.369 us; speedup vs baseline: 1.1796x; 1.0137x over previous
//
#include <hip/hip_runtime.h>
#include <cmath>

#define B_   4
#define N_   2466
#define R_   (B_*N_)     // 9864
#define ELLW 96

typedef _Float16 f16x8 __attribute__((ext_vector_type(8)));
typedef __attribute__((ext_vector_type(4))) float f32x4;

__device__ __forceinline__ unsigned short f16_bits(float x) {
  union { _Float16 h; unsigned short u; } c;
  c.h = (_Float16)x;          // RNE
  return c.u;
}

struct WMats { const float* p[15]; };   // rb-major: w00,w01,pw,w10,w11

// Fragment-order layout (lin_w and res weights), f16 single-pass:
// e = ((slab*8 + nt)*64 + lane)*8 + j ; k = slab*32 + (lane>>4)*8 + j ; n = nt*16 + (lane&15)
// Feature maps are transposed to NHWC *f16* (bit-identical: align weight w ∈ {0,1} exactly,
// so cvt(a·w) == cvt(a)·w — conversion commutes with the weighting).

// ============ fused pre-kernel: transposes(->f16) + ELL(float4) + W f16 splits ============
__global__ __launch_bounds__(256) void k_pre(
    const float* __restrict__ c2, const float* __restrict__ c3,
    const float* __restrict__ c4, const float* __restrict__ c5,
    unsigned short* __restrict__ t0, unsigned short* __restrict__ t1,
    unsigned short* __restrict__ t2, unsigned short* __restrict__ t3,
    const float* __restrict__ adj, int* __restrict__ cols, int* __restrict__ cnts,
    const float* __restrict__ lin_w,
    unsigned short* __restrict__ whf,
    WMats wm,
    unsigned short* __restrict__ wrf) {
  __shared__ float t[32][33];
  int bid = blockIdx.x;
  if (bid < 6144) {
    const float* in; unsigned short* out; int C, P, nx, ny, rem;
    if (bid < 3136)      { in = c2; out = t0; C = 256;  P = 3136; nx = 98; ny = 8;  rem = bid; }
    else if (bid < 4736) { in = c3; out = t1; C = 512;  P = 784;  nx = 25; ny = 16; rem = bid - 3136; }
    else if (bid < 5632) { in = c4; out = t2; C = 1024; P = 196;  nx = 7;  ny = 32; rem = bid - 4736; }
    else                 { in = c5; out = t3; C = 2048; P = 49;   nx = 2;  ny = 64; rem = bid - 5632; }
    int x = rem % nx; int tq = rem / nx; int y = tq % ny; int b = tq / ny;
    int p0 = x * 32, c0 = y * 32;
    int lp = threadIdx.x & 31, lc = threadIdx.x >> 5;
    for (int cc = lc; cc < 32; cc += 8) {
      int c = c0 + cc, p = p0 + lp;
      t[cc][lp] = (c < C && p < P) ? in[((size_t)b*C + c)*P + p] : 0.f;
    }
    __syncthreads();
    for (int pp = lc; pp < 32; pp += 8) {
      int p = p0 + pp, c = c0 + lp;
      if (p < P && c < C) out[((size_t)b*P + p)*C + c] = f16_bits(t[lp][pp]);
    }
  } else if (bid < 8610) {
    // ---- adjacency -> ELL: batched float4 loads (row stride 39456 B % 16 == 0) ----
    int wave = threadIdx.x >> 6, lane = threadIdx.x & 63;
    int row = (bid - 6144) * 4 + wave;
    const float* Ar = adj + (size_t)row * N_;
    int* cp = cols + (size_t)row * ELLW;
    unsigned long long below = (lane == 63) ? 0xFFFFFFFFFFFFFFFFull >> 1
                                            : ((1ull << lane) - 1ull);
    float4 v[10];
    #pragma unroll
    for (int i0 = 0; i0 < 10; i0++) {       // 10*256 = 2560 >= 2466
      int j0 = i0 * 256 + lane * 4;
      if (j0 + 3 < N_) {
        v[i0] = *(const float4*)&Ar[j0];
      } else {
        v[i0] = make_float4(0.f, 0.f, 0.f, 0.f);
        if (j0     < N_) v[i0].x = Ar[j0];
        if (j0 + 1 < N_) v[i0].y = Ar[j0+1];
        if (j0 + 2 < N_) v[i0].z = Ar[j0+2];
      }
    }
    int base = 0;
    #pragma unroll
    for (int i0 = 0; i0 < 10; i0++) {
      int j0 = i0 * 256 + lane * 4;
      bool nz0 = (j0     < N_) && (v[i0].x != 0.f);
      bool nz1 = (j0 + 1 < N_) && (v[i0].y != 0.f);
      bool nz2 = (j0 + 2 < N_) && (v[i0].z != 0.f);
      bool nz3 = (j0 + 3 < N_) && (v[i0].w != 0.f);
      unsigned long long m0 = __ballot(nz0);
      unsigned long long m1 = __ballot(nz1);
      unsigned long long m2 = __ballot(nz2);
      unsigned long long m3 = __ballot(nz3);
      int pre = __popcll(m0 & below) + __popcll(m1 & below)
              + __popcll(m2 & below) + __popcll(m3 & below);
      int p0 = base + pre;
      int p1 = p0 + (nz0 ? 1 : 0);
      int p2 = p1 + (nz1 ? 1 : 0);
      int p3 = p2 + (nz2 ? 1 : 0);
      if (nz0 && p0 < ELLW) cp[p0] = j0;
      if (nz1 && p1 < ELLW) cp[p1] = j0 + 1;
      if (nz2 && p2 < ELLW) cp[p2] = j0 + 2;
      if (nz3 && p3 < ELLW) cp[p3] = j0 + 3;
      base += __popcll(m0) + __popcll(m1) + __popcll(m2) + __popcll(m3);
    }
    if (lane == 0) cnts[row] = (base > ELLW) ? ELLW : base;
  } else if (bid < 9090) {
    // lin_w -> f16 fragments (491520 elems)
    int b = bid - 8610;
    int e0 = (b * 256 + threadIdx.x) * 4;
    #pragma unroll
    for (int u = 0; u < 4; u++) {
      int e = e0 + u;
      int j = e & 7;
      int lane = (e >> 3) & 63;
      int nt = (e >> 9) & 7;
      int slab = e >> 12;
      int k = slab * 32 + ((lane >> 4) << 3) + j;
      int n = nt * 16 + (lane & 15);
      whf[e] = f16_bits(lin_w[(size_t)k * 128 + n]);
    }
  } else {
    // res weights -> f16 fragments (307200 elems, zero-padded past K)
    int b = bid - 9090;                 // 0..299
    int e0 = (b * 256 + threadIdx.x) * 4;
    #pragma unroll
    for (int u = 0; u < 4; u++) {
      int e = e0 + u;
      int rb, mat, rem, K;
      if (e < 143360) {
        rb = 0;
        if (e < 110592) { mat = e / 36864; rem = e - mat * 36864; K = 259; }
        else { int tt = e - 110592; mat = 3 + tt / 16384; rem = tt & 16383; K = 128; }
      } else {
        int tt = e - 143360;
        rb = 1 + tt / 81920;
        int r2 = tt % 81920;
        mat = r2 / 16384; rem = r2 & 16383; K = 128;
      }
      int j = rem & 7, lane = (rem >> 3) & 63, nt = (rem >> 9) & 7, slab = rem >> 12;
      int k = slab * 32 + ((lane >> 4) << 3) + j;
      int n = nt * 16 + (lane & 15);
      float x = (k < K) ? wm.p[rb * 5 + mat][(size_t)k * 128 + n] : 0.f;
      wrf[e] = f16_bits(x);
    }
  }
}

// ============ split-K vertex-align gather (f16 maps) + f16 MFMA GEMM ============
// 512-thread blocks: 8 waves, one 16-row m-tile each -> M=128/block.
// A is one 16B f16x8 load per k-step; weight w ∈ {0,1} applied as zero-select (exact).
__global__ __launch_bounds__(512) void k_align_mfma(
    const unsigned short* __restrict__ tr0, const unsigned short* __restrict__ tr1,
    const unsigned short* __restrict__ tr2, const unsigned short* __restrict__ tr3,
    const float* __restrict__ pos,
    const unsigned short* __restrict__ whf,
    float* __restrict__ part, int kchunk) {
  int tid  = threadIdx.x;
  int wave = tid >> 6, lane = tid & 63;
  int q    = lane >> 4, l15 = lane & 15;
  int m0   = blockIdx.x * 128;
  int s    = blockIdx.y;
  int mrow = m0 + wave * 16 + l15;

  int zero[4]; int base[4];
  {
    int rowc = (mrow < R_) ? mrow : 0;
    int b = rowc / N_;
    float px = pos[rowc*3+0], py = pos[rowc*3+1], pz = pos[rowc*3+2];
    float hh = fminf(fmaxf(248.f*(py/pz)    + 111.5f, 0.f), 223.f);
    float wc = fminf(fmaxf(248.f*(px/(-pz)) + 111.5f, 0.f), 223.f);
    const int Sarr[4] = {56, 28, 14, 7};
    const int Carr[4] = {256, 512, 1024, 2048};
    #pragma unroll
    for (int sc = 0; sc < 4; sc++) {
      int S = Sarr[sc], C = Carr[sc];
      float dv = 224.f / (float)S;
      float x = hh / dv, y = wc / dv;
      int x1 = (int)floorf(x), y1 = (int)floorf(y);
      int x2 = min((int)ceilf(x), S - 1), y2 = min((int)ceilf(y), S - 1);
      int w = (x2 - x1) * (y2 - y1);              // ∈ {0,1}: xi==x1,yi==y1 -> single tap
      zero[sc] = (mrow >= R_) || (w == 0);
      base[sc] = (b * S * S + x1 * S + y1) * C;   // NHWC f16; add channel
    }
  }

  f32x4 acc[8];
  #pragma unroll
  for (int nt = 0; nt < 8; nt++) acc[nt] = (f32x4){0.f, 0.f, 0.f, 0.f};

  const f16x8* BH = (const f16x8*)whf;

  int kbeg = s * kchunk, kend = kbeg + kchunk;
  #pragma unroll 1
  for (int k0 = kbeg; k0 < kend; k0 += 32) {
    const unsigned short* tr; int off, sI;
    if (k0 < 256)       { tr = tr0; off = 0;    sI = 0; }
    else if (k0 < 768)  { tr = tr1; off = 256;  sI = 1; }
    else if (k0 < 1792) { tr = tr2; off = 768;  sI = 2; }
    else                { tr = tr3; off = 1792; sI = 3; }

    f16x8 af = *(const f16x8*)(tr + base[sI] + (k0 - off) + q * 8);
    if (zero[sI]) af = (f16x8)(_Float16)0;     // exact weight ∈ {0,1}

    int slab = k0 >> 5;
    f16x8 Bh[8];
    #pragma unroll
    for (int nt = 0; nt < 8; nt++)
      Bh[nt] = BH[(size_t)(slab * 8 + nt) * 64 + lane];
    #pragma unroll
    for (int nt = 0; nt < 8; nt++)
      acc[nt] = __builtin_amdgcn_mfma_f32_16x16x32_f16(af, Bh[nt], acc[nt], 0, 0, 0);
  }

  // C/D layout: col = lane&15, row_in_tile = q*4 + reg (dtype-independent)
  #pragma unroll
  for (int nt = 0; nt < 8; nt++)
    #pragma unroll
    for (int r = 0; r < 4; r++) {
      int row = m0 + wave * 16 + q * 4 + r;
      if (row < R_)
        part[((size_t)s * R_ + row) * 128 + nt * 16 + l15] = acc[nt][r];
    }
}

// ---------------- reduce partials + bias, build xcat (proj|vf|pos|0pad), stride 288 ----------------
__global__ __launch_bounds__(256) void k_reduce(
    const float* __restrict__ part, const float* __restrict__ lin_b,
    const float* __restrict__ vf, const float* __restrict__ pos,
    float* __restrict__ xcat, int nsplit) {
  int row = blockIdx.x * 2 + (threadIdx.x >> 7);
  int k = threadIdx.x & 127;
  float acc = lin_b[k];
  for (int s = 0; s < nsplit; s++)
    acc += part[((size_t)s*R_ + row)*128 + k];
  xcat[(size_t)row*288 + k]       = acc;
  xcat[(size_t)row*288 + 128 + k] = vf[(size_t)row*128 + k];
  if (k < 32) xcat[(size_t)row*288 + 256 + k] = (k < 3) ? pos[(size_t)row*3 + k] : 0.f;
}

// ============ f16 MFMA GEMM: out[which] = X @ W[which] (+pb for which==2) ============
// M=64/block (4 waves x 16-row m-tiles), N=128, W pre-split f16 fragment order.
template<int SLABS>
__global__ __launch_bounds__(256) void k_gemm_mfma(
    const float* __restrict__ X, int ldx,
    const unsigned short* __restrict__ wf,
    int matStride, const float* __restrict__ pb,
    float* __restrict__ o0, float* __restrict__ o1, float* __restrict__ o2) {
  int tid = threadIdx.x;
  int wave = tid >> 6, lane = tid & 63;
  int q = lane >> 4, l15 = lane & 15;
  int which = blockIdx.y;
  int m0 = blockIdx.x * 64;
  int mrow = m0 + wave * 16 + l15;
  int rowc = (mrow < R_) ? mrow : (R_ - 1);
  const float* xrow = X + (size_t)rowc * ldx + q * 8;

  const f16x8* BH = (const f16x8*)(wf + (size_t)which * matStride);

  f32x4 acc[8];
  #pragma unroll
  for (int nt = 0; nt < 8; nt++) acc[nt] = (f32x4){0.f, 0.f, 0.f, 0.f};

  #pragma unroll 1
  for (int slab = 0; slab < SLABS; slab++) {
    const float* src = xrow + slab * 32;
    float4 a0 = *(const float4*)src;
    float4 a1 = *(const float4*)(src + 4);
    f16x8 af;
    af[0] = (_Float16)a0.x; af[1] = (_Float16)a0.y;
    af[2] = (_Float16)a0.z; af[3] = (_Float16)a0.w;
    af[4] = (_Float16)a1.x; af[5] = (_Float16)a1.y;
    af[6] = (_Float16)a1.z; af[7] = (_Float16)a1.w;
    f16x8 Bh[8];
    #pragma unroll
    for (int nt = 0; nt < 8; nt++)
      Bh[nt] = BH[(size_t)(slab * 8 + nt) * 64 + lane];
    #pragma unroll
    for (int nt = 0; nt < 8; nt++)
      acc[nt] = __builtin_amdgcn_mfma_f32_16x16x32_f16(af, Bh[nt], acc[nt], 0, 0, 0);
  }

  float* out = (which == 0) ? o0 : (which == 1) ? o1 : o2;
  #pragma unroll
  for (int nt = 0; nt < 8; nt++) {
    int col = nt * 16 + l15;
    float bias = (pb != nullptr && which == 2) ? pb[col] : 0.f;
    #pragma unroll
    for (int r = 0; r < 4; r++) {
      int row = m0 + wave * 16 + q * 4 + r;
      if (row < R_) out[(size_t)row * 128 + col] = acc[nt][r] + bias;
    }
  }
}

// ---------------- SpMM: out = [skip +] relu(s + A@t); optional fused 128->3 GEMV ----------------
__global__ __launch_bounds__(256) void k_spmm(
    const float* __restrict__ sb, const float* __restrict__ tb,
    const int* __restrict__ cols, const int* __restrict__ cnts,
    const float* __restrict__ skipb, float* __restrict__ outb,
    const float* __restrict__ gw0, const float* __restrict__ gw1,
    float* __restrict__ gsb, float* __restrict__ gtb, int fuse_gf) {
  int tid = threadIdx.x;
  int grp = tid >> 5, ln = tid & 31;
  int row = blockIdx.x * 8 + grp;           // 1233 * 8 = 9864 exact
  int b = row / N_;
  size_t tbase = (size_t)b * N_;
  const float4* sb4 = (const float4*)sb;
  const float4* tb4 = (const float4*)tb;
  float4 acc = sb4[(size_t)row*32 + ln];
  int cnt = cnts[row];
  const int* cp = cols + (size_t)row * ELLW;
  for (int i = 0; i < cnt; i++) {
    int c = cp[i];
    float4 v = tb4[(tbase + c)*32 + ln];
    acc.x += v.x; acc.y += v.y; acc.z += v.z; acc.w += v.w;
  }
  acc.x = fmaxf(acc.x, 0.f); acc.y = fmaxf(acc.y, 0.f);
  acc.z = fmaxf(acc.z, 0.f); acc.w = fmaxf(acc.w, 0.f);
  if (skipb) {
    float4 sv = ((const float4*)skipb)[(size_t)row*32 + ln];
    acc.x += sv.x; acc.y += sv.y; acc.z += sv.z; acc.w += sv.w;
  }
  if (!fuse_gf) {
    ((float4*)outb)[(size_t)row*32 + ln] = acc;
    return;
  }
  // fused final gemv: p[c] = sum_j x[j]*gw0[j][c], q likewise (fp32, exact order kept)
  float av[4] = {acc.x, acc.y, acc.z, acc.w};
  int j0 = ln * 4;
  float p0 = 0.f, p1 = 0.f, p2 = 0.f, q0 = 0.f, q1 = 0.f, q2 = 0.f;
  #pragma unroll
  for (int u = 0; u < 4; u++) {
    int j = j0 + u;
    p0 += av[u] * gw0[j*3+0]; p1 += av[u] * gw0[j*3+1]; p2 += av[u] * gw0[j*3+2];
    q0 += av[u] * gw1[j*3+0]; q1 += av[u] * gw1[j*3+1]; q2 += av[u] * gw1[j*3+2];
  }
  #pragma unroll
  for (int off = 16; off >= 1; off >>= 1) {
    p0 += __shfl_xor(p0, off); p1 += __shfl_xor(p1, off); p2 += __shfl_xor(p2, off);
    q0 += __shfl_xor(q0, off); q1 += __shfl_xor(q1, off); q2 += __shfl_xor(q2, off);
  }
  if (ln == 0) {
    gsb[(size_t)row*128 + 0] = p0; gsb[(size_t)row*128 + 1] = p1; gsb[(size_t)row*128 + 2] = p2;
    gtb[(size_t)row*128 + 0] = q0; gtb[(size_t)row*128 + 1] = q1; gtb[(size_t)row*128 + 2] = q2;
  }
}

// ---------------- final: out = pos + tanh(relu(s + A@t)) ----------------
__global__ __launch_bounds__(256) void k_gf_final(
    const float* __restrict__ sb, const float* __restrict__ tb,
    const int* __restrict__ cols, const int* __restrict__ cnts,
    const float* __restrict__ pos, float* __restrict__ out) {
  int wave = threadIdx.x >> 6, lane = threadIdx.x & 63;
  int row = blockIdx.x * 4 + wave;          // grid 2466
  if (lane >= 3) return;
  int b = row / N_;
  float acc = sb[(size_t)row*128 + lane];
  int cnt = cnts[row];
  const int* cp = cols + (size_t)row * ELLW;
  size_t tbase = (size_t)b * N_;
  for (int i = 0; i < cnt; i++)
    acc += tb[(tbase + cp[i])*128 + lane];
  float v = tanhf(fmaxf(acc, 0.f));
  out[(size_t)row*3 + lane] = pos[(size_t)row*3 + lane] + v;
}

extern "C" void kernel_launch(void* const* d_in, const int* in_sizes, int n_in,
                              void* d_out, int out_size, void* d_ws, size_t ws_size,
                              hipStream_t stream) {
  const float* conv2_3 = (const float*)d_in[0];
  const float* conv3_4 = (const float*)d_in[1];
  const float* conv4_6 = (const float*)d_in[2];
  const float* conv5_3 = (const float*)d_in[3];
  const float* pos     = (const float*)d_in[4];
  const float* vf      = (const float*)d_in[5];
  const float* adj     = (const float*)d_in[6];
  const float* lin_w   = (const float*)d_in[7];
  const float* lin_b   = (const float*)d_in[8];
  const float* r_pb[3]  = {(const float*)d_in[10], (const float*)d_in[16], (const float*)d_in[22]};
  const float* gf_w0 = (const float*)d_in[27];
  const float* gf_w1 = (const float*)d_in[28];
  float* out = (float*)d_out;

  // ---- workspace layout ----
  // f16 transposed maps (halves): 3,211,264 + 1,605,632 + 802,816 + 401,408 = 6,021,120
  const size_t TRH_TOT = 6021120;                 // halves = 3,010,560 float slots
  const size_t ROWF    = (size_t)R_ * 128;        // 1,262,592
  const size_t XCAT_F  = (size_t)R_ * 288;        // 2,840,832
  const size_t LINW_E  = 491520;                  // shorts
  const size_t RESW_E  = 307200;                  // shorts

  unsigned short* trh0 = (unsigned short*)d_ws;
  unsigned short* trh1 = trh0 + (size_t)4*256*3136;
  unsigned short* trh2 = trh1 + (size_t)4*512*784;
  unsigned short* trh3 = trh2 + (size_t)4*1024*196;
  int*   ell_cnt  = (int*)(trh3 + (size_t)4*2048*49);
  int*   ell_cols = ell_cnt + R_;
  unsigned short* whf = (unsigned short*)(ell_cols + (size_t)R_*ELLW);
  unsigned short* wrf = whf + LINW_E;
  float* part = (float*)(wrf + RESW_E + 512);   // +512 shorts pad -> 16B-aligned region

  size_t fixed_f = TRH_TOT/2 + (size_t)R_*(ELLW+1) + (LINW_E + RESW_E + 512)/2;
  size_t need8 = (fixed_f + (size_t)8*ROWF + XCAT_F + 5*ROWF) * sizeof(float);
  int nsplit = (ws_size >= need8) ? 8 : 4;
  int kchunk = 3840 / nsplit;

  float* xcat = part + (size_t)nsplit * ROWF;
  float* sb   = xcat + XCAT_F;
  float* tb   = sb   + ROWF;
  float* skip = tb   + ROWF;
  float* hb   = skip + ROWF;
  float* xc   = hb   + ROWF;

  WMats wm;
  for (int rb = 0; rb < 3; rb++) {
    wm.p[rb*5 + 0] = (const float*)d_in[11 + 6*rb];  // w00
    wm.p[rb*5 + 1] = (const float*)d_in[12 + 6*rb];  // w01
    wm.p[rb*5 + 2] = (const float*)d_in[9  + 6*rb];  // pw
    wm.p[rb*5 + 3] = (const float*)d_in[13 + 6*rb];  // w10
    wm.p[rb*5 + 4] = (const float*)d_in[14 + 6*rb];  // w11
  }
  const int RB_BASE[3] = {0, 143360, 225280};

  // D0: transposes(->f16) + ELL(float4) + all W f16 splits
  k_pre<<<9390, 256, 0, stream>>>(conv2_3, conv3_4, conv4_6, conv5_3,
                                  trh0, trh1, trh2, trh3,
                                  adj, ell_cols, ell_cnt,
                                  lin_w, whf, wm, wrf);

  // D1: split-K f16 MFMA align GEMM (f16 maps, 16B A-loads)
  k_align_mfma<<<dim3(78, nsplit), 512, 0, stream>>>(trh0, trh1, trh2, trh3, pos,
                                                     whf, part, kchunk);

  // D2: reduce partials + concat (stride 288, zero-padded)
  k_reduce<<<4932, 256, 0, stream>>>(part, lin_b, vf, pos, xcat, nsplit);

  // D3..: three residual graph-conv blocks, all GEMMs via single-pass f16 MFMA
  for (int rb = 0; rb < 3; rb++) {
    if (rb == 0) {
      k_gemm_mfma<9><<<dim3(155, 3), 256, 0, stream>>>(
          xcat, 288, wrf + RB_BASE[0], 36864, r_pb[0], sb, tb, skip);
    } else {
      k_gemm_mfma<4><<<dim3(155, 3), 256, 0, stream>>>(
          xc, 128, wrf + RB_BASE[rb], 16384, r_pb[rb], sb, tb, skip);
    }
    k_spmm<<<1233, 256, 0, stream>>>(sb, tb, ell_cols, ell_cnt, nullptr, hb,
                                     nullptr, nullptr, nullptr, nullptr, 0);
    int g2off = RB_BASE[rb] + ((rb == 0) ? 110592 : 3 * 16384);
    k_gemm_mfma<4><<<dim3(155, 2), 256, 0, stream>>>(
        hb, 128, wrf + g2off, 16384, nullptr, sb, tb, nullptr);
    if (rb < 2) {
      k_spmm<<<1233, 256, 0, stream>>>(sb, tb, ell_cols, ell_cnt, skip, xc,
                                       nullptr, nullptr, nullptr, nullptr, 0);
    } else {
      k_spmm<<<1233, 256, 0, stream>>>(sb, tb, ell_cols, ell_cnt, skip, nullptr,
                                       gf_w0, gf_w1, hb, xc, 1);   // gsb=hb, gtb=xc
    }
  }

  // final: out = pos + tanh(relu(gsb + A@gtb))
  k_gf_final<<<2466, 256, 0, stream>>>(hb, xc, ell_cols, ell_cnt, pos, out);
}

// Round 18
// 441.551 us; speedup vs baseline: 1.1924x; 1.0109x over previous
//
#include <hip/hip_runtime.h>
#include <cmath>

#define B_   4
#define N_   2466
#define R_   (B_*N_)     // 9864
#define ELLW 96

typedef _Float16 f16x8 __attribute__((ext_vector_type(8)));
typedef __attribute__((ext_vector_type(4))) float f32x4;

__device__ __forceinline__ unsigned short f16_bits(float x) {
  union { _Float16 h; unsigned short u; } c;
  c.h = (_Float16)x;          // RNE
  return c.u;
}

struct WMats { const float* p[15]; };   // rb-major: w00,w01,pw,w10,w11

// Fragment-order layout (lin_w and res weights), f16 single-pass:
// e = ((slab*8 + nt)*64 + lane)*8 + j ; k = slab*32 + (lane>>4)*8 + j ; n = nt*16 + (lane&15)
// Feature maps transposed to NHWC f16 (bit-identical: align weight w ∈ {0,1} exactly).

// ============ fused pre-kernel: transposes(->f16, 64x64 tiles) + ELL + W f16 splits ============
// blocks [0,1584): transpose; [1584,4050): ELL; [4050,4530): lin_w; [4530,4830): res W
__global__ __launch_bounds__(256) void k_pre(
    const float* __restrict__ c2, const float* __restrict__ c3,
    const float* __restrict__ c4, const float* __restrict__ c5,
    unsigned short* __restrict__ t0, unsigned short* __restrict__ t1,
    unsigned short* __restrict__ t2, unsigned short* __restrict__ t3,
    const float* __restrict__ adj, int* __restrict__ cols, int* __restrict__ cnts,
    const float* __restrict__ lin_w,
    unsigned short* __restrict__ whf,
    WMats wm,
    unsigned short* __restrict__ wrf) {
  __shared__ float t[64][66];    // [c][p], stride 66: float2 stores 8B-aligned, 2-way banks (free)
  int bid = blockIdx.x;
  int tid = threadIdx.x;
  if (bid < 1584) {
    const float* in; unsigned short* out; int C, P, npb, ncb, rem;
    if (bid < 784)       { in = c2; out = t0; C = 256;  P = 3136; npb = 49; ncb = 4;  rem = bid; }
    else if (bid < 1200) { in = c3; out = t1; C = 512;  P = 784;  npb = 13; ncb = 8;  rem = bid - 784; }
    else if (bid < 1456) { in = c4; out = t2; C = 1024; P = 196;  npb = 4;  ncb = 16; rem = bid - 1200; }
    else                 { in = c5; out = t3; C = 2048; P = 49;   npb = 1;  ncb = 32; rem = bid - 1456; }
    int pb = rem % npb; int tq = rem / npb; int cb = tq % ncb; int b = tq / ncb;
    int c0 = cb * 64, p0 = pb * 64;
    // load 64c x 64p as float2 over p (8 per thread)
    #pragma unroll
    for (int i = 0; i < 8; i++) {
      int e = tid + i * 256;
      int c = e >> 5, f2 = e & 31;
      int p = p0 + f2 * 2;
      float2 v = make_float2(0.f, 0.f);
      const float* src = in + ((size_t)b * C + (c0 + c)) * P + p;
      if (p + 1 < P)      v = *(const float2*)src;
      else if (p < P)     v.x = *src;
      *(float2*)&t[c][f2 * 2] = v;
    }
    __syncthreads();
    // write: per pixel 128 contiguous bytes (64 ch * f16); 16 lanes x ushort4 per pixel
    int jj = tid & 15, c4i = jj * 4;
    #pragma unroll
    for (int pass = 0; pass < 4; pass++) {
      int pp = pass * 16 + (tid >> 4);
      int px = p0 + pp;
      if (px < P) {
        ushort4 o;
        o.x = f16_bits(t[c4i + 0][pp]);
        o.y = f16_bits(t[c4i + 1][pp]);
        o.z = f16_bits(t[c4i + 2][pp]);
        o.w = f16_bits(t[c4i + 3][pp]);
        *(ushort4*)&out[((size_t)b * P + px) * C + c0 + c4i] = o;
      }
    }
  } else if (bid < 4050) {
    // ---- adjacency -> ELL: batched float4 loads ----
    int wave = tid >> 6, lane = tid & 63;
    int row = (bid - 1584) * 4 + wave;
    const float* Ar = adj + (size_t)row * N_;
    int* cp = cols + (size_t)row * ELLW;
    unsigned long long below = (lane == 63) ? 0xFFFFFFFFFFFFFFFFull >> 1
                                            : ((1ull << lane) - 1ull);
    float4 v[10];
    #pragma unroll
    for (int i0 = 0; i0 < 10; i0++) {       // 10*256 = 2560 >= 2466
      int j0 = i0 * 256 + lane * 4;
      if (j0 + 3 < N_) {
        v[i0] = *(const float4*)&Ar[j0];
      } else {
        v[i0] = make_float4(0.f, 0.f, 0.f, 0.f);
        if (j0     < N_) v[i0].x = Ar[j0];
        if (j0 + 1 < N_) v[i0].y = Ar[j0+1];
        if (j0 + 2 < N_) v[i0].z = Ar[j0+2];
      }
    }
    int base = 0;
    #pragma unroll
    for (int i0 = 0; i0 < 10; i0++) {
      int j0 = i0 * 256 + lane * 4;
      bool nz0 = (j0     < N_) && (v[i0].x != 0.f);
      bool nz1 = (j0 + 1 < N_) && (v[i0].y != 0.f);
      bool nz2 = (j0 + 2 < N_) && (v[i0].z != 0.f);
      bool nz3 = (j0 + 3 < N_) && (v[i0].w != 0.f);
      unsigned long long m0 = __ballot(nz0);
      unsigned long long m1 = __ballot(nz1);
      unsigned long long m2 = __ballot(nz2);
      unsigned long long m3 = __ballot(nz3);
      int pre = __popcll(m0 & below) + __popcll(m1 & below)
              + __popcll(m2 & below) + __popcll(m3 & below);
      int p0 = base + pre;
      int p1 = p0 + (nz0 ? 1 : 0);
      int p2 = p1 + (nz1 ? 1 : 0);
      int p3 = p2 + (nz2 ? 1 : 0);
      if (nz0 && p0 < ELLW) cp[p0] = j0;
      if (nz1 && p1 < ELLW) cp[p1] = j0 + 1;
      if (nz2 && p2 < ELLW) cp[p2] = j0 + 2;
      if (nz3 && p3 < ELLW) cp[p3] = j0 + 3;
      base += __popcll(m0) + __popcll(m1) + __popcll(m2) + __popcll(m3);
    }
    if (lane == 0) cnts[row] = (base > ELLW) ? ELLW : base;
  } else if (bid < 4530) {
    // lin_w -> f16 fragments (491520 elems)
    int b = bid - 4050;
    int e0 = (b * 256 + tid) * 4;
    #pragma unroll
    for (int u = 0; u < 4; u++) {
      int e = e0 + u;
      int j = e & 7;
      int lane = (e >> 3) & 63;
      int nt = (e >> 9) & 7;
      int slab = e >> 12;
      int k = slab * 32 + ((lane >> 4) << 3) + j;
      int n = nt * 16 + (lane & 15);
      whf[e] = f16_bits(lin_w[(size_t)k * 128 + n]);
    }
  } else {
    // res weights -> f16 fragments (307200 elems, zero-padded past K)
    int b = bid - 4530;                 // 0..299
    int e0 = (b * 256 + tid) * 4;
    #pragma unroll
    for (int u = 0; u < 4; u++) {
      int e = e0 + u;
      int rb, mat, rem, K;
      if (e < 143360) {
        rb = 0;
        if (e < 110592) { mat = e / 36864; rem = e - mat * 36864; K = 259; }
        else { int tt = e - 110592; mat = 3 + tt / 16384; rem = tt & 16383; K = 128; }
      } else {
        int tt = e - 143360;
        rb = 1 + tt / 81920;
        int r2 = tt % 81920;
        mat = r2 / 16384; rem = r2 & 16383; K = 128;
      }
      int j = rem & 7, lane = (rem >> 3) & 63, nt = (rem >> 9) & 7, slab = rem >> 12;
      int k = slab * 32 + ((lane >> 4) << 3) + j;
      int n = nt * 16 + (lane & 15);
      float x = (k < K) ? wm.p[rb * 5 + mat][(size_t)k * 128 + n] : 0.f;
      wrf[e] = f16_bits(x);
    }
  }
}

// ============ split-K vertex-align gather (f16 maps) + f16 MFMA GEMM ============
// 512-thread blocks: 8 waves, one 16-row m-tile each -> M=128/block.
__global__ __launch_bounds__(512) void k_align_mfma(
    const unsigned short* __restrict__ tr0, const unsigned short* __restrict__ tr1,
    const unsigned short* __restrict__ tr2, const unsigned short* __restrict__ tr3,
    const float* __restrict__ pos,
    const unsigned short* __restrict__ whf,
    float* __restrict__ part, int kchunk) {
  int tid  = threadIdx.x;
  int wave = tid >> 6, lane = tid & 63;
  int q    = lane >> 4, l15 = lane & 15;
  int m0   = blockIdx.x * 128;
  int s    = blockIdx.y;
  int mrow = m0 + wave * 16 + l15;

  int zero[4]; int base[4];
  {
    int rowc = (mrow < R_) ? mrow : 0;
    int b = rowc / N_;
    float px = pos[rowc*3+0], py = pos[rowc*3+1], pz = pos[rowc*3+2];
    float hh = fminf(fmaxf(248.f*(py/pz)    + 111.5f, 0.f), 223.f);
    float wc = fminf(fmaxf(248.f*(px/(-pz)) + 111.5f, 0.f), 223.f);
    const int Sarr[4] = {56, 28, 14, 7};
    const int Carr[4] = {256, 512, 1024, 2048};
    #pragma unroll
    for (int sc = 0; sc < 4; sc++) {
      int S = Sarr[sc], C = Carr[sc];
      float dv = 224.f / (float)S;
      float x = hh / dv, y = wc / dv;
      int x1 = (int)floorf(x), y1 = (int)floorf(y);
      int x2 = min((int)ceilf(x), S - 1), y2 = min((int)ceilf(y), S - 1);
      int w = (x2 - x1) * (y2 - y1);              // ∈ {0,1}
      zero[sc] = (mrow >= R_) || (w == 0);
      base[sc] = (b * S * S + x1 * S + y1) * C;   // NHWC f16; add channel
    }
  }

  f32x4 acc[8];
  #pragma unroll
  for (int nt = 0; nt < 8; nt++) acc[nt] = (f32x4){0.f, 0.f, 0.f, 0.f};

  const f16x8* BH = (const f16x8*)whf;

  int kbeg = s * kchunk, kend = kbeg + kchunk;
  #pragma unroll 1
  for (int k0 = kbeg; k0 < kend; k0 += 32) {
    const unsigned short* tr; int off, sI;
    if (k0 < 256)       { tr = tr0; off = 0;    sI = 0; }
    else if (k0 < 768)  { tr = tr1; off = 256;  sI = 1; }
    else if (k0 < 1792) { tr = tr2; off = 768;  sI = 2; }
    else                { tr = tr3; off = 1792; sI = 3; }

    f16x8 af = *(const f16x8*)(tr + base[sI] + (k0 - off) + q * 8);
    if (zero[sI]) af = (f16x8)(_Float16)0;     // exact weight ∈ {0,1}

    int slab = k0 >> 5;
    f16x8 Bh[8];
    #pragma unroll
    for (int nt = 0; nt < 8; nt++)
      Bh[nt] = BH[(size_t)(slab * 8 + nt) * 64 + lane];
    #pragma unroll
    for (int nt = 0; nt < 8; nt++)
      acc[nt] = __builtin_amdgcn_mfma_f32_16x16x32_f16(af, Bh[nt], acc[nt], 0, 0, 0);
  }

  // C/D layout: col = lane&15, row_in_tile = q*4 + reg
  #pragma unroll
  for (int nt = 0; nt < 8; nt++)
    #pragma unroll
    for (int r = 0; r < 4; r++) {
      int row = m0 + wave * 16 + q * 4 + r;
      if (row < R_)
        part[((size_t)s * R_ + row) * 128 + nt * 16 + l15] = acc[nt][r];
    }
}

// ---------------- reduce partials + bias, build xcat (proj|vf|pos|0pad), stride 288 ----------------
__global__ __launch_bounds__(256) void k_reduce(
    const float* __restrict__ part, const float* __restrict__ lin_b,
    const float* __restrict__ vf, const float* __restrict__ pos,
    float* __restrict__ xcat, int nsplit) {
  int row = blockIdx.x * 2 + (threadIdx.x >> 7);
  int k = threadIdx.x & 127;
  float acc = lin_b[k];
  for (int s = 0; s < nsplit; s++)
    acc += part[((size_t)s*R_ + row)*128 + k];
  xcat[(size_t)row*288 + k]       = acc;
  xcat[(size_t)row*288 + 128 + k] = vf[(size_t)row*128 + k];
  if (k < 32) xcat[(size_t)row*288 + 256 + k] = (k < 3) ? pos[(size_t)row*3 + k] : 0.f;
}

// ============ f16 MFMA GEMM: out[which] = X @ W[which] (+pb for which==2) ============
template<int SLABS>
__global__ __launch_bounds__(256) void k_gemm_mfma(
    const float* __restrict__ X, int ldx,
    const unsigned short* __restrict__ wf,
    int matStride, const float* __restrict__ pb,
    float* __restrict__ o0, float* __restrict__ o1, float* __restrict__ o2) {
  int tid = threadIdx.x;
  int wave = tid >> 6, lane = tid & 63;
  int q = lane >> 4, l15 = lane & 15;
  int which = blockIdx.y;
  int m0 = blockIdx.x * 64;
  int mrow = m0 + wave * 16 + l15;
  int rowc = (mrow < R_) ? mrow : (R_ - 1);
  const float* xrow = X + (size_t)rowc * ldx + q * 8;

  const f16x8* BH = (const f16x8*)(wf + (size_t)which * matStride);

  f32x4 acc[8];
  #pragma unroll
  for (int nt = 0; nt < 8; nt++) acc[nt] = (f32x4){0.f, 0.f, 0.f, 0.f};

  #pragma unroll 1
  for (int slab = 0; slab < SLABS; slab++) {
    const float* src = xrow + slab * 32;
    float4 a0 = *(const float4*)src;
    float4 a1 = *(const float4*)(src + 4);
    f16x8 af;
    af[0] = (_Float16)a0.x; af[1] = (_Float16)a0.y;
    af[2] = (_Float16)a0.z; af[3] = (_Float16)a0.w;
    af[4] = (_Float16)a1.x; af[5] = (_Float16)a1.y;
    af[6] = (_Float16)a1.z; af[7] = (_Float16)a1.w;
    f16x8 Bh[8];
    #pragma unroll
    for (int nt = 0; nt < 8; nt++)
      Bh[nt] = BH[(size_t)(slab * 8 + nt) * 64 + lane];
    #pragma unroll
    for (int nt = 0; nt < 8; nt++)
      acc[nt] = __builtin_amdgcn_mfma_f32_16x16x32_f16(af, Bh[nt], acc[nt], 0, 0, 0);
  }

  float* out = (which == 0) ? o0 : (which == 1) ? o1 : o2;
  #pragma unroll
  for (int nt = 0; nt < 8; nt++) {
    int col = nt * 16 + l15;
    float bias = (pb != nullptr && which == 2) ? pb[col] : 0.f;
    #pragma unroll
    for (int r = 0; r < 4; r++) {
      int row = m0 + wave * 16 + q * 4 + r;
      if (row < R_) out[(size_t)row * 128 + col] = acc[nt][r] + bias;
    }
  }
}

// ---------------- SpMM: out = [skip +] relu(s + A@t); optional fused 128->3 GEMV ----------------
__global__ __launch_bounds__(256) void k_spmm(
    const float* __restrict__ sb, const float* __restrict__ tb,
    const int* __restrict__ cols, const int* __restrict__ cnts,
    const float* __restrict__ skipb, float* __restrict__ outb,
    const float* __restrict__ gw0, const float* __restrict__ gw1,
    float* __restrict__ gsb, float* __restrict__ gtb, int fuse_gf) {
  int tid = threadIdx.x;
  int grp = tid >> 5, ln = tid & 31;
  int row = blockIdx.x * 8 + grp;           // 1233 * 8 = 9864 exact
  int b = row / N_;
  size_t tbase = (size_t)b * N_;
  const float4* sb4 = (const float4*)sb;
  const float4* tb4 = (const float4*)tb;
  float4 acc = sb4[(size_t)row*32 + ln];
  int cnt = cnts[row];
  const int* cp = cols + (size_t)row * ELLW;
  for (int i = 0; i < cnt; i++) {
    int c = cp[i];
    float4 v = tb4[(tbase + c)*32 + ln];
    acc.x += v.x; acc.y += v.y; acc.z += v.z; acc.w += v.w;
  }
  acc.x = fmaxf(acc.x, 0.f); acc.y = fmaxf(acc.y, 0.f);
  acc.z = fmaxf(acc.z, 0.f); acc.w = fmaxf(acc.w, 0.f);
  if (skipb) {
    float4 sv = ((const float4*)skipb)[(size_t)row*32 + ln];
    acc.x += sv.x; acc.y += sv.y; acc.z += sv.z; acc.w += sv.w;
  }
  if (!fuse_gf) {
    ((float4*)outb)[(size_t)row*32 + ln] = acc;
    return;
  }
  float av[4] = {acc.x, acc.y, acc.z, acc.w};
  int j0 = ln * 4;
  float p0 = 0.f, p1 = 0.f, p2 = 0.f, q0 = 0.f, q1 = 0.f, q2 = 0.f;
  #pragma unroll
  for (int u = 0; u < 4; u++) {
    int j = j0 + u;
    p0 += av[u] * gw0[j*3+0]; p1 += av[u] * gw0[j*3+1]; p2 += av[u] * gw0[j*3+2];
    q0 += av[u] * gw1[j*3+0]; q1 += av[u] * gw1[j*3+1]; q2 += av[u] * gw1[j*3+2];
  }
  #pragma unroll
  for (int off = 16; off >= 1; off >>= 1) {
    p0 += __shfl_xor(p0, off); p1 += __shfl_xor(p1, off); p2 += __shfl_xor(p2, off);
    q0 += __shfl_xor(q0, off); q1 += __shfl_xor(q1, off); q2 += __shfl_xor(q2, off);
  }
  if (ln == 0) {
    gsb[(size_t)row*128 + 0] = p0; gsb[(size_t)row*128 + 1] = p1; gsb[(size_t)row*128 + 2] = p2;
    gtb[(size_t)row*128 + 0] = q0; gtb[(size_t)row*128 + 1] = q1; gtb[(size_t)row*128 + 2] = q2;
  }
}

// ---------------- final: out = pos + tanh(relu(s + A@t)) ----------------
__global__ __launch_bounds__(256) void k_gf_final(
    const float* __restrict__ sb, const float* __restrict__ tb,
    const int* __restrict__ cols, const int* __restrict__ cnts,
    const float* __restrict__ pos, float* __restrict__ out) {
  int wave = threadIdx.x >> 6, lane = threadIdx.x & 63;
  int row = blockIdx.x * 4 + wave;          // grid 2466
  if (lane >= 3) return;
  int b = row / N_;
  float acc = sb[(size_t)row*128 + lane];
  int cnt = cnts[row];
  const int* cp = cols + (size_t)row * ELLW;
  size_t tbase = (size_t)b * N_;
  for (int i = 0; i < cnt; i++)
    acc += tb[(tbase + cp[i])*128 + lane];
  float v = tanhf(fmaxf(acc, 0.f));
  out[(size_t)row*3 + lane] = pos[(size_t)row*3 + lane] + v;
}

extern "C" void kernel_launch(void* const* d_in, const int* in_sizes, int n_in,
                              void* d_out, int out_size, void* d_ws, size_t ws_size,
                              hipStream_t stream) {
  const float* conv2_3 = (const float*)d_in[0];
  const float* conv3_4 = (const float*)d_in[1];
  const float* conv4_6 = (const float*)d_in[2];
  const float* conv5_3 = (const float*)d_in[3];
  const float* pos     = (const float*)d_in[4];
  const float* vf      = (const float*)d_in[5];
  const float* adj     = (const float*)d_in[6];
  const float* lin_w   = (const float*)d_in[7];
  const float* lin_b   = (const float*)d_in[8];
  const float* r_pb[3]  = {(const float*)d_in[10], (const float*)d_in[16], (const float*)d_in[22]};
  const float* gf_w0 = (const float*)d_in[27];
  const float* gf_w1 = (const float*)d_in[28];
  float* out = (float*)d_out;

  // ---- workspace layout ----
  const size_t TRH_TOT = 6021120;                 // f16 map elems total
  const size_t ROWF    = (size_t)R_ * 128;        // 1,262,592
  const size_t XCAT_F  = (size_t)R_ * 288;        // 2,840,832
  const size_t LINW_E  = 491520;                  // shorts
  const size_t RESW_E  = 307200;                  // shorts

  unsigned short* trh0 = (unsigned short*)d_ws;
  unsigned short* trh1 = trh0 + (size_t)4*256*3136;
  unsigned short* trh2 = trh1 + (size_t)4*512*784;
  unsigned short* trh3 = trh2 + (size_t)4*1024*196;
  int*   ell_cnt  = (int*)(trh3 + (size_t)4*2048*49);
  int*   ell_cols = ell_cnt + R_;
  unsigned short* whf = (unsigned short*)(ell_cols + (size_t)R_*ELLW);
  unsigned short* wrf = whf + LINW_E;
  float* part = (float*)(wrf + RESW_E + 512);   // +512 shorts pad -> 16B-aligned region

  size_t fixed_f = TRH_TOT/2 + (size_t)R_*(ELLW+1) + (LINW_E + RESW_E + 512)/2;
  size_t need8 = (fixed_f + (size_t)8*ROWF + XCAT_F + 5*ROWF) * sizeof(float);
  int nsplit = (ws_size >= need8) ? 8 : 4;
  int kchunk = 3840 / nsplit;

  float* xcat = part + (size_t)nsplit * ROWF;
  float* sb   = xcat + XCAT_F;
  float* tb   = sb   + ROWF;
  float* skip = tb   + ROWF;
  float* hb   = skip + ROWF;
  float* xc   = hb   + ROWF;

  WMats wm;
  for (int rb = 0; rb < 3; rb++) {
    wm.p[rb*5 + 0] = (const float*)d_in[11 + 6*rb];  // w00
    wm.p[rb*5 + 1] = (const float*)d_in[12 + 6*rb];  // w01
    wm.p[rb*5 + 2] = (const float*)d_in[9  + 6*rb];  // pw
    wm.p[rb*5 + 3] = (const float*)d_in[13 + 6*rb];  // w10
    wm.p[rb*5 + 4] = (const float*)d_in[14 + 6*rb];  // w11
  }
  const int RB_BASE[3] = {0, 143360, 225280};

  // D0: transposes(->f16, vectorized 64x64) + ELL + all W f16 splits
  k_pre<<<4830, 256, 0, stream>>>(conv2_3, conv3_4, conv4_6, conv5_3,
                                  trh0, trh1, trh2, trh3,
                                  adj, ell_cols, ell_cnt,
                                  lin_w, whf, wm, wrf);

  // D1: split-K f16 MFMA align GEMM
  k_align_mfma<<<dim3(78, nsplit), 512, 0, stream>>>(trh0, trh1, trh2, trh3, pos,
                                                     whf, part, kchunk);

  // D2: reduce partials + concat (stride 288, zero-padded)
  k_reduce<<<4932, 256, 0, stream>>>(part, lin_b, vf, pos, xcat, nsplit);

  // D3..: three residual graph-conv blocks, all GEMMs via single-pass f16 MFMA
  for (int rb = 0; rb < 3; rb++) {
    if (rb == 0) {
      k_gemm_mfma<9><<<dim3(155, 3), 256, 0, stream>>>(
          xcat, 288, wrf + RB_BASE[0], 36864, r_pb[0], sb, tb, skip);
    } else {
      k_gemm_mfma<4><<<dim3(155, 3), 256, 0, stream>>>(
          xc, 128, wrf + RB_BASE[rb], 16384, r_pb[rb], sb, tb, skip);
    }
    k_spmm<<<1233, 256, 0, stream>>>(sb, tb, ell_cols, ell_cnt, nullptr, hb,
                                     nullptr, nullptr, nullptr, nullptr, 0);
    int g2off = RB_BASE[rb] + ((rb == 0) ? 110592 : 3 * 16384);
    k_gemm_mfma<4><<<dim3(155, 2), 256, 0, stream>>>(
        hb, 128, wrf + g2off, 16384, nullptr, sb, tb, nullptr);
    if (rb < 2) {
      k_spmm<<<1233, 256, 0, stream>>>(sb, tb, ell_cols, ell_cnt, skip, xc,
                                       nullptr, nullptr, nullptr, nullptr, 0);
    } else {
      k_spmm<<<1233, 256, 0, stream>>>(sb, tb, ell_cols, ell_cnt, skip, nullptr,
                                       gf_w0, gf_w1, hb, xc, 1);   // gsb=hb, gtb=xc
    }
  }

  // final: out = pos + tanh(relu(gsb + A@gtb))
  k_gf_final<<<2466, 256, 0, stream>>>(hb, xc, ell_cols, ell_cnt, pos, out);
}

// Round 19
// 428.106 us; speedup vs baseline: 1.2299x; 1.0314x over previous
//
#include <hip/hip_runtime.h>
#include <cmath>

#define B_   4
#define N_   2466
#define R_   (B_*N_)     // 9864
#define ELLW 96

typedef _Float16 f16x8 __attribute__((ext_vector_type(8)));
typedef __attribute__((ext_vector_type(4))) float f32x4;

__device__ __forceinline__ unsigned short f16_bits(float x) {
  union { _Float16 h; unsigned short u; } c;
  c.h = (_Float16)x;          // RNE
  return c.u;
}

struct WMats { const float* p[15]; };   // rb-major: w00,w01,pw,w10,w11

// Fragment-order layout (lin_w and res weights), f16 single-pass:
// e = ((slab*8 + nt)*64 + lane)*8 + j ; k = slab*32 + (lane>>4)*8 + j ; n = nt*16 + (lane&15)
// Feature maps transposed to NHWC f16 (bit-identical: align weight w ∈ {0,1} exactly).

// ============ fused pre-kernel: transposes(->f16, 64x64 tiles) + ELL + W f16 splits ============
// blocks [0,1584): transpose; [1584,4050): ELL; [4050,4530): lin_w; [4530,4830): res W
__global__ __launch_bounds__(256) void k_pre(
    const float* __restrict__ c2, const float* __restrict__ c3,
    const float* __restrict__ c4, const float* __restrict__ c5,
    unsigned short* __restrict__ t0, unsigned short* __restrict__ t1,
    unsigned short* __restrict__ t2, unsigned short* __restrict__ t3,
    const float* __restrict__ adj, int* __restrict__ cols, int* __restrict__ cnts,
    const float* __restrict__ lin_w,
    unsigned short* __restrict__ whf,
    WMats wm,
    unsigned short* __restrict__ wrf) {
  __shared__ float t[64][66];    // [c][p]; float2 stores 8B-aligned, 2-way banks (free)
  int bid = blockIdx.x;
  int tid = threadIdx.x;
  if (bid < 1584) {
    const float* in; unsigned short* out; int C, P, npb, ncb, rem;
    if (bid < 784)       { in = c2; out = t0; C = 256;  P = 3136; npb = 49; ncb = 4;  rem = bid; }
    else if (bid < 1200) { in = c3; out = t1; C = 512;  P = 784;  npb = 13; ncb = 8;  rem = bid - 784; }
    else if (bid < 1456) { in = c4; out = t2; C = 1024; P = 196;  npb = 4;  ncb = 16; rem = bid - 1200; }
    else                 { in = c5; out = t3; C = 2048; P = 49;   npb = 1;  ncb = 32; rem = bid - 1456; }
    int pb = rem % npb; int tq = rem / npb; int cb = tq % ncb; int b = tq / ncb;
    int c0 = cb * 64, p0 = pb * 64;
    #pragma unroll
    for (int i = 0; i < 8; i++) {
      int e = tid + i * 256;
      int c = e >> 5, f2 = e & 31;
      int p = p0 + f2 * 2;
      float2 v = make_float2(0.f, 0.f);
      const float* src = in + ((size_t)b * C + (c0 + c)) * P + p;
      if (p + 1 < P)      v = *(const float2*)src;
      else if (p < P)     v.x = *src;
      *(float2*)&t[c][f2 * 2] = v;
    }
    __syncthreads();
    int jj = tid & 15, c4i = jj * 4;
    #pragma unroll
    for (int pass = 0; pass < 4; pass++) {
      int pp = pass * 16 + (tid >> 4);
      int px = p0 + pp;
      if (px < P) {
        ushort4 o;
        o.x = f16_bits(t[c4i + 0][pp]);
        o.y = f16_bits(t[c4i + 1][pp]);
        o.z = f16_bits(t[c4i + 2][pp]);
        o.w = f16_bits(t[c4i + 3][pp]);
        *(ushort4*)&out[((size_t)b * P + px) * C + c0 + c4i] = o;
      }
    }
  } else if (bid < 4050) {
    // ---- adjacency -> ELL: batched float4 loads ----
    int wave = tid >> 6, lane = tid & 63;
    int row = (bid - 1584) * 4 + wave;
    const float* Ar = adj + (size_t)row * N_;
    int* cp = cols + (size_t)row * ELLW;
    unsigned long long below = (lane == 63) ? 0xFFFFFFFFFFFFFFFFull >> 1
                                            : ((1ull << lane) - 1ull);
    float4 v[10];
    #pragma unroll
    for (int i0 = 0; i0 < 10; i0++) {       // 10*256 = 2560 >= 2466
      int j0 = i0 * 256 + lane * 4;
      if (j0 + 3 < N_) {
        v[i0] = *(const float4*)&Ar[j0];
      } else {
        v[i0] = make_float4(0.f, 0.f, 0.f, 0.f);
        if (j0     < N_) v[i0].x = Ar[j0];
        if (j0 + 1 < N_) v[i0].y = Ar[j0+1];
        if (j0 + 2 < N_) v[i0].z = Ar[j0+2];
      }
    }
    int base = 0;
    #pragma unroll
    for (int i0 = 0; i0 < 10; i0++) {
      int j0 = i0 * 256 + lane * 4;
      bool nz0 = (j0     < N_) && (v[i0].x != 0.f);
      bool nz1 = (j0 + 1 < N_) && (v[i0].y != 0.f);
      bool nz2 = (j0 + 2 < N_) && (v[i0].z != 0.f);
      bool nz3 = (j0 + 3 < N_) && (v[i0].w != 0.f);
      unsigned long long m0 = __ballot(nz0);
      unsigned long long m1 = __ballot(nz1);
      unsigned long long m2 = __ballot(nz2);
      unsigned long long m3 = __ballot(nz3);
      int pre = __popcll(m0 & below) + __popcll(m1 & below)
              + __popcll(m2 & below) + __popcll(m3 & below);
      int p0 = base + pre;
      int p1 = p0 + (nz0 ? 1 : 0);
      int p2 = p1 + (nz1 ? 1 : 0);
      int p3 = p2 + (nz2 ? 1 : 0);
      if (nz0 && p0 < ELLW) cp[p0] = j0;
      if (nz1 && p1 < ELLW) cp[p1] = j0 + 1;
      if (nz2 && p2 < ELLW) cp[p2] = j0 + 2;
      if (nz3 && p3 < ELLW) cp[p3] = j0 + 3;
      base += __popcll(m0) + __popcll(m1) + __popcll(m2) + __popcll(m3);
    }
    if (lane == 0) cnts[row] = (base > ELLW) ? ELLW : base;
  } else if (bid < 4530) {
    // lin_w -> f16 fragments (491520 elems)
    int b = bid - 4050;
    int e0 = (b * 256 + tid) * 4;
    #pragma unroll
    for (int u = 0; u < 4; u++) {
      int e = e0 + u;
      int j = e & 7;
      int lane = (e >> 3) & 63;
      int nt = (e >> 9) & 7;
      int slab = e >> 12;
      int k = slab * 32 + ((lane >> 4) << 3) + j;
      int n = nt * 16 + (lane & 15);
      whf[e] = f16_bits(lin_w[(size_t)k * 128 + n]);
    }
  } else {
    // res weights -> f16 fragments (307200 elems, zero-padded past K)
    int b = bid - 4530;                 // 0..299
    int e0 = (b * 256 + tid) * 4;
    #pragma unroll
    for (int u = 0; u < 4; u++) {
      int e = e0 + u;
      int rb, mat, rem, K;
      if (e < 143360) {
        rb = 0;
        if (e < 110592) { mat = e / 36864; rem = e - mat * 36864; K = 259; }
        else { int tt = e - 110592; mat = 3 + tt / 16384; rem = tt & 16383; K = 128; }
      } else {
        int tt = e - 143360;
        rb = 1 + tt / 81920;
        int r2 = tt % 81920;
        mat = r2 / 16384; rem = r2 & 16383; K = 128;
      }
      int j = rem & 7, lane = (rem >> 3) & 63, nt = (rem >> 9) & 7, slab = rem >> 12;
      int k = slab * 32 + ((lane >> 4) << 3) + j;
      int n = nt * 16 + (lane & 15);
      float x = (k < K) ? wm.p[rb * 5 + mat][(size_t)k * 128 + n] : 0.f;
      wrf[e] = f16_bits(x);
    }
  }
}

// ============ split-K vertex-align gather (f16 maps) + f16 MFMA GEMM ============
__global__ __launch_bounds__(512) void k_align_mfma(
    const unsigned short* __restrict__ tr0, const unsigned short* __restrict__ tr1,
    const unsigned short* __restrict__ tr2, const unsigned short* __restrict__ tr3,
    const float* __restrict__ pos,
    const unsigned short* __restrict__ whf,
    float* __restrict__ part, int kchunk) {
  int tid  = threadIdx.x;
  int wave = tid >> 6, lane = tid & 63;
  int q    = lane >> 4, l15 = lane & 15;
  int m0   = blockIdx.x * 128;
  int s    = blockIdx.y;
  int mrow = m0 + wave * 16 + l15;

  int zero[4]; int base[4];
  {
    int rowc = (mrow < R_) ? mrow : 0;
    int b = rowc / N_;
    float px = pos[rowc*3+0], py = pos[rowc*3+1], pz = pos[rowc*3+2];
    float hh = fminf(fmaxf(248.f*(py/pz)    + 111.5f, 0.f), 223.f);
    float wc = fminf(fmaxf(248.f*(px/(-pz)) + 111.5f, 0.f), 223.f);
    const int Sarr[4] = {56, 28, 14, 7};
    const int Carr[4] = {256, 512, 1024, 2048};
    #pragma unroll
    for (int sc = 0; sc < 4; sc++) {
      int S = Sarr[sc], C = Carr[sc];
      float dv = 224.f / (float)S;
      float x = hh / dv, y = wc / dv;
      int x1 = (int)floorf(x), y1 = (int)floorf(y);
      int x2 = min((int)ceilf(x), S - 1), y2 = min((int)ceilf(y), S - 1);
      int w = (x2 - x1) * (y2 - y1);              // ∈ {0,1}
      zero[sc] = (mrow >= R_) || (w == 0);
      base[sc] = (b * S * S + x1 * S + y1) * C;   // NHWC f16; add channel
    }
  }

  f32x4 acc[8];
  #pragma unroll
  for (int nt = 0; nt < 8; nt++) acc[nt] = (f32x4){0.f, 0.f, 0.f, 0.f};

  const f16x8* BH = (const f16x8*)whf;

  int kbeg = s * kchunk, kend = kbeg + kchunk;
  #pragma unroll 1
  for (int k0 = kbeg; k0 < kend; k0 += 32) {
    const unsigned short* tr; int off, sI;
    if (k0 < 256)       { tr = tr0; off = 0;    sI = 0; }
    else if (k0 < 768)  { tr = tr1; off = 256;  sI = 1; }
    else if (k0 < 1792) { tr = tr2; off = 768;  sI = 2; }
    else                { tr = tr3; off = 1792; sI = 3; }

    f16x8 af = *(const f16x8*)(tr + base[sI] + (k0 - off) + q * 8);
    if (zero[sI]) af = (f16x8)(_Float16)0;     // exact weight ∈ {0,1}

    int slab = k0 >> 5;
    f16x8 Bh[8];
    #pragma unroll
    for (int nt = 0; nt < 8; nt++)
      Bh[nt] = BH[(size_t)(slab * 8 + nt) * 64 + lane];
    #pragma unroll
    for (int nt = 0; nt < 8; nt++)
      acc[nt] = __builtin_amdgcn_mfma_f32_16x16x32_f16(af, Bh[nt], acc[nt], 0, 0, 0);
  }

  // C/D layout: col = lane&15, row_in_tile = q*4 + reg
  #pragma unroll
  for (int nt = 0; nt < 8; nt++)
    #pragma unroll
    for (int r = 0; r < 4; r++) {
      int row = m0 + wave * 16 + q * 4 + r;
      if (row < R_)
        part[((size_t)s * R_ + row) * 128 + nt * 16 + l15] = acc[nt][r];
    }
}

// ---------------- reduce partials + bias -> xcat (proj|vf|pos|0pad), float4, 8 rows/block ----------------
__global__ __launch_bounds__(256) void k_reduce(
    const float* __restrict__ part, const float* __restrict__ lin_b,
    const float* __restrict__ vf, const float* __restrict__ pos,
    float* __restrict__ xcat, int nsplit) {
  int grp = threadIdx.x >> 5, ln = threadIdx.x & 31;
  int row = blockIdx.x * 8 + grp;           // 1233*8 = 9864
  float4 acc = ((const float4*)lin_b)[ln];
  for (int s = 0; s < nsplit; s++) {
    float4 pv = ((const float4*)part)[((size_t)s * R_ + row) * 32 + ln];
    acc.x += pv.x; acc.y += pv.y; acc.z += pv.z; acc.w += pv.w;
  }
  float4* xr = (float4*)(xcat + (size_t)row * 288);
  xr[ln] = acc;
  xr[32 + ln] = ((const float4*)vf)[(size_t)row * 32 + ln];
  if (ln < 8) {
    float4 z = make_float4(0.f, 0.f, 0.f, 0.f);
    if (ln == 0) {
      z.x = pos[(size_t)row * 3 + 0];
      z.y = pos[(size_t)row * 3 + 1];
      z.z = pos[(size_t)row * 3 + 2];
    }
    xr[64 + ln] = z;
  }
}

// ============ f16 MFMA GEMM: out[which] = X @ W[which] (+pb for which==2) ============
template<int SLABS>
__global__ __launch_bounds__(256) void k_gemm_mfma(
    const float* __restrict__ X, int ldx,
    const unsigned short* __restrict__ wf,
    int matStride, const float* __restrict__ pb,
    float* __restrict__ o0, float* __restrict__ o1, float* __restrict__ o2) {
  int tid = threadIdx.x;
  int wave = tid >> 6, lane = tid & 63;
  int q = lane >> 4, l15 = lane & 15;
  int which = blockIdx.y;
  int m0 = blockIdx.x * 64;
  int mrow = m0 + wave * 16 + l15;
  int rowc = (mrow < R_) ? mrow : (R_ - 1);
  const float* xrow = X + (size_t)rowc * ldx + q * 8;

  const f16x8* BH = (const f16x8*)(wf + (size_t)which * matStride);

  f32x4 acc[8];
  #pragma unroll
  for (int nt = 0; nt < 8; nt++) acc[nt] = (f32x4){0.f, 0.f, 0.f, 0.f};

  #pragma unroll 1
  for (int slab = 0; slab < SLABS; slab++) {
    const float* src = xrow + slab * 32;
    float4 a0 = *(const float4*)src;
    float4 a1 = *(const float4*)(src + 4);
    f16x8 af;
    af[0] = (_Float16)a0.x; af[1] = (_Float16)a0.y;
    af[2] = (_Float16)a0.z; af[3] = (_Float16)a0.w;
    af[4] = (_Float16)a1.x; af[5] = (_Float16)a1.y;
    af[6] = (_Float16)a1.z; af[7] = (_Float16)a1.w;
    f16x8 Bh[8];
    #pragma unroll
    for (int nt = 0; nt < 8; nt++)
      Bh[nt] = BH[(size_t)(slab * 8 + nt) * 64 + lane];
    #pragma unroll
    for (int nt = 0; nt < 8; nt++)
      acc[nt] = __builtin_amdgcn_mfma_f32_16x16x32_f16(af, Bh[nt], acc[nt], 0, 0, 0);
  }

  float* out = (which == 0) ? o0 : (which == 1) ? o1 : o2;
  #pragma unroll
  for (int nt = 0; nt < 8; nt++) {
    int col = nt * 16 + l15;
    float bias = (pb != nullptr && which == 2) ? pb[col] : 0.f;
    #pragma unroll
    for (int r = 0; r < 4; r++) {
      int row = m0 + wave * 16 + q * 4 + r;
      if (row < R_) out[(size_t)row * 128 + col] = acc[nt][r] + bias;
    }
  }
}

// ---------------- SpMM: out = [skip +] relu(s + A@t); optional fused 128->3 GEMV ----------------
// First 8 ELL indices preloaded as int4s -> all gathers issue together (latency fix).
// Adds applied predicated in ascending i order (bit-exact vs serial loop).
__global__ __launch_bounds__(256) void k_spmm(
    const float* __restrict__ sb, const float* __restrict__ tb,
    const int* __restrict__ cols, const int* __restrict__ cnts,
    const float* __restrict__ skipb, float* __restrict__ outb,
    const float* __restrict__ gw0, const float* __restrict__ gw1,
    float* __restrict__ gsb, float* __restrict__ gtb, int fuse_gf) {
  int tid = threadIdx.x;
  int grp = tid >> 5, ln = tid & 31;
  int row = blockIdx.x * 8 + grp;           // 1233 * 8 = 9864 exact
  int b = row / N_;
  size_t tbase = (size_t)b * N_;
  const float4* sb4 = (const float4*)sb;
  const float4* tb4 = (const float4*)tb;
  const int* cp = cols + (size_t)row * ELLW;   // row stride 384 B -> int4-aligned
  int4 ci0 = *(const int4*)cp;
  int4 ci1 = *(const int4*)(cp + 4);
  int cnt = cnts[row];
  float4 acc = sb4[(size_t)row*32 + ln];
  int idx[8] = {ci0.x, ci0.y, ci0.z, ci0.w, ci1.x, ci1.y, ci1.z, ci1.w};
  float4 g[8];
  #pragma unroll
  for (int i = 0; i < 8; i++) {
    int c = idx[i];
    c = (c >= 0 && c < N_) ? c : 0;          // clamp garbage past cnt (value unused)
    g[i] = tb4[(tbase + c)*32 + ln];
  }
  #pragma unroll
  for (int i = 0; i < 8; i++) {
    if (i < cnt) {
      acc.x += g[i].x; acc.y += g[i].y; acc.z += g[i].z; acc.w += g[i].w;
    }
  }
  for (int i = 8; i < cnt; i++) {
    float4 v = tb4[(tbase + cp[i])*32 + ln];
    acc.x += v.x; acc.y += v.y; acc.z += v.z; acc.w += v.w;
  }
  acc.x = fmaxf(acc.x, 0.f); acc.y = fmaxf(acc.y, 0.f);
  acc.z = fmaxf(acc.z, 0.f); acc.w = fmaxf(acc.w, 0.f);
  if (skipb) {
    float4 sv = ((const float4*)skipb)[(size_t)row*32 + ln];
    acc.x += sv.x; acc.y += sv.y; acc.z += sv.z; acc.w += sv.w;
  }
  if (!fuse_gf) {
    ((float4*)outb)[(size_t)row*32 + ln] = acc;
    return;
  }
  float av[4] = {acc.x, acc.y, acc.z, acc.w};
  int j0 = ln * 4;
  float p0 = 0.f, p1 = 0.f, p2 = 0.f, q0 = 0.f, q1 = 0.f, q2 = 0.f;
  #pragma unroll
  for (int u = 0; u < 4; u++) {
    int j = j0 + u;
    p0 += av[u] * gw0[j*3+0]; p1 += av[u] * gw0[j*3+1]; p2 += av[u] * gw0[j*3+2];
    q0 += av[u] * gw1[j*3+0]; q1 += av[u] * gw1[j*3+1]; q2 += av[u] * gw1[j*3+2];
  }
  #pragma unroll
  for (int off = 16; off >= 1; off >>= 1) {
    p0 += __shfl_xor(p0, off); p1 += __shfl_xor(p1, off); p2 += __shfl_xor(p2, off);
    q0 += __shfl_xor(q0, off); q1 += __shfl_xor(q1, off); q2 += __shfl_xor(q2, off);
  }
  if (ln == 0) {
    gsb[(size_t)row*128 + 0] = p0; gsb[(size_t)row*128 + 1] = p1; gsb[(size_t)row*128 + 2] = p2;
    gtb[(size_t)row*128 + 0] = q0; gtb[(size_t)row*128 + 1] = q1; gtb[(size_t)row*128 + 2] = q2;
  }
}

// ---------------- final: out = pos + tanh(relu(s + A@t)) ----------------
__global__ __launch_bounds__(256) void k_gf_final(
    const float* __restrict__ sb, const float* __restrict__ tb,
    const int* __restrict__ cols, const int* __restrict__ cnts,
    const float* __restrict__ pos, float* __restrict__ out) {
  int wave = threadIdx.x >> 6, lane = threadIdx.x & 63;
  int row = blockIdx.x * 4 + wave;          // grid 2466
  if (lane >= 3) return;
  int b = row / N_;
  float acc = sb[(size_t)row*128 + lane];
  int cnt = cnts[row];
  const int* cp = cols + (size_t)row * ELLW;
  size_t tbase = (size_t)b * N_;
  for (int i = 0; i < cnt; i++)
    acc += tb[(tbase + cp[i])*128 + lane];
  float v = tanhf(fmaxf(acc, 0.f));
  out[(size_t)row*3 + lane] = pos[(size_t)row*3 + lane] + v;
}

extern "C" void kernel_launch(void* const* d_in, const int* in_sizes, int n_in,
                              void* d_out, int out_size, void* d_ws, size_t ws_size,
                              hipStream_t stream) {
  const float* conv2_3 = (const float*)d_in[0];
  const float* conv3_4 = (const float*)d_in[1];
  const float* conv4_6 = (const float*)d_in[2];
  const float* conv5_3 = (const float*)d_in[3];
  const float* pos     = (const float*)d_in[4];
  const float* vf      = (const float*)d_in[5];
  const float* adj     = (const float*)d_in[6];
  const float* lin_w   = (const float*)d_in[7];
  const float* lin_b   = (const float*)d_in[8];
  const float* r_pb[3]  = {(const float*)d_in[10], (const float*)d_in[16], (const float*)d_in[22]};
  const float* gf_w0 = (const float*)d_in[27];
  const float* gf_w1 = (const float*)d_in[28];
  float* out = (float*)d_out;

  // ---- workspace layout ----
  const size_t TRH_TOT = 6021120;                 // f16 map elems total
  const size_t ROWF    = (size_t)R_ * 128;        // 1,262,592
  const size_t XCAT_F  = (size_t)R_ * 288;        // 2,840,832
  const size_t LINW_E  = 491520;                  // shorts
  const size_t RESW_E  = 307200;                  // shorts

  unsigned short* trh0 = (unsigned short*)d_ws;
  unsigned short* trh1 = trh0 + (size_t)4*256*3136;
  unsigned short* trh2 = trh1 + (size_t)4*512*784;
  unsigned short* trh3 = trh2 + (size_t)4*1024*196;
  int*   ell_cnt  = (int*)(trh3 + (size_t)4*2048*49);
  int*   ell_cols = ell_cnt + R_;
  unsigned short* whf = (unsigned short*)(ell_cols + (size_t)R_*ELLW);
  unsigned short* wrf = whf + LINW_E;
  float* part = (float*)(wrf + RESW_E + 512);   // +512 shorts pad -> 16B-aligned region

  size_t fixed_f = TRH_TOT/2 + (size_t)R_*(ELLW+1) + (LINW_E + RESW_E + 512)/2;
  size_t need8 = (fixed_f + (size_t)8*ROWF + XCAT_F + 5*ROWF) * sizeof(float);
  int nsplit = (ws_size >= need8) ? 8 : 4;
  int kchunk = 3840 / nsplit;

  float* xcat = part + (size_t)nsplit * ROWF;
  float* sb   = xcat + XCAT_F;
  float* tb   = sb   + ROWF;
  float* skip = tb   + ROWF;
  float* hb   = skip + ROWF;
  float* xc   = hb   + ROWF;

  WMats wm;
  for (int rb = 0; rb < 3; rb++) {
    wm.p[rb*5 + 0] = (const float*)d_in[11 + 6*rb];  // w00
    wm.p[rb*5 + 1] = (const float*)d_in[12 + 6*rb];  // w01
    wm.p[rb*5 + 2] = (const float*)d_in[9  + 6*rb];  // pw
    wm.p[rb*5 + 3] = (const float*)d_in[13 + 6*rb];  // w10
    wm.p[rb*5 + 4] = (const float*)d_in[14 + 6*rb];  // w11
  }
  const int RB_BASE[3] = {0, 143360, 225280};

  // D0: transposes(->f16, vectorized 64x64) + ELL + all W f16 splits
  k_pre<<<4830, 256, 0, stream>>>(conv2_3, conv3_4, conv4_6, conv5_3,
                                  trh0, trh1, trh2, trh3,
                                  adj, ell_cols, ell_cnt,
                                  lin_w, whf, wm, wrf);

  // D1: split-K f16 MFMA align GEMM
  k_align_mfma<<<dim3(78, nsplit), 512, 0, stream>>>(trh0, trh1, trh2, trh3, pos,
                                                     whf, part, kchunk);

  // D2: reduce partials + concat (float4, 8 rows/block)
  k_reduce<<<1233, 256, 0, stream>>>(part, lin_b, vf, pos, xcat, nsplit);

  // D3..: three residual graph-conv blocks, all GEMMs via single-pass f16 MFMA
  for (int rb = 0; rb < 3; rb++) {
    if (rb == 0) {
      k_gemm_mfma<9><<<dim3(155, 3), 256, 0, stream>>>(
          xcat, 288, wrf + RB_BASE[0], 36864, r_pb[0], sb, tb, skip);
    } else {
      k_gemm_mfma<4><<<dim3(155, 3), 256, 0, stream>>>(
          xc, 128, wrf + RB_BASE[rb], 16384, r_pb[rb], sb, tb, skip);
    }
    k_spmm<<<1233, 256, 0, stream>>>(sb, tb, ell_cols, ell_cnt, nullptr, hb,
                                     nullptr, nullptr, nullptr, nullptr, 0);
    int g2off = RB_BASE[rb] + ((rb == 0) ? 110592 : 3 * 16384);
    k_gemm_mfma<4><<<dim3(155, 2), 256, 0, stream>>>(
        hb, 128, wrf + g2off, 16384, nullptr, sb, tb, nullptr);
    if (rb < 2) {
      k_spmm<<<1233, 256, 0, stream>>>(sb, tb, ell_cols, ell_cnt, skip, xc,
                                       nullptr, nullptr, nullptr, nullptr, 0);
    } else {
      k_spmm<<<1233, 256, 0, stream>>>(sb, tb, ell_cols, ell_cnt, skip, nullptr,
                                       gf_w0, gf_w1, hb, xc, 1);   // gsb=hb, gtb=xc
    }
  }

  // final: out = pos + tanh(relu(gsb + A@gtb))
  k_gf_final<<<2466, 256, 0, stream>>>(hb, xc, ell_cols, ell_cnt, pos, out);
}

// Round 20
// 411.631 us; speedup vs baseline: 1.2791x; 1.0400x over previous
//
#include <hip/hip_runtime.h>
#include <cmath>

#define B_   4
#define N_   2466
#define R_   (B_*N_)     // 9864
#define ELLW 96

typedef _Float16 f16x8 __attribute__((ext_vector_type(8)));
typedef __attribute__((ext_vector_type(4))) float f32x4;

__device__ __forceinline__ unsigned short f16_bits(float x) {
  union { _Float16 h; unsigned short u; } c;
  c.h = (_Float16)x;          // RNE
  return c.u;
}

struct WMats { const float* p[15]; };   // rb-major: w00,w01,pw,w10,w11

// Fragment-order layout (lin_w and res weights), f16 single-pass:
// e = ((slab*8 + nt)*64 + lane)*8 + j ; k = slab*32 + (lane>>4)*8 + j ; n = nt*16 + (lane&15)
// Feature maps transposed to NHWC f16 (bit-identical: align weight w ∈ {0,1} exactly).

// ============ fused pre-kernel: transposes(->f16, 64x64 tiles) + ELL + W f16 splits ============
__global__ __launch_bounds__(256) void k_pre(
    const float* __restrict__ c2, const float* __restrict__ c3,
    const float* __restrict__ c4, const float* __restrict__ c5,
    unsigned short* __restrict__ t0, unsigned short* __restrict__ t1,
    unsigned short* __restrict__ t2, unsigned short* __restrict__ t3,
    const float* __restrict__ adj, int* __restrict__ cols, int* __restrict__ cnts,
    const float* __restrict__ lin_w,
    unsigned short* __restrict__ whf,
    WMats wm,
    unsigned short* __restrict__ wrf) {
  __shared__ float t[64][66];
  int bid = blockIdx.x;
  int tid = threadIdx.x;
  if (bid < 1584) {
    const float* in; unsigned short* out; int C, P, npb, ncb, rem;
    if (bid < 784)       { in = c2; out = t0; C = 256;  P = 3136; npb = 49; ncb = 4;  rem = bid; }
    else if (bid < 1200) { in = c3; out = t1; C = 512;  P = 784;  npb = 13; ncb = 8;  rem = bid - 784; }
    else if (bid < 1456) { in = c4; out = t2; C = 1024; P = 196;  npb = 4;  ncb = 16; rem = bid - 1200; }
    else                 { in = c5; out = t3; C = 2048; P = 49;   npb = 1;  ncb = 32; rem = bid - 1456; }
    int pb = rem % npb; int tq = rem / npb; int cb = tq % ncb; int b = tq / ncb;
    int c0 = cb * 64, p0 = pb * 64;
    #pragma unroll
    for (int i = 0; i < 8; i++) {
      int e = tid + i * 256;
      int c = e >> 5, f2 = e & 31;
      int p = p0 + f2 * 2;
      float2 v = make_float2(0.f, 0.f);
      const float* src = in + ((size_t)b * C + (c0 + c)) * P + p;
      if (p + 1 < P)      v = *(const float2*)src;
      else if (p < P)     v.x = *src;
      *(float2*)&t[c][f2 * 2] = v;
    }
    __syncthreads();
    int jj = tid & 15, c4i = jj * 4;
    #pragma unroll
    for (int pass = 0; pass < 4; pass++) {
      int pp = pass * 16 + (tid >> 4);
      int px = p0 + pp;
      if (px < P) {
        ushort4 o;
        o.x = f16_bits(t[c4i + 0][pp]);
        o.y = f16_bits(t[c4i + 1][pp]);
        o.z = f16_bits(t[c4i + 2][pp]);
        o.w = f16_bits(t[c4i + 3][pp]);
        *(ushort4*)&out[((size_t)b * P + px) * C + c0 + c4i] = o;
      }
    }
  } else if (bid < 4050) {
    int wave = tid >> 6, lane = tid & 63;
    int row = (bid - 1584) * 4 + wave;
    const float* Ar = adj + (size_t)row * N_;
    int* cp = cols + (size_t)row * ELLW;
    unsigned long long below = (lane == 63) ? 0xFFFFFFFFFFFFFFFFull >> 1
                                            : ((1ull << lane) - 1ull);
    float4 v[10];
    #pragma unroll
    for (int i0 = 0; i0 < 10; i0++) {
      int j0 = i0 * 256 + lane * 4;
      if (j0 + 3 < N_) {
        v[i0] = *(const float4*)&Ar[j0];
      } else {
        v[i0] = make_float4(0.f, 0.f, 0.f, 0.f);
        if (j0     < N_) v[i0].x = Ar[j0];
        if (j0 + 1 < N_) v[i0].y = Ar[j0+1];
        if (j0 + 2 < N_) v[i0].z = Ar[j0+2];
      }
    }
    int base = 0;
    #pragma unroll
    for (int i0 = 0; i0 < 10; i0++) {
      int j0 = i0 * 256 + lane * 4;
      bool nz0 = (j0     < N_) && (v[i0].x != 0.f);
      bool nz1 = (j0 + 1 < N_) && (v[i0].y != 0.f);
      bool nz2 = (j0 + 2 < N_) && (v[i0].z != 0.f);
      bool nz3 = (j0 + 3 < N_) && (v[i0].w != 0.f);
      unsigned long long m0 = __ballot(nz0);
      unsigned long long m1 = __ballot(nz1);
      unsigned long long m2 = __ballot(nz2);
      unsigned long long m3 = __ballot(nz3);
      int pre = __popcll(m0 & below) + __popcll(m1 & below)
              + __popcll(m2 & below) + __popcll(m3 & below);
      int p0 = base + pre;
      int p1 = p0 + (nz0 ? 1 : 0);
      int p2 = p1 + (nz1 ? 1 : 0);
      int p3 = p2 + (nz2 ? 1 : 0);
      if (nz0 && p0 < ELLW) cp[p0] = j0;
      if (nz1 && p1 < ELLW) cp[p1] = j0 + 1;
      if (nz2 && p2 < ELLW) cp[p2] = j0 + 2;
      if (nz3 && p3 < ELLW) cp[p3] = j0 + 3;
      base += __popcll(m0) + __popcll(m1) + __popcll(m2) + __popcll(m3);
    }
    if (lane == 0) cnts[row] = (base > ELLW) ? ELLW : base;
  } else if (bid < 4530) {
    int b = bid - 4050;
    int e0 = (b * 256 + tid) * 4;
    #pragma unroll
    for (int u = 0; u < 4; u++) {
      int e = e0 + u;
      int j = e & 7;
      int lane = (e >> 3) & 63;
      int nt = (e >> 9) & 7;
      int slab = e >> 12;
      int k = slab * 32 + ((lane >> 4) << 3) + j;
      int n = nt * 16 + (lane & 15);
      whf[e] = f16_bits(lin_w[(size_t)k * 128 + n]);
    }
  } else {
    int b = bid - 4530;
    int e0 = (b * 256 + tid) * 4;
    #pragma unroll
    for (int u = 0; u < 4; u++) {
      int e = e0 + u;
      int rb, mat, rem, K;
      if (e < 143360) {
        rb = 0;
        if (e < 110592) { mat = e / 36864; rem = e - mat * 36864; K = 259; }
        else { int tt = e - 110592; mat = 3 + tt / 16384; rem = tt & 16383; K = 128; }
      } else {
        int tt = e - 143360;
        rb = 1 + tt / 81920;
        int r2 = tt % 81920;
        mat = r2 / 16384; rem = r2 & 16383; K = 128;
      }
      int j = rem & 7, lane = (rem >> 3) & 63, nt = (rem >> 9) & 7, slab = rem >> 12;
      int k = slab * 32 + ((lane >> 4) << 3) + j;
      int n = nt * 16 + (lane & 15);
      float x = (k < K) ? wm.p[rb * 5 + mat][(size_t)k * 128 + n] : 0.f;
      wrf[e] = f16_bits(x);
    }
  }
}

// ============ split-K vertex-align gather (f16 maps) + f16 MFMA GEMM ============
// 256-thread blocks, 4 waves x 2 m-tiles -> M=128/block: each B-fragment load feeds 2 MFMAs
// (halves per-block B L2 traffic vs 1 tile/wave; f16 made B the larger cycle share).
__global__ __launch_bounds__(256) void k_align_mfma(
    const unsigned short* __restrict__ tr0, const unsigned short* __restrict__ tr1,
    const unsigned short* __restrict__ tr2, const unsigned short* __restrict__ tr3,
    const float* __restrict__ pos,
    const unsigned short* __restrict__ whf,
    float* __restrict__ part, int kchunk) {
  int tid  = threadIdx.x;
  int wave = tid >> 6, lane = tid & 63;
  int q    = lane >> 4, l15 = lane & 15;
  int m0   = blockIdx.x * 128;
  int s    = blockIdx.y;

  int zero[2][4]; int base[2][4];
  #pragma unroll
  for (int u = 0; u < 2; u++) {
    int mrow = m0 + (wave * 2 + u) * 16 + l15;
    int rowc = (mrow < R_) ? mrow : 0;
    int b = rowc / N_;
    float px = pos[rowc*3+0], py = pos[rowc*3+1], pz = pos[rowc*3+2];
    float hh = fminf(fmaxf(248.f*(py/pz)    + 111.5f, 0.f), 223.f);
    float wc = fminf(fmaxf(248.f*(px/(-pz)) + 111.5f, 0.f), 223.f);
    const int Sarr[4] = {56, 28, 14, 7};
    const int Carr[4] = {256, 512, 1024, 2048};
    #pragma unroll
    for (int sc = 0; sc < 4; sc++) {
      int S = Sarr[sc], C = Carr[sc];
      float dv = 224.f / (float)S;
      float x = hh / dv, y = wc / dv;
      int x1 = (int)floorf(x), y1 = (int)floorf(y);
      int x2 = min((int)ceilf(x), S - 1), y2 = min((int)ceilf(y), S - 1);
      int w = (x2 - x1) * (y2 - y1);              // ∈ {0,1}
      zero[u][sc] = (mrow >= R_) || (w == 0);
      base[u][sc] = (b * S * S + x1 * S + y1) * C;
    }
  }

  f32x4 acc[2][8];
  #pragma unroll
  for (int u = 0; u < 2; u++)
    #pragma unroll
    for (int nt = 0; nt < 8; nt++) acc[u][nt] = (f32x4){0.f, 0.f, 0.f, 0.f};

  const f16x8* BH = (const f16x8*)whf;

  int kbeg = s * kchunk, kend = kbeg + kchunk;
  #pragma unroll 1
  for (int k0 = kbeg; k0 < kend; k0 += 32) {
    const unsigned short* tr; int off, sI;
    if (k0 < 256)       { tr = tr0; off = 0;    sI = 0; }
    else if (k0 < 768)  { tr = tr1; off = 256;  sI = 1; }
    else if (k0 < 1792) { tr = tr2; off = 768;  sI = 2; }
    else                { tr = tr3; off = 1792; sI = 3; }

    f16x8 af[2];
    #pragma unroll
    for (int u = 0; u < 2; u++) {
      af[u] = *(const f16x8*)(tr + base[u][sI] + (k0 - off) + q * 8);
      if (zero[u][sI]) af[u] = (f16x8)(_Float16)0;
    }

    int slab = k0 >> 5;
    f16x8 Bh[8];
    #pragma unroll
    for (int nt = 0; nt < 8; nt++)
      Bh[nt] = BH[(size_t)(slab * 8 + nt) * 64 + lane];
    #pragma unroll
    for (int nt = 0; nt < 8; nt++) {
      acc[0][nt] = __builtin_amdgcn_mfma_f32_16x16x32_f16(af[0], Bh[nt], acc[0][nt], 0, 0, 0);
      acc[1][nt] = __builtin_amdgcn_mfma_f32_16x16x32_f16(af[1], Bh[nt], acc[1][nt], 0, 0, 0);
    }
  }

  // C/D layout: col = lane&15, row_in_tile = q*4 + reg
  #pragma unroll
  for (int u = 0; u < 2; u++)
    #pragma unroll
    for (int nt = 0; nt < 8; nt++)
      #pragma unroll
      for (int r = 0; r < 4; r++) {
        int row = m0 + (wave * 2 + u) * 16 + q * 4 + r;
        if (row < R_)
          part[((size_t)s * R_ + row) * 128 + nt * 16 + l15] = acc[u][nt][r];
      }
}

// ---------------- reduce partials + bias -> xcat (proj|vf|pos|0pad), float4, 8 rows/block ----------------
__global__ __launch_bounds__(256) void k_reduce(
    const float* __restrict__ part, const float* __restrict__ lin_b,
    const float* __restrict__ vf, const float* __restrict__ pos,
    float* __restrict__ xcat, int nsplit) {
  int grp = threadIdx.x >> 5, ln = threadIdx.x & 31;
  int row = blockIdx.x * 8 + grp;           // 1233*8 = 9864
  float4 acc = ((const float4*)lin_b)[ln];
  for (int s = 0; s < nsplit; s++) {
    float4 pv = ((const float4*)part)[((size_t)s * R_ + row) * 32 + ln];
    acc.x += pv.x; acc.y += pv.y; acc.z += pv.z; acc.w += pv.w;
  }
  float4* xr = (float4*)(xcat + (size_t)row * 288);
  xr[ln] = acc;
  xr[32 + ln] = ((const float4*)vf)[(size_t)row * 32 + ln];
  if (ln < 8) {
    float4 z = make_float4(0.f, 0.f, 0.f, 0.f);
    if (ln == 0) {
      z.x = pos[(size_t)row * 3 + 0];
      z.y = pos[(size_t)row * 3 + 1];
      z.z = pos[(size_t)row * 3 + 2];
    }
    xr[64 + ln] = z;
  }
}

// ============ f16 MFMA GEMM: out[which] = X @ W[which] (+pb for which==2) ============
template<int SLABS>
__global__ __launch_bounds__(256) void k_gemm_mfma(
    const float* __restrict__ X, int ldx,
    const unsigned short* __restrict__ wf,
    int matStride, const float* __restrict__ pb,
    float* __restrict__ o0, float* __restrict__ o1, float* __restrict__ o2) {
  int tid = threadIdx.x;
  int wave = tid >> 6, lane = tid & 63;
  int q = lane >> 4, l15 = lane & 15;
  int which = blockIdx.y;
  int m0 = blockIdx.x * 64;
  int mrow = m0 + wave * 16 + l15;
  int rowc = (mrow < R_) ? mrow : (R_ - 1);
  const float* xrow = X + (size_t)rowc * ldx + q * 8;

  const f16x8* BH = (const f16x8*)(wf + (size_t)which * matStride);

  f32x4 acc[8];
  #pragma unroll
  for (int nt = 0; nt < 8; nt++) acc[nt] = (f32x4){0.f, 0.f, 0.f, 0.f};

  #pragma unroll 1
  for (int slab = 0; slab < SLABS; slab++) {
    const float* src = xrow + slab * 32;
    float4 a0 = *(const float4*)src;
    float4 a1 = *(const float4*)(src + 4);
    f16x8 af;
    af[0] = (_Float16)a0.x; af[1] = (_Float16)a0.y;
    af[2] = (_Float16)a0.z; af[3] = (_Float16)a0.w;
    af[4] = (_Float16)a1.x; af[5] = (_Float16)a1.y;
    af[6] = (_Float16)a1.z; af[7] = (_Float16)a1.w;
    f16x8 Bh[8];
    #pragma unroll
    for (int nt = 0; nt < 8; nt++)
      Bh[nt] = BH[(size_t)(slab * 8 + nt) * 64 + lane];
    #pragma unroll
    for (int nt = 0; nt < 8; nt++)
      acc[nt] = __builtin_amdgcn_mfma_f32_16x16x32_f16(af, Bh[nt], acc[nt], 0, 0, 0);
  }

  float* out = (which == 0) ? o0 : (which == 1) ? o1 : o2;
  #pragma unroll
  for (int nt = 0; nt < 8; nt++) {
    int col = nt * 16 + l15;
    float bias = (pb != nullptr && which == 2) ? pb[col] : 0.f;
    #pragma unroll
    for (int r = 0; r < 4; r++) {
      int row = m0 + wave * 16 + q * 4 + r;
      if (row < R_) out[(size_t)row * 128 + col] = acc[nt][r] + bias;
    }
  }
}

// ---------------- SpMM: out = [skip +] relu(s + A@t); optional fused 128->3 GEMV ----------------
// First 12 ELL indices preloaded (3x int4) -> gathers issue together; covers ~96% of rows.
__global__ __launch_bounds__(256) void k_spmm(
    const float* __restrict__ sb, const float* __restrict__ tb,
    const int* __restrict__ cols, const int* __restrict__ cnts,
    const float* __restrict__ skipb, float* __restrict__ outb,
    const float* __restrict__ gw0, const float* __restrict__ gw1,
    float* __restrict__ gsb, float* __restrict__ gtb, int fuse_gf) {
  int tid = threadIdx.x;
  int grp = tid >> 5, ln = tid & 31;
  int row = blockIdx.x * 8 + grp;           // 1233 * 8 = 9864 exact
  int b = row / N_;
  size_t tbase = (size_t)b * N_;
  const float4* sb4 = (const float4*)sb;
  const float4* tb4 = (const float4*)tb;
  const int* cp = cols + (size_t)row * ELLW;   // row stride 384 B -> int4-aligned
  int4 ci0 = *(const int4*)cp;
  int4 ci1 = *(const int4*)(cp + 4);
  int4 ci2 = *(const int4*)(cp + 8);
  int cnt = cnts[row];
  float4 acc = sb4[(size_t)row*32 + ln];
  int idx[12] = {ci0.x, ci0.y, ci0.z, ci0.w, ci1.x, ci1.y, ci1.z, ci1.w,
                 ci2.x, ci2.y, ci2.z, ci2.w};
  float4 g[12];
  #pragma unroll
  for (int i = 0; i < 12; i++) {
    int c = idx[i];
    c = (c >= 0 && c < N_) ? c : 0;          // clamp garbage past cnt (value unused)
    g[i] = tb4[(tbase + c)*32 + ln];
  }
  #pragma unroll
  for (int i = 0; i < 12; i++) {
    if (i < cnt) {
      acc.x += g[i].x; acc.y += g[i].y; acc.z += g[i].z; acc.w += g[i].w;
    }
  }
  for (int i = 12; i < cnt; i++) {
    float4 v = tb4[(tbase + cp[i])*32 + ln];
    acc.x += v.x; acc.y += v.y; acc.z += v.z; acc.w += v.w;
  }
  acc.x = fmaxf(acc.x, 0.f); acc.y = fmaxf(acc.y, 0.f);
  acc.z = fmaxf(acc.z, 0.f); acc.w = fmaxf(acc.w, 0.f);
  if (skipb) {
    float4 sv = ((const float4*)skipb)[(size_t)row*32 + ln];
    acc.x += sv.x; acc.y += sv.y; acc.z += sv.z; acc.w += sv.w;
  }
  if (!fuse_gf) {
    ((float4*)outb)[(size_t)row*32 + ln] = acc;
    return;
  }
  float av[4] = {acc.x, acc.y, acc.z, acc.w};
  int j0 = ln * 4;
  float p0 = 0.f, p1 = 0.f, p2 = 0.f, q0 = 0.f, q1 = 0.f, q2 = 0.f;
  #pragma unroll
  for (int u = 0; u < 4; u++) {
    int j = j0 + u;
    p0 += av[u] * gw0[j*3+0]; p1 += av[u] * gw0[j*3+1]; p2 += av[u] * gw0[j*3+2];
    q0 += av[u] * gw1[j*3+0]; q1 += av[u] * gw1[j*3+1]; q2 += av[u] * gw1[j*3+2];
  }
  #pragma unroll
  for (int off = 16; off >= 1; off >>= 1) {
    p0 += __shfl_xor(p0, off); p1 += __shfl_xor(p1, off); p2 += __shfl_xor(p2, off);
    q0 += __shfl_xor(q0, off); q1 += __shfl_xor(q1, off); q2 += __shfl_xor(q2, off);
  }
  if (ln == 0) {
    gsb[(size_t)row*128 + 0] = p0; gsb[(size_t)row*128 + 1] = p1; gsb[(size_t)row*128 + 2] = p2;
    gtb[(size_t)row*128 + 0] = q0; gtb[(size_t)row*128 + 1] = q1; gtb[(size_t)row*128 + 2] = q2;
  }
}

// ---------------- final: out = pos + tanh(relu(s + A@t)), batched gathers ----------------
__global__ __launch_bounds__(256) void k_gf_final(
    const float* __restrict__ sb, const float* __restrict__ tb,
    const int* __restrict__ cols, const int* __restrict__ cnts,
    const float* __restrict__ pos, float* __restrict__ out) {
  int wave = threadIdx.x >> 6, lane = threadIdx.x & 63;
  int row = blockIdx.x * 4 + wave;          // grid 2466
  if (lane >= 3) return;
  int b = row / N_;
  size_t tbase = (size_t)b * N_;
  const int* cp = cols + (size_t)row * ELLW;
  int4 ci0 = *(const int4*)cp;
  int4 ci1 = *(const int4*)(cp + 4);
  int4 ci2 = *(const int4*)(cp + 8);
  int cnt = cnts[row];
  float acc = sb[(size_t)row*128 + lane];
  int idx[12] = {ci0.x, ci0.y, ci0.z, ci0.w, ci1.x, ci1.y, ci1.z, ci1.w,
                 ci2.x, ci2.y, ci2.z, ci2.w};
  float g[12];
  #pragma unroll
  for (int i = 0; i < 12; i++) {
    int c = idx[i];
    c = (c >= 0 && c < N_) ? c : 0;
    g[i] = tb[(tbase + c)*128 + lane];
  }
  #pragma unroll
  for (int i = 0; i < 12; i++)
    if (i < cnt) acc += g[i];
  for (int i = 12; i < cnt; i++)
    acc += tb[(tbase + cp[i])*128 + lane];
  float v = tanhf(fmaxf(acc, 0.f));
  out[(size_t)row*3 + lane] = pos[(size_t)row*3 + lane] + v;
}

extern "C" void kernel_launch(void* const* d_in, const int* in_sizes, int n_in,
                              void* d_out, int out_size, void* d_ws, size_t ws_size,
                              hipStream_t stream) {
  const float* conv2_3 = (const float*)d_in[0];
  const float* conv3_4 = (const float*)d_in[1];
  const float* conv4_6 = (const float*)d_in[2];
  const float* conv5_3 = (const float*)d_in[3];
  const float* pos     = (const float*)d_in[4];
  const float* vf      = (const float*)d_in[5];
  const float* adj     = (const float*)d_in[6];
  const float* lin_w   = (const float*)d_in[7];
  const float* lin_b   = (const float*)d_in[8];
  const float* r_pb[3]  = {(const float*)d_in[10], (const float*)d_in[16], (const float*)d_in[22]};
  const float* gf_w0 = (const float*)d_in[27];
  const float* gf_w1 = (const float*)d_in[28];
  float* out = (float*)d_out;

  // ---- workspace layout ----
  const size_t TRH_TOT = 6021120;                 // f16 map elems total
  const size_t ROWF    = (size_t)R_ * 128;        // 1,262,592
  const size_t XCAT_F  = (size_t)R_ * 288;        // 2,840,832
  const size_t LINW_E  = 491520;                  // shorts
  const size_t RESW_E  = 307200;                  // shorts

  unsigned short* trh0 = (unsigned short*)d_ws;
  unsigned short* trh1 = trh0 + (size_t)4*256*3136;
  unsigned short* trh2 = trh1 + (size_t)4*512*784;
  unsigned short* trh3 = trh2 + (size_t)4*1024*196;
  int*   ell_cnt  = (int*)(trh3 + (size_t)4*2048*49);
  int*   ell_cols = ell_cnt + R_;
  unsigned short* whf = (unsigned short*)(ell_cols + (size_t)R_*ELLW);
  unsigned short* wrf = whf + LINW_E;
  float* part = (float*)(wrf + RESW_E + 512);   // +512 shorts pad -> 16B-aligned

  size_t fixed_f = TRH_TOT/2 + (size_t)R_*(ELLW+1) + (LINW_E + RESW_E + 512)/2;
  size_t need8 = (fixed_f + (size_t)8*ROWF + XCAT_F + 5*ROWF) * sizeof(float);
  int nsplit = (ws_size >= need8) ? 8 : 4;
  int kchunk = 3840 / nsplit;

  float* xcat = part + (size_t)nsplit * ROWF;
  float* sb   = xcat + XCAT_F;
  float* tb   = sb   + ROWF;
  float* skip = tb   + ROWF;
  float* hb   = skip + ROWF;
  float* xc   = hb   + ROWF;

  WMats wm;
  for (int rb = 0; rb < 3; rb++) {
    wm.p[rb*5 + 0] = (const float*)d_in[11 + 6*rb];  // w00
    wm.p[rb*5 + 1] = (const float*)d_in[12 + 6*rb];  // w01
    wm.p[rb*5 + 2] = (const float*)d_in[9  + 6*rb];  // pw
    wm.p[rb*5 + 3] = (const float*)d_in[13 + 6*rb];  // w10
    wm.p[rb*5 + 4] = (const float*)d_in[14 + 6*rb];  // w11
  }
  const int RB_BASE[3] = {0, 143360, 225280};

  // D0: transposes(->f16) + ELL + all W f16 splits
  k_pre<<<4830, 256, 0, stream>>>(conv2_3, conv3_4, conv4_6, conv5_3,
                                  trh0, trh1, trh2, trh3,
                                  adj, ell_cols, ell_cnt,
                                  lin_w, whf, wm, wrf);

  // D1: split-K f16 MFMA align GEMM (2 m-tiles/wave, M=128)
  k_align_mfma<<<dim3(78, nsplit), 256, 0, stream>>>(trh0, trh1, trh2, trh3, pos,
                                                     whf, part, kchunk);

  // D2: reduce partials + concat (float4, 8 rows/block)
  k_reduce<<<1233, 256, 0, stream>>>(part, lin_b, vf, pos, xcat, nsplit);

  // D3..: three residual graph-conv blocks, all GEMMs via single-pass f16 MFMA
  for (int rb = 0; rb < 3; rb++) {
    if (rb == 0) {
      k_gemm_mfma<9><<<dim3(155, 3), 256, 0, stream>>>(
          xcat, 288, wrf + RB_BASE[0], 36864, r_pb[0], sb, tb, skip);
    } else {
      k_gemm_mfma<4><<<dim3(155, 3), 256, 0, stream>>>(
          xc, 128, wrf + RB_BASE[rb], 16384, r_pb[rb], sb, tb, skip);
    }
    k_spmm<<<1233, 256, 0, stream>>>(sb, tb, ell_cols, ell_cnt, nullptr, hb,
                                     nullptr, nullptr, nullptr, nullptr, 0);
    int g2off = RB_BASE[rb] + ((rb == 0) ? 110592 : 3 * 16384);
    k_gemm_mfma<4><<<dim3(155, 2), 256, 0, stream>>>(
        hb, 128, wrf + g2off, 16384, nullptr, sb, tb, nullptr);
    if (rb < 2) {
      k_spmm<<<1233, 256, 0, stream>>>(sb, tb, ell_cols, ell_cnt, skip, xc,
                                       nullptr, nullptr, nullptr, nullptr, 0);
    } else {
      k_spmm<<<1233, 256, 0, stream>>>(sb, tb, ell_cols, ell_cnt, skip, nullptr,
                                       gf_w0, gf_w1, hb, xc, 1);   // gsb=hb, gtb=xc
    }
  }

  // final: out = pos + tanh(relu(gsb + A@gtb))
  k_gf_final<<<2466, 256, 0, stream>>>(hb, xc, ell_cols, ell_cnt, pos, out);
}

// Round 21
// 381.844 us; speedup vs baseline: 1.3789x; 1.0780x over previous
//
#include <hip/hip_runtime.h>
#include <cmath>

#define B_   4
#define N_   2466
#define R_   (B_*N_)     // 9864
#define ELLW 96

typedef _Float16 f16x8 __attribute__((ext_vector_type(8)));
typedef _Float16 f16x4 __attribute__((ext_vector_type(4)));
typedef __attribute__((ext_vector_type(4))) float f32x4;

__device__ __forceinline__ unsigned short f16_bits(float x) {
  union { _Float16 h; unsigned short u; } c;
  c.h = (_Float16)x;          // RNE
  return c.u;
}

struct WMats { const float* p[15]; };   // rb-major: w00,w01,pw,w10,w11

// Fragment-order layout (lin_w and res weights), f16 single-pass:
// e = ((slab*8 + nt)*64 + lane)*8 + j ; k = slab*32 + (lane>>4)*8 + j ; n = nt*16 + (lane&15)
// All activations (xcat, s,t,u,v,skip, gsb/gtb) stored f16; adds always fp32.

// ============ fused pre-kernel: transposes(->f16, 64x64 tiles) + ELL + W f16 splits ============
__global__ __launch_bounds__(256) void k_pre(
    const float* __restrict__ c2, const float* __restrict__ c3,
    const float* __restrict__ c4, const float* __restrict__ c5,
    unsigned short* __restrict__ t0, unsigned short* __restrict__ t1,
    unsigned short* __restrict__ t2, unsigned short* __restrict__ t3,
    const float* __restrict__ adj, int* __restrict__ cols, int* __restrict__ cnts,
    const float* __restrict__ lin_w,
    unsigned short* __restrict__ whf,
    WMats wm,
    unsigned short* __restrict__ wrf) {
  __shared__ float t[64][66];
  int bid = blockIdx.x;
  int tid = threadIdx.x;
  if (bid < 1584) {
    const float* in; unsigned short* out; int C, P, npb, ncb, rem;
    if (bid < 784)       { in = c2; out = t0; C = 256;  P = 3136; npb = 49; ncb = 4;  rem = bid; }
    else if (bid < 1200) { in = c3; out = t1; C = 512;  P = 784;  npb = 13; ncb = 8;  rem = bid - 784; }
    else if (bid < 1456) { in = c4; out = t2; C = 1024; P = 196;  npb = 4;  ncb = 16; rem = bid - 1200; }
    else                 { in = c5; out = t3; C = 2048; P = 49;   npb = 1;  ncb = 32; rem = bid - 1456; }
    int pb = rem % npb; int tq = rem / npb; int cb = tq % ncb; int b = tq / ncb;
    int c0 = cb * 64, p0 = pb * 64;
    #pragma unroll
    for (int i = 0; i < 8; i++) {
      int e = tid + i * 256;
      int c = e >> 5, f2 = e & 31;
      int p = p0 + f2 * 2;
      float2 v = make_float2(0.f, 0.f);
      const float* src = in + ((size_t)b * C + (c0 + c)) * P + p;
      if (p + 1 < P)      v = *(const float2*)src;
      else if (p < P)     v.x = *src;
      *(float2*)&t[c][f2 * 2] = v;
    }
    __syncthreads();
    int jj = tid & 15, c4i = jj * 4;
    #pragma unroll
    for (int pass = 0; pass < 4; pass++) {
      int pp = pass * 16 + (tid >> 4);
      int px = p0 + pp;
      if (px < P) {
        ushort4 o;
        o.x = f16_bits(t[c4i + 0][pp]);
        o.y = f16_bits(t[c4i + 1][pp]);
        o.z = f16_bits(t[c4i + 2][pp]);
        o.w = f16_bits(t[c4i + 3][pp]);
        *(ushort4*)&out[((size_t)b * P + px) * C + c0 + c4i] = o;
      }
    }
  } else if (bid < 4050) {
    int wave = tid >> 6, lane = tid & 63;
    int row = (bid - 1584) * 4 + wave;
    const float* Ar = adj + (size_t)row * N_;
    int* cp = cols + (size_t)row * ELLW;
    unsigned long long below = (lane == 63) ? 0xFFFFFFFFFFFFFFFFull >> 1
                                            : ((1ull << lane) - 1ull);
    float4 v[10];
    #pragma unroll
    for (int i0 = 0; i0 < 10; i0++) {
      int j0 = i0 * 256 + lane * 4;
      if (j0 + 3 < N_) {
        v[i0] = *(const float4*)&Ar[j0];
      } else {
        v[i0] = make_float4(0.f, 0.f, 0.f, 0.f);
        if (j0     < N_) v[i0].x = Ar[j0];
        if (j0 + 1 < N_) v[i0].y = Ar[j0+1];
        if (j0 + 2 < N_) v[i0].z = Ar[j0+2];
      }
    }
    int base = 0;
    #pragma unroll
    for (int i0 = 0; i0 < 10; i0++) {
      int j0 = i0 * 256 + lane * 4;
      bool nz0 = (j0     < N_) && (v[i0].x != 0.f);
      bool nz1 = (j0 + 1 < N_) && (v[i0].y != 0.f);
      bool nz2 = (j0 + 2 < N_) && (v[i0].z != 0.f);
      bool nz3 = (j0 + 3 < N_) && (v[i0].w != 0.f);
      unsigned long long m0 = __ballot(nz0);
      unsigned long long m1 = __ballot(nz1);
      unsigned long long m2 = __ballot(nz2);
      unsigned long long m3 = __ballot(nz3);
      int pre = __popcll(m0 & below) + __popcll(m1 & below)
              + __popcll(m2 & below) + __popcll(m3 & below);
      int p0 = base + pre;
      int p1 = p0 + (nz0 ? 1 : 0);
      int p2 = p1 + (nz1 ? 1 : 0);
      int p3 = p2 + (nz2 ? 1 : 0);
      if (nz0 && p0 < ELLW) cp[p0] = j0;
      if (nz1 && p1 < ELLW) cp[p1] = j0 + 1;
      if (nz2 && p2 < ELLW) cp[p2] = j0 + 2;
      if (nz3 && p3 < ELLW) cp[p3] = j0 + 3;
      base += __popcll(m0) + __popcll(m1) + __popcll(m2) + __popcll(m3);
    }
    if (lane == 0) cnts[row] = (base > ELLW) ? ELLW : base;
  } else if (bid < 4530) {
    int b = bid - 4050;
    int e0 = (b * 256 + tid) * 4;
    #pragma unroll
    for (int u = 0; u < 4; u++) {
      int e = e0 + u;
      int j = e & 7;
      int lane = (e >> 3) & 63;
      int nt = (e >> 9) & 7;
      int slab = e >> 12;
      int k = slab * 32 + ((lane >> 4) << 3) + j;
      int n = nt * 16 + (lane & 15);
      whf[e] = f16_bits(lin_w[(size_t)k * 128 + n]);
    }
  } else {
    int b = bid - 4530;
    int e0 = (b * 256 + tid) * 4;
    #pragma unroll
    for (int u = 0; u < 4; u++) {
      int e = e0 + u;
      int rb, mat, rem, K;
      if (e < 143360) {
        rb = 0;
        if (e < 110592) { mat = e / 36864; rem = e - mat * 36864; K = 259; }
        else { int tt = e - 110592; mat = 3 + tt / 16384; rem = tt & 16383; K = 128; }
      } else {
        int tt = e - 143360;
        rb = 1 + tt / 81920;
        int r2 = tt % 81920;
        mat = r2 / 16384; rem = r2 & 16383; K = 128;
      }
      int j = rem & 7, lane = (rem >> 3) & 63, nt = (rem >> 9) & 7, slab = rem >> 12;
      int k = slab * 32 + ((lane >> 4) << 3) + j;
      int n = nt * 16 + (lane & 15);
      float x = (k < K) ? wm.p[rb * 5 + mat][(size_t)k * 128 + n] : 0.f;
      wrf[e] = f16_bits(x);
    }
  }
}

// ============ split-K vertex-align gather (f16 maps) + f16 MFMA GEMM ============
// 256-thread blocks, 4 waves x 2 m-tiles -> M=128/block (R20-proven).
__global__ __launch_bounds__(256) void k_align_mfma(
    const unsigned short* __restrict__ tr0, const unsigned short* __restrict__ tr1,
    const unsigned short* __restrict__ tr2, const unsigned short* __restrict__ tr3,
    const float* __restrict__ pos,
    const unsigned short* __restrict__ whf,
    float* __restrict__ part, int kchunk) {
  int tid  = threadIdx.x;
  int wave = tid >> 6, lane = tid & 63;
  int q    = lane >> 4, l15 = lane & 15;
  int m0   = blockIdx.x * 128;
  int s    = blockIdx.y;

  int zero[2][4]; int base[2][4];
  #pragma unroll
  for (int u = 0; u < 2; u++) {
    int mrow = m0 + (wave * 2 + u) * 16 + l15;
    int rowc = (mrow < R_) ? mrow : 0;
    int b = rowc / N_;
    float px = pos[rowc*3+0], py = pos[rowc*3+1], pz = pos[rowc*3+2];
    float hh = fminf(fmaxf(248.f*(py/pz)    + 111.5f, 0.f), 223.f);
    float wc = fminf(fmaxf(248.f*(px/(-pz)) + 111.5f, 0.f), 223.f);
    const int Sarr[4] = {56, 28, 14, 7};
    const int Carr[4] = {256, 512, 1024, 2048};
    #pragma unroll
    for (int sc = 0; sc < 4; sc++) {
      int S = Sarr[sc], C = Carr[sc];
      float dv = 224.f / (float)S;
      float x = hh / dv, y = wc / dv;
      int x1 = (int)floorf(x), y1 = (int)floorf(y);
      int x2 = min((int)ceilf(x), S - 1), y2 = min((int)ceilf(y), S - 1);
      int w = (x2 - x1) * (y2 - y1);              // ∈ {0,1}
      zero[u][sc] = (mrow >= R_) || (w == 0);
      base[u][sc] = (b * S * S + x1 * S + y1) * C;
    }
  }

  f32x4 acc[2][8];
  #pragma unroll
  for (int u = 0; u < 2; u++)
    #pragma unroll
    for (int nt = 0; nt < 8; nt++) acc[u][nt] = (f32x4){0.f, 0.f, 0.f, 0.f};

  const f16x8* BH = (const f16x8*)whf;

  int kbeg = s * kchunk, kend = kbeg + kchunk;
  #pragma unroll 1
  for (int k0 = kbeg; k0 < kend; k0 += 32) {
    const unsigned short* tr; int off, sI;
    if (k0 < 256)       { tr = tr0; off = 0;    sI = 0; }
    else if (k0 < 768)  { tr = tr1; off = 256;  sI = 1; }
    else if (k0 < 1792) { tr = tr2; off = 768;  sI = 2; }
    else                { tr = tr3; off = 1792; sI = 3; }

    f16x8 af[2];
    #pragma unroll
    for (int u = 0; u < 2; u++) {
      af[u] = *(const f16x8*)(tr + base[u][sI] + (k0 - off) + q * 8);
      if (zero[u][sI]) af[u] = (f16x8)(_Float16)0;
    }

    int slab = k0 >> 5;
    f16x8 Bh[8];
    #pragma unroll
    for (int nt = 0; nt < 8; nt++)
      Bh[nt] = BH[(size_t)(slab * 8 + nt) * 64 + lane];
    #pragma unroll
    for (int nt = 0; nt < 8; nt++) {
      acc[0][nt] = __builtin_amdgcn_mfma_f32_16x16x32_f16(af[0], Bh[nt], acc[0][nt], 0, 0, 0);
      acc[1][nt] = __builtin_amdgcn_mfma_f32_16x16x32_f16(af[1], Bh[nt], acc[1][nt], 0, 0, 0);
    }
  }

  #pragma unroll
  for (int u = 0; u < 2; u++)
    #pragma unroll
    for (int nt = 0; nt < 8; nt++)
      #pragma unroll
      for (int r = 0; r < 4; r++) {
        int row = m0 + (wave * 2 + u) * 16 + q * 4 + r;
        if (row < R_)
          part[((size_t)s * R_ + row) * 128 + nt * 16 + l15] = acc[u][nt][r];
      }
}

// ---------------- reduce partials(fp32) + bias -> xcat f16 (proj|vf|pos|0pad), stride 288 ----------------
__global__ __launch_bounds__(256) void k_reduce(
    const float* __restrict__ part, const float* __restrict__ lin_b,
    const float* __restrict__ vf, const float* __restrict__ pos,
    unsigned short* __restrict__ xcat, int nsplit) {
  int grp = threadIdx.x >> 5, ln = threadIdx.x & 31;
  int row = blockIdx.x * 8 + grp;           // 1233*8 = 9864
  float4 acc = ((const float4*)lin_b)[ln];
  for (int s = 0; s < nsplit; s++) {
    float4 pv = ((const float4*)part)[((size_t)s * R_ + row) * 32 + ln];
    acc.x += pv.x; acc.y += pv.y; acc.z += pv.z; acc.w += pv.w;
  }
  ushort4* xr = (ushort4*)(xcat + (size_t)row * 288);
  ushort4 o;
  o.x = f16_bits(acc.x); o.y = f16_bits(acc.y);
  o.z = f16_bits(acc.z); o.w = f16_bits(acc.w);
  xr[ln] = o;
  float4 vv = ((const float4*)vf)[(size_t)row * 32 + ln];
  o.x = f16_bits(vv.x); o.y = f16_bits(vv.y);
  o.z = f16_bits(vv.z); o.w = f16_bits(vv.w);
  xr[32 + ln] = o;
  if (ln < 8) {
    ushort4 z = make_ushort4(0, 0, 0, 0);
    if (ln == 0) {
      z.x = f16_bits(pos[(size_t)row * 3 + 0]);
      z.y = f16_bits(pos[(size_t)row * 3 + 1]);
      z.z = f16_bits(pos[(size_t)row * 3 + 2]);
    }
    xr[64 + ln] = z;
  }
}

// ============ f16 MFMA GEMM: out[which] = X @ W[which] (+pb for which==2) ============
// X already f16 in fragment-friendly row-major -> direct f16x8 A-loads (no cvt chain).
template<int SLABS>
__global__ __launch_bounds__(256) void k_gemm_mfma(
    const unsigned short* __restrict__ X, int ldx,
    const unsigned short* __restrict__ wf,
    int matStride, const float* __restrict__ pb,
    unsigned short* __restrict__ o0, unsigned short* __restrict__ o1,
    unsigned short* __restrict__ o2) {
  int tid = threadIdx.x;
  int wave = tid >> 6, lane = tid & 63;
  int q = lane >> 4, l15 = lane & 15;
  int which = blockIdx.y;
  int m0 = blockIdx.x * 64;
  int mrow = m0 + wave * 16 + l15;
  int rowc = (mrow < R_) ? mrow : (R_ - 1);
  const unsigned short* xrow = X + (size_t)rowc * ldx + q * 8;

  const f16x8* BH = (const f16x8*)(wf + (size_t)which * matStride);

  f32x4 acc[8];
  #pragma unroll
  for (int nt = 0; nt < 8; nt++) acc[nt] = (f32x4){0.f, 0.f, 0.f, 0.f};

  #pragma unroll 1
  for (int slab = 0; slab < SLABS; slab++) {
    f16x8 af = *(const f16x8*)(xrow + slab * 32);
    f16x8 Bh[8];
    #pragma unroll
    for (int nt = 0; nt < 8; nt++)
      Bh[nt] = BH[(size_t)(slab * 8 + nt) * 64 + lane];
    #pragma unroll
    for (int nt = 0; nt < 8; nt++)
      acc[nt] = __builtin_amdgcn_mfma_f32_16x16x32_f16(af, Bh[nt], acc[nt], 0, 0, 0);
  }

  unsigned short* out = (which == 0) ? o0 : (which == 1) ? o1 : o2;
  #pragma unroll
  for (int nt = 0; nt < 8; nt++) {
    int col = nt * 16 + l15;
    float bias = (pb != nullptr && which == 2) ? pb[col] : 0.f;
    #pragma unroll
    for (int r = 0; r < 4; r++) {
      int row = m0 + wave * 16 + q * 4 + r;
      if (row < R_) out[(size_t)row * 128 + col] = f16_bits(acc[nt][r] + bias);
    }
  }
}

// ---------------- SpMM (f16 in/out, fp32 adds): out = [skip +] relu(s + A@t) ----------------
// First 12 ELL indices preloaded (3x int4) -> gathers issue together (~96% rows covered).
__global__ __launch_bounds__(256) void k_spmm(
    const unsigned short* __restrict__ sb, const unsigned short* __restrict__ tb,
    const int* __restrict__ cols, const int* __restrict__ cnts,
    const unsigned short* __restrict__ skipb, unsigned short* __restrict__ outb,
    const float* __restrict__ gw0, const float* __restrict__ gw1,
    unsigned short* __restrict__ gsb, unsigned short* __restrict__ gtb, int fuse_gf) {
  int tid = threadIdx.x;
  int grp = tid >> 5, ln = tid & 31;
  int row = blockIdx.x * 8 + grp;           // 1233 * 8 = 9864 exact
  int b = row / N_;
  size_t tbase = (size_t)b * N_;
  const f16x4* sb4 = (const f16x4*)sb;
  const f16x4* tb4 = (const f16x4*)tb;
  const int* cp = cols + (size_t)row * ELLW;   // row stride 384 B -> int4-aligned
  int4 ci0 = *(const int4*)cp;
  int4 ci1 = *(const int4*)(cp + 4);
  int4 ci2 = *(const int4*)(cp + 8);
  int cnt = cnts[row];
  f16x4 sv = sb4[(size_t)row*32 + ln];
  float4 acc = make_float4((float)sv[0], (float)sv[1], (float)sv[2], (float)sv[3]);
  int idx[12] = {ci0.x, ci0.y, ci0.z, ci0.w, ci1.x, ci1.y, ci1.z, ci1.w,
                 ci2.x, ci2.y, ci2.z, ci2.w};
  f16x4 g[12];
  #pragma unroll
  for (int i = 0; i < 12; i++) {
    int c = idx[i];
    c = (c >= 0 && c < N_) ? c : 0;          // clamp garbage past cnt (value unused)
    g[i] = tb4[(tbase + c)*32 + ln];
  }
  #pragma unroll
  for (int i = 0; i < 12; i++) {
    if (i < cnt) {
      acc.x += (float)g[i][0]; acc.y += (float)g[i][1];
      acc.z += (float)g[i][2]; acc.w += (float)g[i][3];
    }
  }
  for (int i = 12; i < cnt; i++) {
    f16x4 v = tb4[(tbase + cp[i])*32 + ln];
    acc.x += (float)v[0]; acc.y += (float)v[1];
    acc.z += (float)v[2]; acc.w += (float)v[3];
  }
  acc.x = fmaxf(acc.x, 0.f); acc.y = fmaxf(acc.y, 0.f);
  acc.z = fmaxf(acc.z, 0.f); acc.w = fmaxf(acc.w, 0.f);
  if (skipb) {
    f16x4 sk = ((const f16x4*)skipb)[(size_t)row*32 + ln];
    acc.x += (float)sk[0]; acc.y += (float)sk[1];
    acc.z += (float)sk[2]; acc.w += (float)sk[3];
  }
  if (!fuse_gf) {
    ushort4 o;
    o.x = f16_bits(acc.x); o.y = f16_bits(acc.y);
    o.z = f16_bits(acc.z); o.w = f16_bits(acc.w);
    ((ushort4*)outb)[(size_t)row*32 + ln] = o;
    return;
  }
  float av[4] = {acc.x, acc.y, acc.z, acc.w};
  int j0 = ln * 4;
  float p0 = 0.f, p1 = 0.f, p2 = 0.f, q0 = 0.f, q1 = 0.f, q2 = 0.f;
  #pragma unroll
  for (int u = 0; u < 4; u++) {
    int j = j0 + u;
    p0 += av[u] * gw0[j*3+0]; p1 += av[u] * gw0[j*3+1]; p2 += av[u] * gw0[j*3+2];
    q0 += av[u] * gw1[j*3+0]; q1 += av[u] * gw1[j*3+1]; q2 += av[u] * gw1[j*3+2];
  }
  #pragma unroll
  for (int off = 16; off >= 1; off >>= 1) {
    p0 += __shfl_xor(p0, off); p1 += __shfl_xor(p1, off); p2 += __shfl_xor(p2, off);
    q0 += __shfl_xor(q0, off); q1 += __shfl_xor(q1, off); q2 += __shfl_xor(q2, off);
  }
  if (ln == 0) {
    gsb[(size_t)row*128 + 0] = f16_bits(p0);
    gsb[(size_t)row*128 + 1] = f16_bits(p1);
    gsb[(size_t)row*128 + 2] = f16_bits(p2);
    gtb[(size_t)row*128 + 0] = f16_bits(q0);
    gtb[(size_t)row*128 + 1] = f16_bits(q1);
    gtb[(size_t)row*128 + 2] = f16_bits(q2);
  }
}

// ---------------- final: out = pos + tanh(relu(s + A@t)), f16 in, fp32 out ----------------
__global__ __launch_bounds__(256) void k_gf_final(
    const unsigned short* __restrict__ sb, const unsigned short* __restrict__ tb,
    const int* __restrict__ cols, const int* __restrict__ cnts,
    const float* __restrict__ pos, float* __restrict__ out) {
  int wave = threadIdx.x >> 6, lane = threadIdx.x & 63;
  int row = blockIdx.x * 4 + wave;          // grid 2466
  if (lane >= 3) return;
  int b = row / N_;
  size_t tbase = (size_t)b * N_;
  const int* cp = cols + (size_t)row * ELLW;
  int4 ci0 = *(const int4*)cp;
  int4 ci1 = *(const int4*)(cp + 4);
  int4 ci2 = *(const int4*)(cp + 8);
  int cnt = cnts[row];
  union { unsigned short u; _Float16 h; } cv;
  cv.u = sb[(size_t)row*128 + lane];
  float acc = (float)cv.h;
  int idx[12] = {ci0.x, ci0.y, ci0.z, ci0.w, ci1.x, ci1.y, ci1.z, ci1.w,
                 ci2.x, ci2.y, ci2.z, ci2.w};
  float g[12];
  #pragma unroll
  for (int i = 0; i < 12; i++) {
    int c = idx[i];
    c = (c >= 0 && c < N_) ? c : 0;
    cv.u = tb[(tbase + c)*128 + lane];
    g[i] = (float)cv.h;
  }
  #pragma unroll
  for (int i = 0; i < 12; i++)
    if (i < cnt) acc += g[i];
  for (int i = 12; i < cnt; i++) {
    cv.u = tb[(tbase + cp[i])*128 + lane];
    acc += (float)cv.h;
  }
  float v = tanhf(fmaxf(acc, 0.f));
  out[(size_t)row*3 + lane] = pos[(size_t)row*3 + lane] + v;
}

extern "C" void kernel_launch(void* const* d_in, const int* in_sizes, int n_in,
                              void* d_out, int out_size, void* d_ws, size_t ws_size,
                              hipStream_t stream) {
  const float* conv2_3 = (const float*)d_in[0];
  const float* conv3_4 = (const float*)d_in[1];
  const float* conv4_6 = (const float*)d_in[2];
  const float* conv5_3 = (const float*)d_in[3];
  const float* pos     = (const float*)d_in[4];
  const float* vf      = (const float*)d_in[5];
  const float* adj     = (const float*)d_in[6];
  const float* lin_w   = (const float*)d_in[7];
  const float* lin_b   = (const float*)d_in[8];
  const float* r_pb[3]  = {(const float*)d_in[10], (const float*)d_in[16], (const float*)d_in[22]};
  const float* gf_w0 = (const float*)d_in[27];
  const float* gf_w1 = (const float*)d_in[28];
  float* out = (float*)d_out;

  // ---- workspace layout (all segments 16B-aligned) ----
  const size_t TRH_TOT = 6021120;                 // f16 map elems
  const size_t ROWF    = (size_t)R_ * 128;        // 1,262,592 elems per activation
  const size_t XCATE   = (size_t)R_ * 288;        // 2,840,832 f16 elems
  const size_t LINW_E  = 491520;                  // shorts
  const size_t RESW_E  = 307200;                  // shorts

  unsigned short* trh0 = (unsigned short*)d_ws;
  unsigned short* trh1 = trh0 + (size_t)4*256*3136;
  unsigned short* trh2 = trh1 + (size_t)4*512*784;
  unsigned short* trh3 = trh2 + (size_t)4*1024*196;
  int*   ell_cnt  = (int*)(trh3 + (size_t)4*2048*49);
  int*   ell_cols = ell_cnt + R_;
  unsigned short* whf = (unsigned short*)(ell_cols + (size_t)R_*ELLW);
  unsigned short* wrf = whf + LINW_E;
  float* part = (float*)(wrf + RESW_E + 512);     // fp32 split-K partials

  size_t fixed_f = TRH_TOT/2 + (size_t)R_*(ELLW+1) + (LINW_E + RESW_E + 512)/2;
  size_t need8 = (fixed_f + (size_t)8*ROWF + (XCATE + 5*ROWF + 1024)/2) * sizeof(float);
  int nsplit = (ws_size >= need8) ? 8 : 4;
  int kchunk = 3840 / nsplit;

  unsigned short* xcat = (unsigned short*)(part + (size_t)nsplit * ROWF);
  unsigned short* sb   = xcat + XCATE;
  unsigned short* tb   = sb   + ROWF;
  unsigned short* skip = tb   + ROWF;
  unsigned short* hb   = skip + ROWF;
  unsigned short* xc   = hb   + ROWF;

  WMats wm;
  for (int rb = 0; rb < 3; rb++) {
    wm.p[rb*5 + 0] = (const float*)d_in[11 + 6*rb];  // w00
    wm.p[rb*5 + 1] = (const float*)d_in[12 + 6*rb];  // w01
    wm.p[rb*5 + 2] = (const float*)d_in[9  + 6*rb];  // pw
    wm.p[rb*5 + 3] = (const float*)d_in[13 + 6*rb];  // w10
    wm.p[rb*5 + 4] = (const float*)d_in[14 + 6*rb];  // w11
  }
  const int RB_BASE[3] = {0, 143360, 225280};

  // D0: transposes(->f16) + ELL + all W f16 splits
  k_pre<<<4830, 256, 0, stream>>>(conv2_3, conv3_4, conv4_6, conv5_3,
                                  trh0, trh1, trh2, trh3,
                                  adj, ell_cols, ell_cnt,
                                  lin_w, whf, wm, wrf);

  // D1: split-K f16 MFMA align GEMM (2 m-tiles/wave, M=128)
  k_align_mfma<<<dim3(78, nsplit), 256, 0, stream>>>(trh0, trh1, trh2, trh3, pos,
                                                     whf, part, kchunk);

  // D2: reduce partials(fp32) + concat -> xcat f16
  k_reduce<<<1233, 256, 0, stream>>>(part, lin_b, vf, pos, xcat, nsplit);

  // D3..: three residual graph-conv blocks; activations f16, adds fp32
  for (int rb = 0; rb < 3; rb++) {
    if (rb == 0) {
      k_gemm_mfma<9><<<dim3(155, 3), 256, 0, stream>>>(
          xcat, 288, wrf + RB_BASE[0], 36864, r_pb[0], sb, tb, skip);
    } else {
      k_gemm_mfma<4><<<dim3(155, 3), 256, 0, stream>>>(
          xc, 128, wrf + RB_BASE[rb], 16384, r_pb[rb], sb, tb, skip);
    }
    k_spmm<<<1233, 256, 0, stream>>>(sb, tb, ell_cols, ell_cnt, nullptr, hb,
                                     nullptr, nullptr, nullptr, nullptr, 0);
    int g2off = RB_BASE[rb] + ((rb == 0) ? 110592 : 3 * 16384);
    k_gemm_mfma<4><<<dim3(155, 2), 256, 0, stream>>>(
        hb, 128, wrf + g2off, 16384, nullptr, sb, tb, nullptr);
    if (rb < 2) {
      k_spmm<<<1233, 256, 0, stream>>>(sb, tb, ell_cols, ell_cnt, skip, xc,
                                       nullptr, nullptr, nullptr, nullptr, 0);
    } else {
      k_spmm<<<1233, 256, 0, stream>>>(sb, tb, ell_cols, ell_cnt, skip, nullptr,
                                       gf_w0, gf_w1, hb, xc, 1);   // gsb=hb, gtb=xc
    }
  }

  // final: out = pos + tanh(relu(gsb + A@gtb))
  k_gf_final<<<2466, 256, 0, stream>>>(hb, xc, ell_cols, ell_cnt, pos, out);
}

// Round 22
// 379.718 us; speedup vs baseline: 1.3866x; 1.0056x over previous
//
#include <hip/hip_runtime.h>
#include <cmath>

#define B_   4
#define N_   2466
#define R_   (B_*N_)     // 9864
#define ELLW 96

typedef _Float16 f16x8 __attribute__((ext_vector_type(8)));
typedef _Float16 f16x4 __attribute__((ext_vector_type(4)));
typedef __attribute__((ext_vector_type(4))) float f32x4;

__device__ __forceinline__ unsigned short f16_bits(float x) {
  union { _Float16 h; unsigned short u; } c;
  c.h = (_Float16)x;          // RNE
  return c.u;
}

struct WMats { const float* p[15]; };   // rb-major: w00,w01,pw,w10,w11

// Fragment-order layout (lin_w and res weights), f16 single-pass:
// e = ((slab*8 + nt)*64 + lane)*8 + j ; k = slab*32 + (lane>>4)*8 + j ; n = nt*16 + (lane&15)
// All activations AND split-K partials stored f16; all adds fp32.

// ============ fused pre-kernel: transposes(->f16, 64x64 tiles) + ELL + W f16 splits ============
__global__ __launch_bounds__(256) void k_pre(
    const float* __restrict__ c2, const float* __restrict__ c3,
    const float* __restrict__ c4, const float* __restrict__ c5,
    unsigned short* __restrict__ t0, unsigned short* __restrict__ t1,
    unsigned short* __restrict__ t2, unsigned short* __restrict__ t3,
    const float* __restrict__ adj, int* __restrict__ cols, int* __restrict__ cnts,
    const float* __restrict__ lin_w,
    unsigned short* __restrict__ whf,
    WMats wm,
    unsigned short* __restrict__ wrf) {
  __shared__ float t[64][66];
  int bid = blockIdx.x;
  int tid = threadIdx.x;
  if (bid < 1584) {
    const float* in; unsigned short* out; int C, P, npb, ncb, rem;
    if (bid < 784)       { in = c2; out = t0; C = 256;  P = 3136; npb = 49; ncb = 4;  rem = bid; }
    else if (bid < 1200) { in = c3; out = t1; C = 512;  P = 784;  npb = 13; ncb = 8;  rem = bid - 784; }
    else if (bid < 1456) { in = c4; out = t2; C = 1024; P = 196;  npb = 4;  ncb = 16; rem = bid - 1200; }
    else                 { in = c5; out = t3; C = 2048; P = 49;   npb = 1;  ncb = 32; rem = bid - 1456; }
    int pb = rem % npb; int tq = rem / npb; int cb = tq % ncb; int b = tq / ncb;
    int c0 = cb * 64, p0 = pb * 64;
    #pragma unroll
    for (int i = 0; i < 8; i++) {
      int e = tid + i * 256;
      int c = e >> 5, f2 = e & 31;
      int p = p0 + f2 * 2;
      float2 v = make_float2(0.f, 0.f);
      const float* src = in + ((size_t)b * C + (c0 + c)) * P + p;
      if (p + 1 < P)      v = *(const float2*)src;
      else if (p < P)     v.x = *src;
      *(float2*)&t[c][f2 * 2] = v;
    }
    __syncthreads();
    int jj = tid & 15, c4i = jj * 4;
    #pragma unroll
    for (int pass = 0; pass < 4; pass++) {
      int pp = pass * 16 + (tid >> 4);
      int px = p0 + pp;
      if (px < P) {
        ushort4 o;
        o.x = f16_bits(t[c4i + 0][pp]);
        o.y = f16_bits(t[c4i + 1][pp]);
        o.z = f16_bits(t[c4i + 2][pp]);
        o.w = f16_bits(t[c4i + 3][pp]);
        *(ushort4*)&out[((size_t)b * P + px) * C + c0 + c4i] = o;
      }
    }
  } else if (bid < 4050) {
    int wave = tid >> 6, lane = tid & 63;
    int row = (bid - 1584) * 4 + wave;
    const float* Ar = adj + (size_t)row * N_;
    int* cp = cols + (size_t)row * ELLW;
    unsigned long long below = (lane == 63) ? 0xFFFFFFFFFFFFFFFFull >> 1
                                            : ((1ull << lane) - 1ull);
    float4 v[10];
    #pragma unroll
    for (int i0 = 0; i0 < 10; i0++) {
      int j0 = i0 * 256 + lane * 4;
      if (j0 + 3 < N_) {
        v[i0] = *(const float4*)&Ar[j0];
      } else {
        v[i0] = make_float4(0.f, 0.f, 0.f, 0.f);
        if (j0     < N_) v[i0].x = Ar[j0];
        if (j0 + 1 < N_) v[i0].y = Ar[j0+1];
        if (j0 + 2 < N_) v[i0].z = Ar[j0+2];
      }
    }
    int base = 0;
    #pragma unroll
    for (int i0 = 0; i0 < 10; i0++) {
      int j0 = i0 * 256 + lane * 4;
      bool nz0 = (j0     < N_) && (v[i0].x != 0.f);
      bool nz1 = (j0 + 1 < N_) && (v[i0].y != 0.f);
      bool nz2 = (j0 + 2 < N_) && (v[i0].z != 0.f);
      bool nz3 = (j0 + 3 < N_) && (v[i0].w != 0.f);
      unsigned long long m0 = __ballot(nz0);
      unsigned long long m1 = __ballot(nz1);
      unsigned long long m2 = __ballot(nz2);
      unsigned long long m3 = __ballot(nz3);
      int pre = __popcll(m0 & below) + __popcll(m1 & below)
              + __popcll(m2 & below) + __popcll(m3 & below);
      int p0 = base + pre;
      int p1 = p0 + (nz0 ? 1 : 0);
      int p2 = p1 + (nz1 ? 1 : 0);
      int p3 = p2 + (nz2 ? 1 : 0);
      if (nz0 && p0 < ELLW) cp[p0] = j0;
      if (nz1 && p1 < ELLW) cp[p1] = j0 + 1;
      if (nz2 && p2 < ELLW) cp[p2] = j0 + 2;
      if (nz3 && p3 < ELLW) cp[p3] = j0 + 3;
      base += __popcll(m0) + __popcll(m1) + __popcll(m2) + __popcll(m3);
    }
    if (lane == 0) cnts[row] = (base > ELLW) ? ELLW : base;
  } else if (bid < 4530) {
    int b = bid - 4050;
    int e0 = (b * 256 + tid) * 4;
    #pragma unroll
    for (int u = 0; u < 4; u++) {
      int e = e0 + u;
      int j = e & 7;
      int lane = (e >> 3) & 63;
      int nt = (e >> 9) & 7;
      int slab = e >> 12;
      int k = slab * 32 + ((lane >> 4) << 3) + j;
      int n = nt * 16 + (lane & 15);
      whf[e] = f16_bits(lin_w[(size_t)k * 128 + n]);
    }
  } else {
    int b = bid - 4530;
    int e0 = (b * 256 + tid) * 4;
    #pragma unroll
    for (int u = 0; u < 4; u++) {
      int e = e0 + u;
      int rb, mat, rem, K;
      if (e < 143360) {
        rb = 0;
        if (e < 110592) { mat = e / 36864; rem = e - mat * 36864; K = 259; }
        else { int tt = e - 110592; mat = 3 + tt / 16384; rem = tt & 16383; K = 128; }
      } else {
        int tt = e - 143360;
        rb = 1 + tt / 81920;
        int r2 = tt % 81920;
        mat = r2 / 16384; rem = r2 & 16383; K = 128;
      }
      int j = rem & 7, lane = (rem >> 3) & 63, nt = (rem >> 9) & 7, slab = rem >> 12;
      int k = slab * 32 + ((lane >> 4) << 3) + j;
      int n = nt * 16 + (lane & 15);
      float x = (k < K) ? wm.p[rb * 5 + mat][(size_t)k * 128 + n] : 0.f;
      wrf[e] = f16_bits(x);
    }
  }
}

// ============ split-K vertex-align gather (f16 maps) + f16 MFMA GEMM, f16 partials ============
__global__ __launch_bounds__(256) void k_align_mfma(
    const unsigned short* __restrict__ tr0, const unsigned short* __restrict__ tr1,
    const unsigned short* __restrict__ tr2, const unsigned short* __restrict__ tr3,
    const float* __restrict__ pos,
    const unsigned short* __restrict__ whf,
    unsigned short* __restrict__ part, int kchunk) {
  int tid  = threadIdx.x;
  int wave = tid >> 6, lane = tid & 63;
  int q    = lane >> 4, l15 = lane & 15;
  int m0   = blockIdx.x * 128;
  int s    = blockIdx.y;

  int zero[2][4]; int base[2][4];
  #pragma unroll
  for (int u = 0; u < 2; u++) {
    int mrow = m0 + (wave * 2 + u) * 16 + l15;
    int rowc = (mrow < R_) ? mrow : 0;
    int b = rowc / N_;
    float px = pos[rowc*3+0], py = pos[rowc*3+1], pz = pos[rowc*3+2];
    float hh = fminf(fmaxf(248.f*(py/pz)    + 111.5f, 0.f), 223.f);
    float wc = fminf(fmaxf(248.f*(px/(-pz)) + 111.5f, 0.f), 223.f);
    const int Sarr[4] = {56, 28, 14, 7};
    const int Carr[4] = {256, 512, 1024, 2048};
    #pragma unroll
    for (int sc = 0; sc < 4; sc++) {
      int S = Sarr[sc], C = Carr[sc];
      float dv = 224.f / (float)S;
      float x = hh / dv, y = wc / dv;
      int x1 = (int)floorf(x), y1 = (int)floorf(y);
      int x2 = min((int)ceilf(x), S - 1), y2 = min((int)ceilf(y), S - 1);
      int w = (x2 - x1) * (y2 - y1);              // ∈ {0,1}
      zero[u][sc] = (mrow >= R_) || (w == 0);
      base[u][sc] = (b * S * S + x1 * S + y1) * C;
    }
  }

  f32x4 acc[2][8];
  #pragma unroll
  for (int u = 0; u < 2; u++)
    #pragma unroll
    for (int nt = 0; nt < 8; nt++) acc[u][nt] = (f32x4){0.f, 0.f, 0.f, 0.f};

  const f16x8* BH = (const f16x8*)whf;

  int kbeg = s * kchunk, kend = kbeg + kchunk;
  #pragma unroll 1
  for (int k0 = kbeg; k0 < kend; k0 += 32) {
    const unsigned short* tr; int off, sI;
    if (k0 < 256)       { tr = tr0; off = 0;    sI = 0; }
    else if (k0 < 768)  { tr = tr1; off = 256;  sI = 1; }
    else if (k0 < 1792) { tr = tr2; off = 768;  sI = 2; }
    else                { tr = tr3; off = 1792; sI = 3; }

    f16x8 af[2];
    #pragma unroll
    for (int u = 0; u < 2; u++) {
      af[u] = *(const f16x8*)(tr + base[u][sI] + (k0 - off) + q * 8);
      if (zero[u][sI]) af[u] = (f16x8)(_Float16)0;
    }

    int slab = k0 >> 5;
    f16x8 Bh[8];
    #pragma unroll
    for (int nt = 0; nt < 8; nt++)
      Bh[nt] = BH[(size_t)(slab * 8 + nt) * 64 + lane];
    #pragma unroll
    for (int nt = 0; nt < 8; nt++) {
      acc[0][nt] = __builtin_amdgcn_mfma_f32_16x16x32_f16(af[0], Bh[nt], acc[0][nt], 0, 0, 0);
      acc[1][nt] = __builtin_amdgcn_mfma_f32_16x16x32_f16(af[1], Bh[nt], acc[1][nt], 0, 0, 0);
    }
  }

  #pragma unroll
  for (int u = 0; u < 2; u++)
    #pragma unroll
    for (int nt = 0; nt < 8; nt++)
      #pragma unroll
      for (int r = 0; r < 4; r++) {
        int row = m0 + (wave * 2 + u) * 16 + q * 4 + r;
        if (row < R_)
          part[((size_t)s * R_ + row) * 128 + nt * 16 + l15] = f16_bits(acc[u][nt][r]);
      }
}

// ---------------- reduce f16 partials(fp32 adds) + bias -> xcat f16 ----------------
__global__ __launch_bounds__(256) void k_reduce(
    const unsigned short* __restrict__ part, const float* __restrict__ lin_b,
    const float* __restrict__ vf, const float* __restrict__ pos,
    unsigned short* __restrict__ xcat, int nsplit) {
  int grp = threadIdx.x >> 5, ln = threadIdx.x & 31;
  int row = blockIdx.x * 8 + grp;           // 1233*8 = 9864
  float4 acc = ((const float4*)lin_b)[ln];
  const f16x4* p4 = (const f16x4*)part;
  for (int s = 0; s < nsplit; s++) {
    f16x4 pv = p4[((size_t)s * R_ + row) * 32 + ln];
    acc.x += (float)pv[0]; acc.y += (float)pv[1];
    acc.z += (float)pv[2]; acc.w += (float)pv[3];
  }
  ushort4* xr = (ushort4*)(xcat + (size_t)row * 288);
  ushort4 o;
  o.x = f16_bits(acc.x); o.y = f16_bits(acc.y);
  o.z = f16_bits(acc.z); o.w = f16_bits(acc.w);
  xr[ln] = o;
  float4 vv = ((const float4*)vf)[(size_t)row * 32 + ln];
  o.x = f16_bits(vv.x); o.y = f16_bits(vv.y);
  o.z = f16_bits(vv.z); o.w = f16_bits(vv.w);
  xr[32 + ln] = o;
  if (ln < 8) {
    ushort4 z = make_ushort4(0, 0, 0, 0);
    if (ln == 0) {
      z.x = f16_bits(pos[(size_t)row * 3 + 0]);
      z.y = f16_bits(pos[(size_t)row * 3 + 1]);
      z.z = f16_bits(pos[(size_t)row * 3 + 2]);
    }
    xr[64 + ln] = z;
  }
}

// ============ f16 MFMA GEMM: out[which] = X @ W[which] (+pb for which==2) ============
template<int SLABS>
__global__ __launch_bounds__(256) void k_gemm_mfma(
    const unsigned short* __restrict__ X, int ldx,
    const unsigned short* __restrict__ wf,
    int matStride, const float* __restrict__ pb,
    unsigned short* __restrict__ o0, unsigned short* __restrict__ o1,
    unsigned short* __restrict__ o2) {
  int tid = threadIdx.x;
  int wave = tid >> 6, lane = tid & 63;
  int q = lane >> 4, l15 = lane & 15;
  int which = blockIdx.y;
  int m0 = blockIdx.x * 64;
  int mrow = m0 + wave * 16 + l15;
  int rowc = (mrow < R_) ? mrow : (R_ - 1);
  const unsigned short* xrow = X + (size_t)rowc * ldx + q * 8;

  const f16x8* BH = (const f16x8*)(wf + (size_t)which * matStride);

  f32x4 acc[8];
  #pragma unroll
  for (int nt = 0; nt < 8; nt++) acc[nt] = (f32x4){0.f, 0.f, 0.f, 0.f};

  #pragma unroll 1
  for (int slab = 0; slab < SLABS; slab++) {
    f16x8 af = *(const f16x8*)(xrow + slab * 32);
    f16x8 Bh[8];
    #pragma unroll
    for (int nt = 0; nt < 8; nt++)
      Bh[nt] = BH[(size_t)(slab * 8 + nt) * 64 + lane];
    #pragma unroll
    for (int nt = 0; nt < 8; nt++)
      acc[nt] = __builtin_amdgcn_mfma_f32_16x16x32_f16(af, Bh[nt], acc[nt], 0, 0, 0);
  }

  unsigned short* out = (which == 0) ? o0 : (which == 1) ? o1 : o2;
  #pragma unroll
  for (int nt = 0; nt < 8; nt++) {
    int col = nt * 16 + l15;
    float bias = (pb != nullptr && which == 2) ? pb[col] : 0.f;
    #pragma unroll
    for (int r = 0; r < 4; r++) {
      int row = m0 + wave * 16 + q * 4 + r;
      if (row < R_) out[(size_t)row * 128 + col] = f16_bits(acc[nt][r] + bias);
    }
  }
}

// ---------------- SpMM (f16 in/out, fp32 adds): out = [skip +] relu(s + A@t) ----------------
__global__ __launch_bounds__(256) void k_spmm(
    const unsigned short* __restrict__ sb, const unsigned short* __restrict__ tb,
    const int* __restrict__ cols, const int* __restrict__ cnts,
    const unsigned short* __restrict__ skipb, unsigned short* __restrict__ outb,
    const float* __restrict__ gw0, const float* __restrict__ gw1,
    unsigned short* __restrict__ gsb, unsigned short* __restrict__ gtb, int fuse_gf) {
  int tid = threadIdx.x;
  int grp = tid >> 5, ln = tid & 31;
  int row = blockIdx.x * 8 + grp;           // 1233 * 8 = 9864 exact
  int b = row / N_;
  size_t tbase = (size_t)b * N_;
  const f16x4* sb4 = (const f16x4*)sb;
  const f16x4* tb4 = (const f16x4*)tb;
  const int* cp = cols + (size_t)row * ELLW;
  int4 ci0 = *(const int4*)cp;
  int4 ci1 = *(const int4*)(cp + 4);
  int4 ci2 = *(const int4*)(cp + 8);
  int cnt = cnts[row];
  f16x4 sv = sb4[(size_t)row*32 + ln];
  float4 acc = make_float4((float)sv[0], (float)sv[1], (float)sv[2], (float)sv[3]);
  int idx[12] = {ci0.x, ci0.y, ci0.z, ci0.w, ci1.x, ci1.y, ci1.z, ci1.w,
                 ci2.x, ci2.y, ci2.z, ci2.w};
  f16x4 g[12];
  #pragma unroll
  for (int i = 0; i < 12; i++) {
    int c = idx[i];
    c = (c >= 0 && c < N_) ? c : 0;
    g[i] = tb4[(tbase + c)*32 + ln];
  }
  #pragma unroll
  for (int i = 0; i < 12; i++) {
    if (i < cnt) {
      acc.x += (float)g[i][0]; acc.y += (float)g[i][1];
      acc.z += (float)g[i][2]; acc.w += (float)g[i][3];
    }
  }
  for (int i = 12; i < cnt; i++) {
    f16x4 v = tb4[(tbase + cp[i])*32 + ln];
    acc.x += (float)v[0]; acc.y += (float)v[1];
    acc.z += (float)v[2]; acc.w += (float)v[3];
  }
  acc.x = fmaxf(acc.x, 0.f); acc.y = fmaxf(acc.y, 0.f);
  acc.z = fmaxf(acc.z, 0.f); acc.w = fmaxf(acc.w, 0.f);
  if (skipb) {
    f16x4 sk = ((const f16x4*)skipb)[(size_t)row*32 + ln];
    acc.x += (float)sk[0]; acc.y += (float)sk[1];
    acc.z += (float)sk[2]; acc.w += (float)sk[3];
  }
  if (!fuse_gf) {
    ushort4 o;
    o.x = f16_bits(acc.x); o.y = f16_bits(acc.y);
    o.z = f16_bits(acc.z); o.w = f16_bits(acc.w);
    ((ushort4*)outb)[(size_t)row*32 + ln] = o;
    return;
  }
  float av[4] = {acc.x, acc.y, acc.z, acc.w};
  int j0 = ln * 4;
  float p0 = 0.f, p1 = 0.f, p2 = 0.f, q0 = 0.f, q1 = 0.f, q2 = 0.f;
  #pragma unroll
  for (int u = 0; u < 4; u++) {
    int j = j0 + u;
    p0 += av[u] * gw0[j*3+0]; p1 += av[u] * gw0[j*3+1]; p2 += av[u] * gw0[j*3+2];
    q0 += av[u] * gw1[j*3+0]; q1 += av[u] * gw1[j*3+1]; q2 += av[u] * gw1[j*3+2];
  }
  #pragma unroll
  for (int off = 16; off >= 1; off >>= 1) {
    p0 += __shfl_xor(p0, off); p1 += __shfl_xor(p1, off); p2 += __shfl_xor(p2, off);
    q0 += __shfl_xor(q0, off); q1 += __shfl_xor(q1, off); q2 += __shfl_xor(q2, off);
  }
  if (ln == 0) {
    gsb[(size_t)row*128 + 0] = f16_bits(p0);
    gsb[(size_t)row*128 + 1] = f16_bits(p1);
    gsb[(size_t)row*128 + 2] = f16_bits(p2);
    gtb[(size_t)row*128 + 0] = f16_bits(q0);
    gtb[(size_t)row*128 + 1] = f16_bits(q1);
    gtb[(size_t)row*128 + 2] = f16_bits(q2);
  }
}

// ---------------- final: out = pos + tanh(relu(s + A@t)), f16 in, fp32 out ----------------
__global__ __launch_bounds__(256) void k_gf_final(
    const unsigned short* __restrict__ sb, const unsigned short* __restrict__ tb,
    const int* __restrict__ cols, const int* __restrict__ cnts,
    const float* __restrict__ pos, float* __restrict__ out) {
  int wave = threadIdx.x >> 6, lane = threadIdx.x & 63;
  int row = blockIdx.x * 4 + wave;          // grid 2466
  if (lane >= 3) return;
  int b = row / N_;
  size_t tbase = (size_t)b * N_;
  const int* cp = cols + (size_t)row * ELLW;
  int4 ci0 = *(const int4*)cp;
  int4 ci1 = *(const int4*)(cp + 4);
  int4 ci2 = *(const int4*)(cp + 8);
  int cnt = cnts[row];
  union { unsigned short u; _Float16 h; } cv;
  cv.u = sb[(size_t)row*128 + lane];
  float acc = (float)cv.h;
  int idx[12] = {ci0.x, ci0.y, ci0.z, ci0.w, ci1.x, ci1.y, ci1.z, ci1.w,
                 ci2.x, ci2.y, ci2.z, ci2.w};
  float g[12];
  #pragma unroll
  for (int i = 0; i < 12; i++) {
    int c = idx[i];
    c = (c >= 0 && c < N_) ? c : 0;
    cv.u = tb[(tbase + c)*128 + lane];
    g[i] = (float)cv.h;
  }
  #pragma unroll
  for (int i = 0; i < 12; i++)
    if (i < cnt) acc += g[i];
  for (int i = 12; i < cnt; i++) {
    cv.u = tb[(tbase + cp[i])*128 + lane];
    acc += (float)cv.h;
  }
  float v = tanhf(fmaxf(acc, 0.f));
  out[(size_t)row*3 + lane] = pos[(size_t)row*3 + lane] + v;
}

extern "C" void kernel_launch(void* const* d_in, const int* in_sizes, int n_in,
                              void* d_out, int out_size, void* d_ws, size_t ws_size,
                              hipStream_t stream) {
  const float* conv2_3 = (const float*)d_in[0];
  const float* conv3_4 = (const float*)d_in[1];
  const float* conv4_6 = (const float*)d_in[2];
  const float* conv5_3 = (const float*)d_in[3];
  const float* pos     = (const float*)d_in[4];
  const float* vf      = (const float*)d_in[5];
  const float* adj     = (const float*)d_in[6];
  const float* lin_w   = (const float*)d_in[7];
  const float* lin_b   = (const float*)d_in[8];
  const float* r_pb[3]  = {(const float*)d_in[10], (const float*)d_in[16], (const float*)d_in[22]};
  const float* gf_w0 = (const float*)d_in[27];
  const float* gf_w1 = (const float*)d_in[28];
  float* out = (float*)d_out;

  // ---- workspace layout (all segments 16B-aligned; everything f16 except ELL ints) ----
  const size_t ROWF    = (size_t)R_ * 128;        // elems per activation buffer
  const size_t XCATE   = (size_t)R_ * 288;
  const size_t LINW_E  = 491520;
  const size_t RESW_E  = 307200;

  unsigned short* trh0 = (unsigned short*)d_ws;
  unsigned short* trh1 = trh0 + (size_t)4*256*3136;
  unsigned short* trh2 = trh1 + (size_t)4*512*784;
  unsigned short* trh3 = trh2 + (size_t)4*1024*196;
  int*   ell_cnt  = (int*)(trh3 + (size_t)4*2048*49);
  int*   ell_cols = ell_cnt + R_;
  unsigned short* whf = (unsigned short*)(ell_cols + (size_t)R_*ELLW);
  unsigned short* wrf = whf + LINW_E;
  unsigned short* part = wrf + RESW_E + 512;      // f16 split-K partials

  size_t fixed_h = 6021120 + 2*(size_t)R_*(ELLW+1) + LINW_E + RESW_E + 512;  // shorts
  size_t need8 = (fixed_h + (size_t)8*ROWF + XCATE + 5*ROWF + 1024) * 2;     // bytes
  int nsplit = (ws_size >= need8) ? 8 : 4;
  int kchunk = 3840 / nsplit;

  unsigned short* xcat = part + (size_t)nsplit * ROWF;
  unsigned short* sb   = xcat + XCATE;
  unsigned short* tb   = sb   + ROWF;
  unsigned short* skip = tb   + ROWF;
  unsigned short* hb   = skip + ROWF;
  unsigned short* xc   = hb   + ROWF;

  WMats wm;
  for (int rb = 0; rb < 3; rb++) {
    wm.p[rb*5 + 0] = (const float*)d_in[11 + 6*rb];  // w00
    wm.p[rb*5 + 1] = (const float*)d_in[12 + 6*rb];  // w01
    wm.p[rb*5 + 2] = (const float*)d_in[9  + 6*rb];  // pw
    wm.p[rb*5 + 3] = (const float*)d_in[13 + 6*rb];  // w10
    wm.p[rb*5 + 4] = (const float*)d_in[14 + 6*rb];  // w11
  }
  const int RB_BASE[3] = {0, 143360, 225280};

  // D0: transposes(->f16) + ELL + all W f16 splits
  k_pre<<<4830, 256, 0, stream>>>(conv2_3, conv3_4, conv4_6, conv5_3,
                                  trh0, trh1, trh2, trh3,
                                  adj, ell_cols, ell_cnt,
                                  lin_w, whf, wm, wrf);

  // D1: split-K f16 MFMA align GEMM (f16 partials)
  k_align_mfma<<<dim3(78, nsplit), 256, 0, stream>>>(trh0, trh1, trh2, trh3, pos,
                                                     whf, part, kchunk);

  // D2: reduce f16 partials (fp32 adds) + concat -> xcat f16
  k_reduce<<<1233, 256, 0, stream>>>(part, lin_b, vf, pos, xcat, nsplit);

  // D3..: three residual graph-conv blocks; activations f16, adds fp32
  for (int rb = 0; rb < 3; rb++) {
    if (rb == 0) {
      k_gemm_mfma<9><<<dim3(155, 3), 256, 0, stream>>>(
          xcat, 288, wrf + RB_BASE[0], 36864, r_pb[0], sb, tb, skip);
    } else {
      k_gemm_mfma<4><<<dim3(155, 3), 256, 0, stream>>>(
          xc, 128, wrf + RB_BASE[rb], 16384, r_pb[rb], sb, tb, skip);
    }
    k_spmm<<<1233, 256, 0, stream>>>(sb, tb, ell_cols, ell_cnt, nullptr, hb,
                                     nullptr, nullptr, nullptr, nullptr, 0);
    int g2off = RB_BASE[rb] + ((rb == 0) ? 110592 : 3 * 16384);
    k_gemm_mfma<4><<<dim3(155, 2), 256, 0, stream>>>(
        hb, 128, wrf + g2off, 16384, nullptr, sb, tb, nullptr);
    if (rb < 2) {
      k_spmm<<<1233, 256, 0, stream>>>(sb, tb, ell_cols, ell_cnt, skip, xc,
                                       nullptr, nullptr, nullptr, nullptr, 0);
    } else {
      k_spmm<<<1233, 256, 0, stream>>>(sb, tb, ell_cols, ell_cnt, skip, nullptr,
                                       gf_w0, gf_w1, hb, xc, 1);   // gsb=hb, gtb=xc
    }
  }

  // final: out = pos + tanh(relu(gsb + A@gtb))
  k_gf_final<<<2466, 256, 0, stream>>>(hb, xc, ell_cols, ell_cnt, pos, out);
}